// Round 1
// baseline (2816.769 us; speedup 1.0000x reference)
//
#include <hip/hip_runtime.h>

#define N_NODES 100000
#define N_EDGES 1600000
#define N_GRAPHS 256
#define EPS 1e-5f

// ---------------------------------------------------------------------------
// Edge MLP: ew[e] = Linear(16,1)(ReLU(Linear(8,16)(edge_attr[e])))
// fused with degree accumulation: deg[tgt[e]] += ew[e]
// ---------------------------------------------------------------------------
__global__ __launch_bounds__(256) void k_edge_mlp(
    const float* __restrict__ ea, const float* __restrict__ w1,
    const float* __restrict__ b1, const float* __restrict__ w2,
    const float* __restrict__ b2, const int* __restrict__ tgt,
    float* __restrict__ ew, float* __restrict__ deg) {
  __shared__ float W1[128], B1[16], W2[16];
  int t = threadIdx.x;
  if (t < 128) W1[t] = w1[t];
  if (t < 16) { B1[t] = b1[t]; W2[t] = w2[t]; }
  __syncthreads();
  int e = blockIdx.x * 256 + t;
  if (e >= N_EDGES) return;
  const float4* ap = (const float4*)(ea + (size_t)e * 8);
  float4 a0 = ap[0], a1 = ap[1];
  float a[8] = {a0.x, a0.y, a0.z, a0.w, a1.x, a1.y, a1.z, a1.w};
  float out = b2[0];
#pragma unroll
  for (int i = 0; i < 16; ++i) {
    float h = B1[i];
#pragma unroll
    for (int j = 0; j < 8; ++j) h += a[j] * W1[i * 8 + j];
    out += fmaxf(h, 0.f) * W2[i];
  }
  ew[e] = out;
  atomicAdd(&deg[tgt[e]], out);
}

// dinv[n] = deg+1 > 0 ? 1/sqrt(deg+1) : 0
__global__ void k_dinv(const float* __restrict__ deg, float* __restrict__ dinv) {
  int n = blockIdx.x * 256 + threadIdx.x;
  if (n >= N_NODES) return;
  float d = deg[n] + 1.0f;
  dinv[n] = d > 0.f ? 1.0f / sqrtf(d) : 0.f;
}

// ew[e] *= dinv[src]*dinv[tgt]  (in-place -> norm_e)
__global__ void k_norm_edge(float* __restrict__ ew, const int* __restrict__ src,
                            const int* __restrict__ tgt,
                            const float* __restrict__ dinv) {
  int e = blockIdx.x * 256 + threadIdx.x;
  if (e >= N_EDGES) return;
  ew[e] *= dinv[src[e]] * dinv[tgt[e]];
}

// graph segment starts: start[g] = lower_bound(batch, g); start[256] = N
__global__ void k_starts(const int* __restrict__ batch, int* __restrict__ start) {
  int g = blockIdx.x * blockDim.x + threadIdx.x;
  if (g > N_GRAPHS) return;
  int lo = 0, hi = N_NODES;
  while (lo < hi) {
    int mid = (lo + hi) >> 1;
    if (batch[mid] < g) lo = mid + 1; else hi = mid;
  }
  start[g] = lo;
}

// ---------------------------------------------------------------------------
// hw = h @ W   (h: [N, CIN], W: [CIN, 128] row-major (in,out))
// block: 256 thr = 4 nodes x 64 channels; blockIdx.y selects channel half.
// W half staged in LDS (CIN*64*4 B <= 32 KB).
// ---------------------------------------------------------------------------
template <int CIN>
__global__ __launch_bounds__(256) void k_hw(const float* __restrict__ h,
                                            const float* __restrict__ W,
                                            float* __restrict__ hw) {
  __shared__ float Ws[CIN * 64];
  __shared__ float hs[4][CIN];
  const int t = threadIdx.x;
  const int chalf = blockIdx.y;
  for (int i = t; i < CIN * 64; i += 256) {
    int k = i >> 6, cc = i & 63;
    Ws[i] = W[k * 128 + chalf * 64 + cc];
  }
  const int c = t & 63;
  const int p = t >> 6;  // 0..3
  const int base = blockIdx.x * 128;
  for (int it = 0; it < 32; ++it) {
    int n0 = base + it * 4;
    if (n0 >= N_NODES) break;
    __syncthreads();
    for (int i = t; i < 4 * CIN; i += 256) {
      int pp = i / CIN, k = i % CIN;
      int n = n0 + pp;
      hs[pp][k] = (n < N_NODES) ? h[(size_t)n * CIN + k] : 0.f;
    }
    __syncthreads();
    int n = n0 + p;
    if (n < N_NODES) {
      float acc = 0.f;
#pragma unroll 8
      for (int k = 0; k < CIN; ++k) acc += hs[p][k] * Ws[k * 64 + c];
      hw[(size_t)n * 128 + chalf * 64 + c] = acc;
    }
  }
}

// agg[n,c] = dinv[n]^2 * hw[n,c] + bias[c]   (self-loop + conv bias)
__global__ void k_agg_init(const float* __restrict__ hw,
                           const float* __restrict__ dinv,
                           const float* __restrict__ bias,
                           float* __restrict__ agg) {
  int i = blockIdx.x * 256 + threadIdx.x;
  if (i >= N_NODES * 128) return;
  int n = i >> 7, c = i & 127;
  float dv = dinv[n];
  agg[i] = dv * dv * hw[i] + bias[c];
}

// scatter: agg[tgt,c] += norm_e[e] * hw[src,c]
__global__ __launch_bounds__(256) void k_scatter(
    const float* __restrict__ ew, const int* __restrict__ src,
    const int* __restrict__ tgt, const float* __restrict__ hw,
    float* __restrict__ agg) {
  const int total = N_EDGES * 128;  // 204.8M < 2^31
  for (int i = blockIdx.x * 256 + threadIdx.x; i < total;
       i += gridDim.x * 256) {
    int e = i >> 7, c = i & 127;
    float w = ew[e];
    int s = src[e], d = tgt[e];
    atomicAdd(&agg[d * 128 + c], w * hw[s * 128 + c]);
  }
}

// ---------------------------------------------------------------------------
// GraphNorm (in-place) + ReLU. One block (512 thr) per graph; batch sorted.
// var = E[h^2] - ms*(2-ms)*mean^2
// ---------------------------------------------------------------------------
__global__ __launch_bounds__(512) void k_gnorm(float* __restrict__ h,
                                               const int* __restrict__ start,
                                               const float* __restrict__ gw,
                                               const float* __restrict__ gb,
                                               const float* __restrict__ gms) {
  int g = blockIdx.x;
  int s = start[g], e = start[g + 1];
  int t = threadIdx.x, p = t >> 7, c = t & 127;
  float sum = 0.f, sq = 0.f;
  for (int n = s + p; n < e; n += 4) {
    float v = h[(size_t)n * 128 + c];
    sum += v;
    sq += v * v;
  }
  __shared__ float S[4][128], Q[4][128], A[128], B[128];
  S[p][c] = sum;
  Q[p][c] = sq;
  __syncthreads();
  if (t < 128) {
    float cnt = (float)max(e - s, 1);
    float mean = (S[0][t] + S[1][t] + S[2][t] + S[3][t]) / cnt;
    float e2 = (Q[0][t] + Q[1][t] + Q[2][t] + Q[3][t]) / cnt;
    float ms = gms[t];
    float var = fmaxf(e2 - ms * (2.f - ms) * mean * mean, 0.f);
    float scale = gw[t] / sqrtf(var + EPS);
    A[t] = scale;
    B[t] = gb[t] - scale * ms * mean;
  }
  __syncthreads();
  for (int n = s + p; n < e; n += 4) {
    size_t idx = (size_t)n * 128 + c;
    h[idx] = fmaxf(A[c] * h[idx] + B[c], 0.f);
  }
}

// pooled[g,c] = mean over graph nodes
__global__ __launch_bounds__(512) void k_pool(const float* __restrict__ h,
                                              const int* __restrict__ start,
                                              float* __restrict__ pooled) {
  int g = blockIdx.x;
  int s = start[g], e = start[g + 1];
  int t = threadIdx.x, p = t >> 7, c = t & 127;
  float sum = 0.f;
  for (int n = s + p; n < e; n += 4) sum += h[(size_t)n * 128 + c];
  __shared__ float S[4][128];
  S[p][c] = sum;
  __syncthreads();
  if (t < 128) {
    float cnt = (float)max(e - s, 1);
    pooled[g * 128 + t] = (S[0][t] + S[1][t] + S[2][t] + S[3][t]) / cnt;
  }
}

// MLP head: 128 ->256 (BN,ReLU) ->128 (BN,ReLU) ->1; writes out[g] and h2.
__global__ __launch_bounds__(256) void k_head(
    const float* __restrict__ pooled, const float* __restrict__ w0,
    const float* __restrict__ b0, const float* __restrict__ g0,
    const float* __restrict__ bb0, const float* __restrict__ w1,
    const float* __restrict__ b1, const float* __restrict__ g1,
    const float* __restrict__ bb1, const float* __restrict__ ow,
    const float* __restrict__ ob, float* __restrict__ out) {
  __shared__ float p[128], h1[256], h2[128];
  int g = blockIdx.x, t = threadIdx.x;
  const float inv = 1.0f / sqrtf(1.0f + EPS);
  if (t < 128) p[t] = pooled[g * 128 + t];
  __syncthreads();
  {
    float acc = b0[t];
#pragma unroll 8
    for (int k = 0; k < 128; ++k) acc += p[k] * w0[k * 256 + t];
    h1[t] = fmaxf(acc * inv * g0[t] + bb0[t], 0.f);
  }
  __syncthreads();
  if (t < 128) {
    float acc = b1[t];
#pragma unroll 8
    for (int k = 0; k < 256; ++k) acc += h1[k] * w1[k * 128 + t];
    float v = fmaxf(acc * inv * g1[t] + bb1[t], 0.f);
    h2[t] = v;
    out[N_GRAPHS + g * 128 + t] = v;
  }
  __syncthreads();
  if (t < 64) {
    float v = h2[t] * ow[t] + h2[t + 64] * ow[t + 64];
#pragma unroll
    for (int off = 32; off; off >>= 1) v += __shfl_down(v, off);
    if (t == 0) out[g] = v + ob[0];
  }
}

// ---------------------------------------------------------------------------
extern "C" void kernel_launch(void* const* d_in, const int* in_sizes, int n_in,
                              void* d_out, int out_size, void* d_ws,
                              size_t ws_size, hipStream_t stream) {
  const float* x = (const float*)d_in[0];
  const float* edge_attr = (const float*)d_in[1];
  const float* em_w1 = (const float*)d_in[2];
  const float* em_b1 = (const float*)d_in[3];
  const float* em_w2 = (const float*)d_in[4];
  const float* em_b2 = (const float*)d_in[5];
  const float* conv_w[3] = {(const float*)d_in[6], (const float*)d_in[8],
                            (const float*)d_in[10]};
  const float* conv_b[3] = {(const float*)d_in[7], (const float*)d_in[9],
                            (const float*)d_in[11]};
  const float* gn_w[3] = {(const float*)d_in[12], (const float*)d_in[15],
                          (const float*)d_in[18]};
  const float* gn_b[3] = {(const float*)d_in[13], (const float*)d_in[16],
                          (const float*)d_in[19]};
  const float* gn_ms[3] = {(const float*)d_in[14], (const float*)d_in[17],
                           (const float*)d_in[20]};
  const float* lin_w0 = (const float*)d_in[21];
  const float* lin_b0 = (const float*)d_in[22];
  const float* bn_g0 = (const float*)d_in[23];
  const float* bn_b0 = (const float*)d_in[24];
  const float* lin_w1 = (const float*)d_in[25];
  const float* lin_b1 = (const float*)d_in[26];
  const float* bn_g1 = (const float*)d_in[27];
  const float* bn_b1 = (const float*)d_in[28];
  const float* out_w = (const float*)d_in[29];
  const float* out_b = (const float*)d_in[30];
  const int* edge_index = (const int*)d_in[31];
  const int* batch = (const int*)d_in[32];
  const int* src = edge_index;
  const int* tgt = edge_index + N_EDGES;

  // workspace carve-up
  char* w = (char*)d_ws;
  size_t off = 0;
  auto carve = [&](size_t bytes) {
    void* p = w + off;
    off = (off + bytes + 511) & ~(size_t)511;
    return p;
  };
  float* ew = (float*)carve((size_t)N_EDGES * 4);
  float* deg = (float*)carve((size_t)N_NODES * 4);
  float* dinv = (float*)carve((size_t)N_NODES * 4);
  int* start = (int*)carve((N_GRAPHS + 1) * 4);
  float* big0 = (float*)carve((size_t)N_NODES * 128 * 4);
  float* big1 = (float*)carve((size_t)N_NODES * 128 * 4);
  float* big2 = (float*)carve((size_t)N_NODES * 128 * 4);
  float* pooled = (float*)carve((size_t)N_GRAPHS * 128 * 4);

  hipMemsetAsync(deg, 0, (size_t)N_NODES * 4, stream);

  k_edge_mlp<<<(N_EDGES + 255) / 256, 256, 0, stream>>>(
      edge_attr, em_w1, em_b1, em_w2, em_b2, tgt, ew, deg);
  k_dinv<<<(N_NODES + 255) / 256, 256, 0, stream>>>(deg, dinv);
  k_norm_edge<<<(N_EDGES + 255) / 256, 256, 0, stream>>>(ew, src, tgt, dinv);
  k_starts<<<1, 512, 0, stream>>>(batch, start);

  // layer buffer rotation: hw always big0; agg: big1, big2, big1
  const float* h_in[3] = {x, big1, big2};
  float* agg[3] = {big1, big2, big1};

  for (int l = 0; l < 3; ++l) {
    dim3 gw_grid((N_NODES + 127) / 128, 2);
    if (l == 0)
      k_hw<64><<<gw_grid, 256, 0, stream>>>(h_in[l], conv_w[l], big0);
    else
      k_hw<128><<<gw_grid, 256, 0, stream>>>(h_in[l], conv_w[l], big0);
    k_agg_init<<<(N_NODES * 128 + 255) / 256, 256, 0, stream>>>(
        big0, dinv, conv_b[l], agg[l]);
    k_scatter<<<16384, 256, 0, stream>>>(ew, src, tgt, big0, agg[l]);
    k_gnorm<<<N_GRAPHS, 512, 0, stream>>>(agg[l], start, gn_w[l], gn_b[l],
                                          gn_ms[l]);
  }

  k_pool<<<N_GRAPHS, 512, 0, stream>>>(big1, start, pooled);
  k_head<<<N_GRAPHS, 256, 0, stream>>>(pooled, lin_w0, lin_b0, bn_g0, bn_b0,
                                       lin_w1, lin_b1, bn_g1, bn_b1, out_w,
                                       out_b, (float*)d_out);
}

// Round 2
// 1645.211 us; speedup vs baseline: 1.7121x; 1.7121x over previous
//
#include <hip/hip_runtime.h>

#define N_NODES 100000
#define N_EDGES 1600000
#define N_GRAPHS 256
#define EPS 1e-5f

// ---------------------------------------------------------------------------
// Edge MLP: ew[e] = Linear(16,1)(ReLU(Linear(8,16)(edge_attr[e])))
// fused with weighted-degree accumulation AND integer in-degree histogram.
// ---------------------------------------------------------------------------
__global__ __launch_bounds__(256) void k_edge_mlp(
    const float* __restrict__ ea, const float* __restrict__ w1,
    const float* __restrict__ b1, const float* __restrict__ w2,
    const float* __restrict__ b2, const int* __restrict__ tgt,
    float* __restrict__ ew, float* __restrict__ deg,
    int* __restrict__ rowcnt) {
  __shared__ float W1[128], B1[16], W2[16];
  int t = threadIdx.x;
  if (t < 128) W1[t] = w1[t];
  if (t < 16) { B1[t] = b1[t]; W2[t] = w2[t]; }
  __syncthreads();
  int e = blockIdx.x * 256 + t;
  if (e >= N_EDGES) return;
  const float4* ap = (const float4*)(ea + (size_t)e * 8);
  float4 a0 = ap[0], a1 = ap[1];
  float a[8] = {a0.x, a0.y, a0.z, a0.w, a1.x, a1.y, a1.z, a1.w};
  float out = b2[0];
#pragma unroll
  for (int i = 0; i < 16; ++i) {
    float h = B1[i];
#pragma unroll
    for (int j = 0; j < 8; ++j) h += a[j] * W1[i * 8 + j];
    out += fmaxf(h, 0.f) * W2[i];
  }
  ew[e] = out;
  int d = tgt[e];
  atomicAdd(&deg[d], out);
  atomicAdd(&rowcnt[d], 1);
}

// dinv[n] = deg+1 > 0 ? 1/sqrt(deg+1) : 0
__global__ void k_dinv(const float* __restrict__ deg, float* __restrict__ dinv) {
  int n = blockIdx.x * 256 + threadIdx.x;
  if (n >= N_NODES) return;
  float d = deg[n] + 1.0f;
  dinv[n] = d > 0.f ? 1.0f / sqrtf(d) : 0.f;
}

// ew[e] *= dinv[src]*dinv[tgt]  (in-place -> norm_e)
__global__ void k_norm_edge(float* __restrict__ ew, const int* __restrict__ src,
                            const int* __restrict__ tgt,
                            const float* __restrict__ dinv) {
  int e = blockIdx.x * 256 + threadIdx.x;
  if (e >= N_EDGES) return;
  ew[e] *= dinv[src[e]] * dinv[tgt[e]];
}

// Exclusive scan of rowcnt -> rowstart[0..N], cursor copy. One block, 1024 thr.
__global__ __launch_bounds__(1024) void k_scan(const int* __restrict__ cnt,
                                               int* __restrict__ rowstart,
                                               int* __restrict__ cursor) {
  __shared__ int sums[1024];
  const int t = threadIdx.x;
  const int CH = (N_NODES + 1023) / 1024;  // 98
  const int base = t * CH;
  int s = 0;
  for (int i = 0; i < CH; ++i) {
    int idx = base + i;
    if (idx < N_NODES) s += cnt[idx];
  }
  sums[t] = s;
  __syncthreads();
  // Hillis-Steele inclusive scan
  for (int off = 1; off < 1024; off <<= 1) {
    int v = (t >= off) ? sums[t - off] : 0;
    __syncthreads();
    sums[t] += v;
    __syncthreads();
  }
  int pre = (t == 0) ? 0 : sums[t - 1];
  for (int i = 0; i < CH; ++i) {
    int idx = base + i;
    if (idx < N_NODES) {
      rowstart[idx] = pre;
      cursor[idx] = pre;
      pre += cnt[idx];
    }
  }
  if (t == 1023) rowstart[N_NODES] = pre;
}

// Bucket edges by target: src_s / ew_s sorted by tgt (order within row free).
__global__ __launch_bounds__(256) void k_fill(
    const int* __restrict__ src, const int* __restrict__ tgt,
    const float* __restrict__ ew, int* __restrict__ cursor,
    int* __restrict__ src_s, float* __restrict__ ew_s) {
  int e = blockIdx.x * 256 + threadIdx.x;
  if (e >= N_EDGES) return;
  int p = atomicAdd(&cursor[tgt[e]], 1);
  src_s[p] = src[e];
  ew_s[p] = ew[e];
}

// graph segment starts: start[g] = lower_bound(batch, g); start[256] = N
__global__ void k_starts(const int* __restrict__ batch, int* __restrict__ start) {
  int g = blockIdx.x * blockDim.x + threadIdx.x;
  if (g > N_GRAPHS) return;
  int lo = 0, hi = N_NODES;
  while (lo < hi) {
    int mid = (lo + hi) >> 1;
    if (batch[mid] < g) lo = mid + 1; else hi = mid;
  }
  start[g] = lo;
}

// ---------------------------------------------------------------------------
// hw = h @ W   (h: [N, CIN], W: [CIN, 128] row-major (in,out))
// block: 256 thr = 4 nodes x 64 channels; blockIdx.y selects channel half.
// ---------------------------------------------------------------------------
template <int CIN>
__global__ __launch_bounds__(256) void k_hw(const float* __restrict__ h,
                                            const float* __restrict__ W,
                                            float* __restrict__ hw) {
  __shared__ float Ws[CIN * 64];
  __shared__ float hs[4][CIN];
  const int t = threadIdx.x;
  const int chalf = blockIdx.y;
  for (int i = t; i < CIN * 64; i += 256) {
    int k = i >> 6, cc = i & 63;
    Ws[i] = W[k * 128 + chalf * 64 + cc];
  }
  const int c = t & 63;
  const int p = t >> 6;  // 0..3
  const int base = blockIdx.x * 128;
  for (int it = 0; it < 32; ++it) {
    int n0 = base + it * 4;
    if (n0 >= N_NODES) break;
    __syncthreads();
    for (int i = t; i < 4 * CIN; i += 256) {
      int pp = i / CIN, k = i % CIN;
      int n = n0 + pp;
      hs[pp][k] = (n < N_NODES) ? h[(size_t)n * CIN + k] : 0.f;
    }
    __syncthreads();
    int n = n0 + p;
    if (n < N_NODES) {
      float acc = 0.f;
#pragma unroll 8
      for (int k = 0; k < CIN; ++k) acc += hs[p][k] * Ws[k * 64 + c];
      hw[(size_t)n * 128 + chalf * 64 + c] = acc;
    }
  }
}

// ---------------------------------------------------------------------------
// CSR gather aggregation (replaces scatter + agg_init):
// agg[n,c] = dinv[n]^2*hw[n,c] + bias[c] + sum_j ew_s[j]*hw[src_s[j],c]
// 256 thr = 2 nodes x 128 channels; 4 accumulators for load-latency hiding.
// ---------------------------------------------------------------------------
__global__ __launch_bounds__(256) void k_gather(
    const float* __restrict__ hw, const float* __restrict__ ew_s,
    const int* __restrict__ src_s, const int* __restrict__ rowstart,
    const float* __restrict__ dinv, const float* __restrict__ bias,
    float* __restrict__ agg) {
  const int t = threadIdx.x;
  const int n = blockIdx.x * 2 + (t >> 7);
  const int c = t & 127;
  if (n >= N_NODES) return;
  const int rs = rowstart[n], re = rowstart[n + 1];
  const float dv = dinv[n];
  float a0 = dv * dv * hw[(size_t)n * 128 + c] + bias[c];
  float a1 = 0.f, a2 = 0.f, a3 = 0.f;
  int j = rs;
  for (; j + 4 <= re; j += 4) {
    int s0 = src_s[j], s1 = src_s[j + 1], s2 = src_s[j + 2], s3 = src_s[j + 3];
    float w0 = ew_s[j], w1 = ew_s[j + 1], w2 = ew_s[j + 2], w3 = ew_s[j + 3];
    a0 += w0 * hw[(size_t)s0 * 128 + c];
    a1 += w1 * hw[(size_t)s1 * 128 + c];
    a2 += w2 * hw[(size_t)s2 * 128 + c];
    a3 += w3 * hw[(size_t)s3 * 128 + c];
  }
  for (; j < re; ++j) a0 += ew_s[j] * hw[(size_t)src_s[j] * 128 + c];
  agg[(size_t)n * 128 + c] = (a0 + a1) + (a2 + a3);
}

// ---------------------------------------------------------------------------
// GraphNorm (in-place) + ReLU. One block (512 thr) per graph; batch sorted.
// var = E[h^2] - ms*(2-ms)*mean^2
// ---------------------------------------------------------------------------
__global__ __launch_bounds__(512) void k_gnorm(float* __restrict__ h,
                                               const int* __restrict__ start,
                                               const float* __restrict__ gw,
                                               const float* __restrict__ gb,
                                               const float* __restrict__ gms) {
  int g = blockIdx.x;
  int s = start[g], e = start[g + 1];
  int t = threadIdx.x, p = t >> 7, c = t & 127;
  float sum = 0.f, sq = 0.f;
  for (int n = s + p; n < e; n += 4) {
    float v = h[(size_t)n * 128 + c];
    sum += v;
    sq += v * v;
  }
  __shared__ float S[4][128], Q[4][128], A[128], B[128];
  S[p][c] = sum;
  Q[p][c] = sq;
  __syncthreads();
  if (t < 128) {
    float cnt = (float)max(e - s, 1);
    float mean = (S[0][t] + S[1][t] + S[2][t] + S[3][t]) / cnt;
    float e2 = (Q[0][t] + Q[1][t] + Q[2][t] + Q[3][t]) / cnt;
    float ms = gms[t];
    float var = fmaxf(e2 - ms * (2.f - ms) * mean * mean, 0.f);
    float scale = gw[t] / sqrtf(var + EPS);
    A[t] = scale;
    B[t] = gb[t] - scale * ms * mean;
  }
  __syncthreads();
  for (int n = s + p; n < e; n += 4) {
    size_t idx = (size_t)n * 128 + c;
    h[idx] = fmaxf(A[c] * h[idx] + B[c], 0.f);
  }
}

// pooled[g,c] = mean over graph nodes
__global__ __launch_bounds__(512) void k_pool(const float* __restrict__ h,
                                              const int* __restrict__ start,
                                              float* __restrict__ pooled) {
  int g = blockIdx.x;
  int s = start[g], e = start[g + 1];
  int t = threadIdx.x, p = t >> 7, c = t & 127;
  float sum = 0.f;
  for (int n = s + p; n < e; n += 4) sum += h[(size_t)n * 128 + c];
  __shared__ float S[4][128];
  S[p][c] = sum;
  __syncthreads();
  if (t < 128) {
    float cnt = (float)max(e - s, 1);
    pooled[g * 128 + t] = (S[0][t] + S[1][t] + S[2][t] + S[3][t]) / cnt;
  }
}

// MLP head: 128 ->256 (BN,ReLU) ->128 (BN,ReLU) ->1; writes out[g] and h2.
__global__ __launch_bounds__(256) void k_head(
    const float* __restrict__ pooled, const float* __restrict__ w0,
    const float* __restrict__ b0, const float* __restrict__ g0,
    const float* __restrict__ bb0, const float* __restrict__ w1,
    const float* __restrict__ b1, const float* __restrict__ g1,
    const float* __restrict__ bb1, const float* __restrict__ ow,
    const float* __restrict__ ob, float* __restrict__ out) {
  __shared__ float p[128], h1[256], h2[128];
  int g = blockIdx.x, t = threadIdx.x;
  const float inv = 1.0f / sqrtf(1.0f + EPS);
  if (t < 128) p[t] = pooled[g * 128 + t];
  __syncthreads();
  {
    float acc = b0[t];
#pragma unroll 8
    for (int k = 0; k < 128; ++k) acc += p[k] * w0[k * 256 + t];
    h1[t] = fmaxf(acc * inv * g0[t] + bb0[t], 0.f);
  }
  __syncthreads();
  if (t < 128) {
    float acc = b1[t];
#pragma unroll 8
    for (int k = 0; k < 256; ++k) acc += h1[k] * w1[k * 128 + t];
    float v = fmaxf(acc * inv * g1[t] + bb1[t], 0.f);
    h2[t] = v;
    out[N_GRAPHS + g * 128 + t] = v;
  }
  __syncthreads();
  if (t < 64) {
    float v = h2[t] * ow[t] + h2[t + 64] * ow[t + 64];
#pragma unroll
    for (int off = 32; off; off >>= 1) v += __shfl_down(v, off);
    if (t == 0) out[g] = v + ob[0];
  }
}

// ---------------------------------------------------------------------------
extern "C" void kernel_launch(void* const* d_in, const int* in_sizes, int n_in,
                              void* d_out, int out_size, void* d_ws,
                              size_t ws_size, hipStream_t stream) {
  const float* x = (const float*)d_in[0];
  const float* edge_attr = (const float*)d_in[1];
  const float* em_w1 = (const float*)d_in[2];
  const float* em_b1 = (const float*)d_in[3];
  const float* em_w2 = (const float*)d_in[4];
  const float* em_b2 = (const float*)d_in[5];
  const float* conv_w[3] = {(const float*)d_in[6], (const float*)d_in[8],
                            (const float*)d_in[10]};
  const float* conv_b[3] = {(const float*)d_in[7], (const float*)d_in[9],
                            (const float*)d_in[11]};
  const float* gn_w[3] = {(const float*)d_in[12], (const float*)d_in[15],
                          (const float*)d_in[18]};
  const float* gn_b[3] = {(const float*)d_in[13], (const float*)d_in[16],
                          (const float*)d_in[19]};
  const float* gn_ms[3] = {(const float*)d_in[14], (const float*)d_in[17],
                           (const float*)d_in[20]};
  const float* lin_w0 = (const float*)d_in[21];
  const float* lin_b0 = (const float*)d_in[22];
  const float* bn_g0 = (const float*)d_in[23];
  const float* bn_b0 = (const float*)d_in[24];
  const float* lin_w1 = (const float*)d_in[25];
  const float* lin_b1 = (const float*)d_in[26];
  const float* bn_g1 = (const float*)d_in[27];
  const float* bn_b1 = (const float*)d_in[28];
  const float* out_w = (const float*)d_in[29];
  const float* out_b = (const float*)d_in[30];
  const int* edge_index = (const int*)d_in[31];
  const int* batch = (const int*)d_in[32];
  const int* src = edge_index;
  const int* tgt = edge_index + N_EDGES;

  // workspace carve-up
  char* w = (char*)d_ws;
  size_t off = 0;
  auto carve = [&](size_t bytes) {
    void* p = w + off;
    off = (off + bytes + 511) & ~(size_t)511;
    return p;
  };
  float* ew = (float*)carve((size_t)N_EDGES * 4);
  float* deg = (float*)carve((size_t)N_NODES * 4);
  float* dinv = (float*)carve((size_t)N_NODES * 4);
  int* rowcnt = (int*)carve((size_t)N_NODES * 4);
  int* rowstart = (int*)carve((size_t)(N_NODES + 1) * 4);
  int* cursor = (int*)carve((size_t)N_NODES * 4);
  int* src_s = (int*)carve((size_t)N_EDGES * 4);
  float* ew_s = (float*)carve((size_t)N_EDGES * 4);
  int* start = (int*)carve((N_GRAPHS + 1) * 4);
  float* big0 = (float*)carve((size_t)N_NODES * 128 * 4);
  float* big1 = (float*)carve((size_t)N_NODES * 128 * 4);
  float* big2 = (float*)carve((size_t)N_NODES * 128 * 4);
  float* pooled = (float*)carve((size_t)N_GRAPHS * 128 * 4);

  hipMemsetAsync(deg, 0, (size_t)N_NODES * 4, stream);
  hipMemsetAsync(rowcnt, 0, (size_t)N_NODES * 4, stream);

  k_edge_mlp<<<(N_EDGES + 255) / 256, 256, 0, stream>>>(
      edge_attr, em_w1, em_b1, em_w2, em_b2, tgt, ew, deg, rowcnt);
  k_dinv<<<(N_NODES + 255) / 256, 256, 0, stream>>>(deg, dinv);
  k_norm_edge<<<(N_EDGES + 255) / 256, 256, 0, stream>>>(ew, src, tgt, dinv);
  k_scan<<<1, 1024, 0, stream>>>(rowcnt, rowstart, cursor);
  k_fill<<<(N_EDGES + 255) / 256, 256, 0, stream>>>(src, tgt, ew, cursor,
                                                    src_s, ew_s);
  k_starts<<<1, 512, 0, stream>>>(batch, start);

  // layer buffer rotation: hw always big0; agg ping-pong big1/big2
  const float* h_in[3] = {x, big1, big2};
  float* agg[3] = {big1, big2, big1};

  for (int l = 0; l < 3; ++l) {
    dim3 gw_grid((N_NODES + 127) / 128, 2);
    if (l == 0)
      k_hw<64><<<gw_grid, 256, 0, stream>>>(h_in[l], conv_w[l], big0);
    else
      k_hw<128><<<gw_grid, 256, 0, stream>>>(h_in[l], conv_w[l], big0);
    k_gather<<<(N_NODES + 1) / 2, 256, 0, stream>>>(
        big0, ew_s, src_s, rowstart, dinv, conv_b[l], agg[l]);
    k_gnorm<<<N_GRAPHS, 512, 0, stream>>>(agg[l], start, gn_w[l], gn_b[l],
                                          gn_ms[l]);
  }

  k_pool<<<N_GRAPHS, 512, 0, stream>>>(big1, start, pooled);
  k_head<<<N_GRAPHS, 256, 0, stream>>>(pooled, lin_w0, lin_b0, bn_g0, bn_b0,
                                       lin_w1, lin_b1, bn_g1, bn_b1, out_w,
                                       out_b, (float*)d_out);
}

// Round 3
// 1191.728 us; speedup vs baseline: 2.3636x; 1.3805x over previous
//
#include <hip/hip_runtime.h>

#define N_NODES 100000
#define N_EDGES 1600000
#define N_GRAPHS 256
#define EPS 1e-5f

#define SCAN_BLOCKS ((N_NODES + 255) / 256)  // 391

// ---------------------------------------------------------------------------
// Edge MLP: ew[e] = Linear(16,1)(ReLU(Linear(8,16)(edge_attr[e])))
// fused with weighted-degree accumulation AND integer in-degree histogram.
// ---------------------------------------------------------------------------
__global__ __launch_bounds__(256) void k_edge_mlp(
    const float* __restrict__ ea, const float* __restrict__ w1,
    const float* __restrict__ b1, const float* __restrict__ w2,
    const float* __restrict__ b2, const int* __restrict__ tgt,
    float* __restrict__ ew, float* __restrict__ deg,
    int* __restrict__ rowcnt) {
  __shared__ float W1[128], B1[16], W2[16];
  int t = threadIdx.x;
  if (t < 128) W1[t] = w1[t];
  if (t < 16) { B1[t] = b1[t]; W2[t] = w2[t]; }
  __syncthreads();
  int e = blockIdx.x * 256 + t;
  if (e >= N_EDGES) return;
  const float4* ap = (const float4*)(ea + (size_t)e * 8);
  float4 a0 = ap[0], a1 = ap[1];
  float a[8] = {a0.x, a0.y, a0.z, a0.w, a1.x, a1.y, a1.z, a1.w};
  float out = b2[0];
#pragma unroll
  for (int i = 0; i < 16; ++i) {
    float h = B1[i];
#pragma unroll
    for (int j = 0; j < 8; ++j) h += a[j] * W1[i * 8 + j];
    out += fmaxf(h, 0.f) * W2[i];
  }
  ew[e] = out;
  int d = tgt[e];
  atomicAdd(&deg[d], out);
  atomicAdd(&rowcnt[d], 1);
}

// dinv[n] = deg+1 > 0 ? 1/sqrt(deg+1) : 0
__global__ void k_dinv(const float* __restrict__ deg, float* __restrict__ dinv) {
  int n = blockIdx.x * 256 + threadIdx.x;
  if (n >= N_NODES) return;
  float d = deg[n] + 1.0f;
  dinv[n] = d > 0.f ? 1.0f / sqrtf(d) : 0.f;
}

// ew[e] *= dinv[src]*dinv[tgt]  (in-place -> norm_e)
__global__ void k_norm_edge(float* __restrict__ ew, const int* __restrict__ src,
                            const int* __restrict__ tgt,
                            const float* __restrict__ dinv) {
  int e = blockIdx.x * 256 + threadIdx.x;
  if (e >= N_EDGES) return;
  ew[e] *= dinv[src[e]] * dinv[tgt[e]];
}

// ---------------------------------------------------------------------------
// Parallel 3-phase exclusive scan of rowcnt -> rowstart[0..N], cursor copy
// ---------------------------------------------------------------------------
__global__ __launch_bounds__(256) void k_scan1(const int* __restrict__ cnt,
                                               int* __restrict__ bsum) {
  int i = blockIdx.x * 256 + threadIdx.x;
  int v = (i < N_NODES) ? cnt[i] : 0;
#pragma unroll
  for (int off = 32; off; off >>= 1) v += __shfl_down(v, off);
  __shared__ int ws[4];
  if ((threadIdx.x & 63) == 0) ws[threadIdx.x >> 6] = v;
  __syncthreads();
  if (threadIdx.x == 0) bsum[blockIdx.x] = ws[0] + ws[1] + ws[2] + ws[3];
}

__global__ __launch_bounds__(512) void k_scan2(const int* __restrict__ bsum,
                                               int* __restrict__ boff) {
  __shared__ int s[512];
  int t = threadIdx.x;
  s[t] = (t < SCAN_BLOCKS) ? bsum[t] : 0;
  __syncthreads();
  for (int off = 1; off < 512; off <<= 1) {
    int u = (t >= off) ? s[t - off] : 0;
    __syncthreads();
    s[t] += u;
    __syncthreads();
  }
  boff[t] = (t == 0) ? 0 : s[t - 1];
}

__global__ __launch_bounds__(256) void k_scan3(const int* __restrict__ cnt,
                                               const int* __restrict__ boff,
                                               int* __restrict__ rowstart,
                                               int* __restrict__ cursor) {
  __shared__ int s[256];
  int t = threadIdx.x;
  int i = blockIdx.x * 256 + t;
  int v = (i < N_NODES) ? cnt[i] : 0;
  s[t] = v;
  __syncthreads();
  for (int off = 1; off < 256; off <<= 1) {
    int u = (t >= off) ? s[t - off] : 0;
    __syncthreads();
    s[t] += u;
    __syncthreads();
  }
  if (i < N_NODES) {
    int pre = boff[blockIdx.x] + s[t] - v;  // exclusive
    rowstart[i] = pre;
    cursor[i] = pre;
    if (i == N_NODES - 1) rowstart[N_NODES] = pre + v;
  }
}

// Bucket edges by target: src_s / ew_s sorted by tgt (order within row free).
__global__ __launch_bounds__(256) void k_fill(
    const int* __restrict__ src, const int* __restrict__ tgt,
    const float* __restrict__ ew, int* __restrict__ cursor,
    int* __restrict__ src_s, float* __restrict__ ew_s) {
  int e = blockIdx.x * 256 + threadIdx.x;
  if (e >= N_EDGES) return;
  int p = atomicAdd(&cursor[tgt[e]], 1);
  src_s[p] = src[e];
  ew_s[p] = ew[e];
}

// graph segment starts: start[g] = lower_bound(batch, g); start[256] = N
__global__ void k_starts(const int* __restrict__ batch, int* __restrict__ start) {
  int g = blockIdx.x * blockDim.x + threadIdx.x;
  if (g > N_GRAPHS) return;
  int lo = 0, hi = N_NODES;
  while (lo < hi) {
    int mid = (lo + hi) >> 1;
    if (batch[mid] < g) lo = mid + 1; else hi = mid;
  }
  start[g] = lo;
}

// ---------------------------------------------------------------------------
// hw = h @ W   (h: [N, CIN], W: [CIN, 128] row-major (in,out))
// 256 thr = 8 node-slots x 32 lanes; each lane computes 2 adjacent channels
// (float2) of one 64-channel half (blockIdx.y). W half staged in LDS (<=32KB),
// read as ds_read_b64. 64 nodes per block.
// ---------------------------------------------------------------------------
template <int CIN>
__global__ __launch_bounds__(256) void k_hw(const float* __restrict__ h,
                                            const float* __restrict__ W,
                                            float* __restrict__ hw) {
  __shared__ float Ws[CIN * 64];
  __shared__ float hs[8][CIN];
  const int t = threadIdx.x;
  const int chalf = blockIdx.y;
  // stage W half: row k -> Ws[k*64 .. +63]
  for (int i = t; i < CIN * 16; i += 256) {
    int k = i >> 4, c4 = i & 15;
    ((float4*)&Ws[k * 64])[c4] = ((const float4*)&W[k * 128 + chalf * 64])[c4];
  }
  const int cl = t & 31;
  const int nslot = t >> 5;  // 0..7
  const int base = blockIdx.x * 64;
  for (int it = 0; it < 8; ++it) {
    int n0 = base + it * 8;
    if (n0 >= N_NODES) break;
    __syncthreads();
    for (int i = t; i < 2 * CIN; i += 256) {  // 8*CIN floats as float4
      int pp = i / (CIN / 4), k4 = i % (CIN / 4);
      int n = n0 + pp;
      ((float4*)hs[pp])[k4] =
          (n < N_NODES) ? ((const float4*)&h[(size_t)n * CIN])[k4]
                        : make_float4(0.f, 0.f, 0.f, 0.f);
    }
    __syncthreads();
    int n = n0 + nslot;
    if (n < N_NODES) {
      float2 acc = make_float2(0.f, 0.f);
#pragma unroll 8
      for (int k = 0; k < CIN; ++k) {
        float hv = hs[nslot][k];
        float2 wv = ((const float2*)&Ws[k * 64])[cl];
        acc.x += hv * wv.x;
        acc.y += hv * wv.y;
      }
      ((float2*)&hw[(size_t)n * 128 + chalf * 64])[cl] = acc;
    }
  }
}

// ---------------------------------------------------------------------------
// CSR gather aggregation: one wave per node, lane = 2 channels (float2).
// agg[n,c] = dinv[n]^2*hw[n,c] + bias[c] + sum_j ew_s[j]*hw[src_s[j],c]
// ---------------------------------------------------------------------------
__global__ __launch_bounds__(256) void k_gather(
    const float* __restrict__ hw, const float* __restrict__ ew_s,
    const int* __restrict__ src_s, const int* __restrict__ rowstart,
    const float* __restrict__ dinv, const float* __restrict__ bias,
    float* __restrict__ agg) {
  const int lane = threadIdx.x & 63;
  const int n = blockIdx.x * 4 + (threadIdx.x >> 6);
  if (n >= N_NODES) return;
  const int rs = rowstart[n], re = rowstart[n + 1];
  const float dv = dinv[n];
  const float2* hw2 = (const float2*)hw;
  float2 hv = hw2[(size_t)n * 64 + lane];
  float2 bv = ((const float2*)bias)[lane];
  float2 a0 = make_float2(dv * dv * hv.x + bv.x, dv * dv * hv.y + bv.y);
  float2 a1 = make_float2(0.f, 0.f), a2 = make_float2(0.f, 0.f),
         a3 = make_float2(0.f, 0.f);
  int j = rs;
  for (; j + 4 <= re; j += 4) {
    int s0 = src_s[j], s1 = src_s[j + 1], s2 = src_s[j + 2], s3 = src_s[j + 3];
    float w0 = ew_s[j], w1 = ew_s[j + 1], w2 = ew_s[j + 2], w3 = ew_s[j + 3];
    float2 v0 = hw2[(size_t)s0 * 64 + lane];
    float2 v1 = hw2[(size_t)s1 * 64 + lane];
    float2 v2 = hw2[(size_t)s2 * 64 + lane];
    float2 v3 = hw2[(size_t)s3 * 64 + lane];
    a0.x += w0 * v0.x; a0.y += w0 * v0.y;
    a1.x += w1 * v1.x; a1.y += w1 * v1.y;
    a2.x += w2 * v2.x; a2.y += w2 * v2.y;
    a3.x += w3 * v3.x; a3.y += w3 * v3.y;
  }
  for (; j < re; ++j) {
    float w = ew_s[j];
    float2 v = hw2[(size_t)src_s[j] * 64 + lane];
    a0.x += w * v.x; a0.y += w * v.y;
  }
  float2 r = make_float2((a0.x + a1.x) + (a2.x + a3.x),
                         (a0.y + a1.y) + (a2.y + a3.y));
  ((float2*)agg)[(size_t)n * 64 + lane] = r;
}

// ---------------------------------------------------------------------------
// GraphNorm (in-place) + ReLU. One block (512 thr) per graph; batch sorted.
// var = E[h^2] - ms*(2-ms)*mean^2
// ---------------------------------------------------------------------------
__global__ __launch_bounds__(512) void k_gnorm(float* __restrict__ h,
                                               const int* __restrict__ start,
                                               const float* __restrict__ gw,
                                               const float* __restrict__ gb,
                                               const float* __restrict__ gms) {
  int g = blockIdx.x;
  int s = start[g], e = start[g + 1];
  int t = threadIdx.x, p = t >> 7, c = t & 127;
  float sum = 0.f, sq = 0.f;
  for (int n = s + p; n < e; n += 4) {
    float v = h[(size_t)n * 128 + c];
    sum += v;
    sq += v * v;
  }
  __shared__ float S[4][128], Q[4][128], A[128], B[128];
  S[p][c] = sum;
  Q[p][c] = sq;
  __syncthreads();
  if (t < 128) {
    float cnt = (float)max(e - s, 1);
    float mean = (S[0][t] + S[1][t] + S[2][t] + S[3][t]) / cnt;
    float e2 = (Q[0][t] + Q[1][t] + Q[2][t] + Q[3][t]) / cnt;
    float ms = gms[t];
    float var = fmaxf(e2 - ms * (2.f - ms) * mean * mean, 0.f);
    float scale = gw[t] / sqrtf(var + EPS);
    A[t] = scale;
    B[t] = gb[t] - scale * ms * mean;
  }
  __syncthreads();
  for (int n = s + p; n < e; n += 4) {
    size_t idx = (size_t)n * 128 + c;
    h[idx] = fmaxf(A[c] * h[idx] + B[c], 0.f);
  }
}

// pooled[g,c] = mean over graph nodes
__global__ __launch_bounds__(512) void k_pool(const float* __restrict__ h,
                                              const int* __restrict__ start,
                                              float* __restrict__ pooled) {
  int g = blockIdx.x;
  int s = start[g], e = start[g + 1];
  int t = threadIdx.x, p = t >> 7, c = t & 127;
  float sum = 0.f;
  for (int n = s + p; n < e; n += 4) sum += h[(size_t)n * 128 + c];
  __shared__ float S[4][128];
  S[p][c] = sum;
  __syncthreads();
  if (t < 128) {
    float cnt = (float)max(e - s, 1);
    pooled[g * 128 + t] = (S[0][t] + S[1][t] + S[2][t] + S[3][t]) / cnt;
  }
}

// MLP head: 128 ->256 (BN,ReLU) ->128 (BN,ReLU) ->1; writes out[g] and h2.
__global__ __launch_bounds__(256) void k_head(
    const float* __restrict__ pooled, const float* __restrict__ w0,
    const float* __restrict__ b0, const float* __restrict__ g0,
    const float* __restrict__ bb0, const float* __restrict__ w1,
    const float* __restrict__ b1, const float* __restrict__ g1,
    const float* __restrict__ bb1, const float* __restrict__ ow,
    const float* __restrict__ ob, float* __restrict__ out) {
  __shared__ float p[128], h1[256], h2[128];
  int g = blockIdx.x, t = threadIdx.x;
  const float inv = 1.0f / sqrtf(1.0f + EPS);
  if (t < 128) p[t] = pooled[g * 128 + t];
  __syncthreads();
  {
    float acc = b0[t];
#pragma unroll 8
    for (int k = 0; k < 128; ++k) acc += p[k] * w0[k * 256 + t];
    h1[t] = fmaxf(acc * inv * g0[t] + bb0[t], 0.f);
  }
  __syncthreads();
  if (t < 128) {
    float acc = b1[t];
#pragma unroll 8
    for (int k = 0; k < 256; ++k) acc += h1[k] * w1[k * 128 + t];
    float v = fmaxf(acc * inv * g1[t] + bb1[t], 0.f);
    h2[t] = v;
    out[N_GRAPHS + g * 128 + t] = v;
  }
  __syncthreads();
  if (t < 64) {
    float v = h2[t] * ow[t] + h2[t + 64] * ow[t + 64];
#pragma unroll
    for (int off = 32; off; off >>= 1) v += __shfl_down(v, off);
    if (t == 0) out[g] = v + ob[0];
  }
}

// ---------------------------------------------------------------------------
extern "C" void kernel_launch(void* const* d_in, const int* in_sizes, int n_in,
                              void* d_out, int out_size, void* d_ws,
                              size_t ws_size, hipStream_t stream) {
  const float* x = (const float*)d_in[0];
  const float* edge_attr = (const float*)d_in[1];
  const float* em_w1 = (const float*)d_in[2];
  const float* em_b1 = (const float*)d_in[3];
  const float* em_w2 = (const float*)d_in[4];
  const float* em_b2 = (const float*)d_in[5];
  const float* conv_w[3] = {(const float*)d_in[6], (const float*)d_in[8],
                            (const float*)d_in[10]};
  const float* conv_b[3] = {(const float*)d_in[7], (const float*)d_in[9],
                            (const float*)d_in[11]};
  const float* gn_w[3] = {(const float*)d_in[12], (const float*)d_in[15],
                          (const float*)d_in[18]};
  const float* gn_b[3] = {(const float*)d_in[13], (const float*)d_in[16],
                          (const float*)d_in[19]};
  const float* gn_ms[3] = {(const float*)d_in[14], (const float*)d_in[17],
                           (const float*)d_in[20]};
  const float* lin_w0 = (const float*)d_in[21];
  const float* lin_b0 = (const float*)d_in[22];
  const float* bn_g0 = (const float*)d_in[23];
  const float* bn_b0 = (const float*)d_in[24];
  const float* lin_w1 = (const float*)d_in[25];
  const float* lin_b1 = (const float*)d_in[26];
  const float* bn_g1 = (const float*)d_in[27];
  const float* bn_b1 = (const float*)d_in[28];
  const float* out_w = (const float*)d_in[29];
  const float* out_b = (const float*)d_in[30];
  const int* edge_index = (const int*)d_in[31];
  const int* batch = (const int*)d_in[32];
  const int* src = edge_index;
  const int* tgt = edge_index + N_EDGES;

  // workspace carve-up
  char* w = (char*)d_ws;
  size_t off = 0;
  auto carve = [&](size_t bytes) {
    void* p = w + off;
    off = (off + bytes + 511) & ~(size_t)511;
    return p;
  };
  float* ew = (float*)carve((size_t)N_EDGES * 4);
  float* deg = (float*)carve((size_t)N_NODES * 4);
  float* dinv = (float*)carve((size_t)N_NODES * 4);
  int* rowcnt = (int*)carve((size_t)N_NODES * 4);
  int* rowstart = (int*)carve((size_t)(N_NODES + 1) * 4);
  int* cursor = (int*)carve((size_t)N_NODES * 4);
  int* bsum = (int*)carve((size_t)SCAN_BLOCKS * 4);
  int* boff = (int*)carve((size_t)512 * 4);
  int* src_s = (int*)carve((size_t)N_EDGES * 4);
  float* ew_s = (float*)carve((size_t)N_EDGES * 4);
  int* start = (int*)carve((N_GRAPHS + 1) * 4);
  float* big0 = (float*)carve((size_t)N_NODES * 128 * 4);
  float* big1 = (float*)carve((size_t)N_NODES * 128 * 4);
  float* big2 = (float*)carve((size_t)N_NODES * 128 * 4);
  float* pooled = (float*)carve((size_t)N_GRAPHS * 128 * 4);

  hipMemsetAsync(deg, 0, (size_t)N_NODES * 4, stream);
  hipMemsetAsync(rowcnt, 0, (size_t)N_NODES * 4, stream);

  k_edge_mlp<<<(N_EDGES + 255) / 256, 256, 0, stream>>>(
      edge_attr, em_w1, em_b1, em_w2, em_b2, tgt, ew, deg, rowcnt);
  k_dinv<<<(N_NODES + 255) / 256, 256, 0, stream>>>(deg, dinv);
  k_norm_edge<<<(N_EDGES + 255) / 256, 256, 0, stream>>>(ew, src, tgt, dinv);
  k_scan1<<<SCAN_BLOCKS, 256, 0, stream>>>(rowcnt, bsum);
  k_scan2<<<1, 512, 0, stream>>>(bsum, boff);
  k_scan3<<<SCAN_BLOCKS, 256, 0, stream>>>(rowcnt, boff, rowstart, cursor);
  k_fill<<<(N_EDGES + 255) / 256, 256, 0, stream>>>(src, tgt, ew, cursor,
                                                    src_s, ew_s);
  k_starts<<<1, 512, 0, stream>>>(batch, start);

  // layer buffer rotation: hw always big0; agg ping-pong big1/big2
  const float* h_in[3] = {x, big1, big2};
  float* agg[3] = {big1, big2, big1};

  for (int l = 0; l < 3; ++l) {
    dim3 gw_grid((N_NODES + 63) / 64, 2);
    if (l == 0)
      k_hw<64><<<gw_grid, 256, 0, stream>>>(h_in[l], conv_w[l], big0);
    else
      k_hw<128><<<gw_grid, 256, 0, stream>>>(h_in[l], conv_w[l], big0);
    k_gather<<<(N_NODES + 3) / 4, 256, 0, stream>>>(
        big0, ew_s, src_s, rowstart, dinv, conv_b[l], agg[l]);
    k_gnorm<<<N_GRAPHS, 512, 0, stream>>>(agg[l], start, gn_w[l], gn_b[l],
                                          gn_ms[l]);
  }

  k_pool<<<N_GRAPHS, 512, 0, stream>>>(big1, start, pooled);
  k_head<<<N_GRAPHS, 256, 0, stream>>>(pooled, lin_w0, lin_b0, bn_g0, bn_b0,
                                       lin_w1, lin_b1, bn_g1, bn_b1, out_w,
                                       out_b, (float*)d_out);
}

// Round 4
// 1058.500 us; speedup vs baseline: 2.6611x; 1.1259x over previous
//
#include <hip/hip_runtime.h>

#define N_NODES 100000
#define N_EDGES 1600000
#define N_GRAPHS 256
#define EPS 1e-5f

#define SCAN_BLOCKS ((N_NODES + 255) / 256)  // 391

__device__ __forceinline__ void fma4(float4& a, float s, const float4& w) {
  a.x += s * w.x; a.y += s * w.y; a.z += s * w.z; a.w += s * w.w;
}

// ---------------------------------------------------------------------------
// Edge MLP: ew[e] = Linear(16,1)(ReLU(Linear(8,16)(edge_attr[e])))
// + within-row rank via rowcnt histogram (the ONLY atomic pass).
// ---------------------------------------------------------------------------
__global__ __launch_bounds__(256) void k_edge_mlp(
    const float* __restrict__ ea, const float* __restrict__ w1,
    const float* __restrict__ b1, const float* __restrict__ w2,
    const float* __restrict__ b2, const int* __restrict__ tgt,
    float* __restrict__ ew, int* __restrict__ rowcnt,
    int* __restrict__ rank) {
  __shared__ float W1[128], B1[16], W2[16];
  int t = threadIdx.x;
  if (t < 128) W1[t] = w1[t];
  if (t < 16) { B1[t] = b1[t]; W2[t] = w2[t]; }
  __syncthreads();
  int e = blockIdx.x * 256 + t;
  if (e >= N_EDGES) return;
  const float4* ap = (const float4*)(ea + (size_t)e * 8);
  float4 a0 = ap[0], a1 = ap[1];
  float a[8] = {a0.x, a0.y, a0.z, a0.w, a1.x, a1.y, a1.z, a1.w};
  float out = b2[0];
#pragma unroll
  for (int i = 0; i < 16; ++i) {
    float h = B1[i];
#pragma unroll
    for (int j = 0; j < 8; ++j) h += a[j] * W1[i * 8 + j];
    out += fmaxf(h, 0.f) * W2[i];
  }
  ew[e] = out;
  rank[e] = atomicAdd(&rowcnt[tgt[e]], 1);
}

// ---------------------------------------------------------------------------
// Parallel 3-phase exclusive scan of rowcnt -> rowstart[0..N]
// ---------------------------------------------------------------------------
__global__ __launch_bounds__(256) void k_scan1(const int* __restrict__ cnt,
                                               int* __restrict__ bsum) {
  int i = blockIdx.x * 256 + threadIdx.x;
  int v = (i < N_NODES) ? cnt[i] : 0;
#pragma unroll
  for (int off = 32; off; off >>= 1) v += __shfl_down(v, off);
  __shared__ int ws[4];
  if ((threadIdx.x & 63) == 0) ws[threadIdx.x >> 6] = v;
  __syncthreads();
  if (threadIdx.x == 0) bsum[blockIdx.x] = ws[0] + ws[1] + ws[2] + ws[3];
}

__global__ __launch_bounds__(512) void k_scan2(const int* __restrict__ bsum,
                                               int* __restrict__ boff) {
  __shared__ int s[512];
  int t = threadIdx.x;
  s[t] = (t < SCAN_BLOCKS) ? bsum[t] : 0;
  __syncthreads();
  for (int off = 1; off < 512; off <<= 1) {
    int u = (t >= off) ? s[t - off] : 0;
    __syncthreads();
    s[t] += u;
    __syncthreads();
  }
  boff[t] = (t == 0) ? 0 : s[t - 1];
}

__global__ __launch_bounds__(256) void k_scan3(const int* __restrict__ cnt,
                                               const int* __restrict__ boff,
                                               int* __restrict__ rowstart) {
  __shared__ int s[256];
  int t = threadIdx.x;
  int i = blockIdx.x * 256 + t;
  int v = (i < N_NODES) ? cnt[i] : 0;
  s[t] = v;
  __syncthreads();
  for (int off = 1; off < 256; off <<= 1) {
    int u = (t >= off) ? s[t - off] : 0;
    __syncthreads();
    s[t] += u;
    __syncthreads();
  }
  if (i < N_NODES) {
    int pre = boff[blockIdx.x] + s[t] - v;  // exclusive
    rowstart[i] = pre;
    if (i == N_NODES - 1) rowstart[N_NODES] = pre + v;
  }
}

// Atomic-free CSR fill: slot = rowstart[tgt] + rank (unique by construction).
__global__ __launch_bounds__(256) void k_fill(
    const int* __restrict__ src, const int* __restrict__ tgt,
    const float* __restrict__ ew, const int* __restrict__ rank,
    const int* __restrict__ rowstart, int* __restrict__ src_s,
    float* __restrict__ ew_s) {
  int e = blockIdx.x * 256 + threadIdx.x;
  if (e >= N_EDGES) return;
  int p = rowstart[tgt[e]] + rank[e];
  src_s[p] = src[e];
  ew_s[p] = ew[e];
}

// deg row-sum (atomic-free) fused with dinv: dinv[n] = rsqrt(1 + sum ew_row)
__global__ __launch_bounds__(256) void k_deg(const float* __restrict__ ew_s,
                                             const int* __restrict__ rowstart,
                                             float* __restrict__ dinv) {
  int n = blockIdx.x * 256 + threadIdx.x;
  if (n >= N_NODES) return;
  int rs = rowstart[n], re = rowstart[n + 1];
  float d = 1.f;
  for (int j = rs; j < re; ++j) d += ew_s[j];
  dinv[n] = d > 0.f ? rsqrtf(d) : 0.f;
}

// ew_s[j] *= dinv[src_s[j]] * dinv[row]; wave per node.
__global__ __launch_bounds__(256) void k_scale(float* __restrict__ ew_s,
                                               const int* __restrict__ src_s,
                                               const int* __restrict__ rowstart,
                                               const float* __restrict__ dinv) {
  int n = blockIdx.x * 4 + (threadIdx.x >> 6);
  if (n >= N_NODES) return;
  int lane = threadIdx.x & 63;
  int rs = rowstart[n], re = rowstart[n + 1];
  float dv = dinv[n];
  for (int j = rs + lane; j < re; j += 64) ew_s[j] *= dinv[src_s[j]] * dv;
}

// graph segment starts: start[g] = lower_bound(batch, g); start[256] = N
__global__ void k_starts(const int* __restrict__ batch, int* __restrict__ start) {
  int g = blockIdx.x * blockDim.x + threadIdx.x;
  if (g > N_GRAPHS) return;
  int lo = 0, hi = N_NODES;
  while (lo < hi) {
    int mid = (lo + hi) >> 1;
    if (batch[mid] < g) lo = mid + 1; else hi = mid;
  }
  start[g] = lo;
}

// ---------------------------------------------------------------------------
// hw = h @ W   (h: [N, CIN], W: [CIN, 128] row-major (in,out))
// 256 thr = 8 node-slots x 32 lanes; lane computes 2 adjacent channels
// of one 64-channel half (blockIdx.y). W half in LDS.
// ---------------------------------------------------------------------------
template <int CIN>
__global__ __launch_bounds__(256) void k_hw(const float* __restrict__ h,
                                            const float* __restrict__ W,
                                            float* __restrict__ hw) {
  __shared__ float Ws[CIN * 64];
  __shared__ float hs[8][CIN];
  const int t = threadIdx.x;
  const int chalf = blockIdx.y;
  for (int i = t; i < CIN * 16; i += 256) {
    int k = i >> 4, c4 = i & 15;
    ((float4*)&Ws[k * 64])[c4] = ((const float4*)&W[k * 128 + chalf * 64])[c4];
  }
  const int cl = t & 31;
  const int nslot = t >> 5;  // 0..7
  const int base = blockIdx.x * 64;
  for (int it = 0; it < 8; ++it) {
    int n0 = base + it * 8;
    if (n0 >= N_NODES) break;
    __syncthreads();
    for (int i = t; i < 2 * CIN; i += 256) {
      int pp = i / (CIN / 4), k4 = i % (CIN / 4);
      int n = n0 + pp;
      ((float4*)hs[pp])[k4] =
          (n < N_NODES) ? ((const float4*)&h[(size_t)n * CIN])[k4]
                        : make_float4(0.f, 0.f, 0.f, 0.f);
    }
    __syncthreads();
    int n = n0 + nslot;
    if (n < N_NODES) {
      float2 acc = make_float2(0.f, 0.f);
#pragma unroll 8
      for (int k = 0; k < CIN; ++k) {
        float hv = hs[nslot][k];
        float2 wv = ((const float2*)&Ws[k * 64])[cl];
        acc.x += hv * wv.x;
        acc.y += hv * wv.y;
      }
      ((float2*)&hw[(size_t)n * 128 + chalf * 64])[cl] = acc;
    }
  }
}

// ---------------------------------------------------------------------------
// CSR gather: one wave per node; lanes = 2 edges x 32 float4-channel-groups.
// agg[n,c] = dinv[n]^2*hw[n,c] + bias[c] + sum_j ew_s[j]*hw[src_s[j],c]
// ---------------------------------------------------------------------------
__global__ __launch_bounds__(256) void k_gather(
    const float* __restrict__ hw, const float* __restrict__ ew_s,
    const int* __restrict__ src_s, const int* __restrict__ rowstart,
    const float* __restrict__ dinv, const float* __restrict__ bias,
    float* __restrict__ agg) {
  const int t = threadIdx.x;
  const int n = blockIdx.x * 4 + (t >> 6);
  if (n >= N_NODES) return;
  const int lane = t & 63;
  const int q = lane >> 5;   // edge-of-pair selector
  const int cl = lane & 31;  // float4 channel group (128 ch)
  const int rs = rowstart[n], re = rowstart[n + 1];
  const float4* hw4 = (const float4*)hw;
  float4 a0 = make_float4(0.f, 0.f, 0.f, 0.f);
  float4 a1 = make_float4(0.f, 0.f, 0.f, 0.f);
  int j = rs;
  for (; j + 4 <= re; j += 4) {
    int i0 = j + q, i1 = j + 2 + q;
    int s0 = src_s[i0], s1 = src_s[i1];
    float w0 = ew_s[i0], w1 = ew_s[i1];
    float4 v0 = hw4[(size_t)s0 * 32 + cl];
    float4 v1 = hw4[(size_t)s1 * 32 + cl];
    fma4(a0, w0, v0);
    fma4(a1, w1, v1);
  }
  for (; j + 2 <= re; j += 2) {
    int i0 = j + q;
    int s0 = src_s[i0];
    float w0 = ew_s[i0];
    float4 v0 = hw4[(size_t)s0 * 32 + cl];
    fma4(a0, w0, v0);
  }
  if (q == 0 && j < re) {
    int s0 = src_s[j];
    float w0 = ew_s[j];
    fma4(a0, w0, hw4[(size_t)s0 * 32 + cl]);
  }
  a0.x += a1.x; a0.y += a1.y; a0.z += a1.z; a0.w += a1.w;
  a0.x += __shfl_xor(a0.x, 32);
  a0.y += __shfl_xor(a0.y, 32);
  a0.z += __shfl_xor(a0.z, 32);
  a0.w += __shfl_xor(a0.w, 32);
  if (q == 0) {
    float dv = dinv[n];
    float4 hv = hw4[(size_t)n * 32 + cl];
    float4 bv = ((const float4*)bias)[cl];
    float4 r = make_float4(a0.x + dv * dv * hv.x + bv.x,
                           a0.y + dv * dv * hv.y + bv.y,
                           a0.z + dv * dv * hv.z + bv.z,
                           a0.w + dv * dv * hv.w + bv.w);
    ((float4*)agg)[(size_t)n * 32 + cl] = r;
  }
}

// ---------------------------------------------------------------------------
// GraphNorm (in-place) + ReLU. One block (512 thr) per graph; batch sorted.
// ---------------------------------------------------------------------------
__global__ __launch_bounds__(512) void k_gnorm(float* __restrict__ h,
                                               const int* __restrict__ start,
                                               const float* __restrict__ gw,
                                               const float* __restrict__ gb,
                                               const float* __restrict__ gms) {
  int g = blockIdx.x;
  int s = start[g], e = start[g + 1];
  int t = threadIdx.x, p = t >> 7, c = t & 127;
  float sum = 0.f, sq = 0.f;
  for (int n = s + p; n < e; n += 4) {
    float v = h[(size_t)n * 128 + c];
    sum += v;
    sq += v * v;
  }
  __shared__ float S[4][128], Q[4][128], A[128], B[128];
  S[p][c] = sum;
  Q[p][c] = sq;
  __syncthreads();
  if (t < 128) {
    float cnt = (float)max(e - s, 1);
    float mean = (S[0][t] + S[1][t] + S[2][t] + S[3][t]) / cnt;
    float e2 = (Q[0][t] + Q[1][t] + Q[2][t] + Q[3][t]) / cnt;
    float ms = gms[t];
    float var = fmaxf(e2 - ms * (2.f - ms) * mean * mean, 0.f);
    float scale = gw[t] / sqrtf(var + EPS);
    A[t] = scale;
    B[t] = gb[t] - scale * ms * mean;
  }
  __syncthreads();
  for (int n = s + p; n < e; n += 4) {
    size_t idx = (size_t)n * 128 + c;
    h[idx] = fmaxf(A[c] * h[idx] + B[c], 0.f);
  }
}

// pooled[g,c] = mean over graph nodes
__global__ __launch_bounds__(512) void k_pool(const float* __restrict__ h,
                                              const int* __restrict__ start,
                                              float* __restrict__ pooled) {
  int g = blockIdx.x;
  int s = start[g], e = start[g + 1];
  int t = threadIdx.x, p = t >> 7, c = t & 127;
  float sum = 0.f;
  for (int n = s + p; n < e; n += 4) sum += h[(size_t)n * 128 + c];
  __shared__ float S[4][128];
  S[p][c] = sum;
  __syncthreads();
  if (t < 128) {
    float cnt = (float)max(e - s, 1);
    pooled[g * 128 + t] = (S[0][t] + S[1][t] + S[2][t] + S[3][t]) / cnt;
  }
}

// MLP head: 128 ->256 (BN,ReLU) ->128 (BN,ReLU) ->1; writes out[g] and h2.
__global__ __launch_bounds__(256) void k_head(
    const float* __restrict__ pooled, const float* __restrict__ w0,
    const float* __restrict__ b0, const float* __restrict__ g0,
    const float* __restrict__ bb0, const float* __restrict__ w1,
    const float* __restrict__ b1, const float* __restrict__ g1,
    const float* __restrict__ bb1, const float* __restrict__ ow,
    const float* __restrict__ ob, float* __restrict__ out) {
  __shared__ float p[128], h1[256], h2[128];
  int g = blockIdx.x, t = threadIdx.x;
  const float inv = 1.0f / sqrtf(1.0f + EPS);
  if (t < 128) p[t] = pooled[g * 128 + t];
  __syncthreads();
  {
    float acc = b0[t];
#pragma unroll 8
    for (int k = 0; k < 128; ++k) acc += p[k] * w0[k * 256 + t];
    h1[t] = fmaxf(acc * inv * g0[t] + bb0[t], 0.f);
  }
  __syncthreads();
  if (t < 128) {
    float acc = b1[t];
#pragma unroll 8
    for (int k = 0; k < 256; ++k) acc += h1[k] * w1[k * 128 + t];
    float v = fmaxf(acc * inv * g1[t] + bb1[t], 0.f);
    h2[t] = v;
    out[N_GRAPHS + g * 128 + t] = v;
  }
  __syncthreads();
  if (t < 64) {
    float v = h2[t] * ow[t] + h2[t + 64] * ow[t + 64];
#pragma unroll
    for (int off = 32; off; off >>= 1) v += __shfl_down(v, off);
    if (t == 0) out[g] = v + ob[0];
  }
}

// ---------------------------------------------------------------------------
extern "C" void kernel_launch(void* const* d_in, const int* in_sizes, int n_in,
                              void* d_out, int out_size, void* d_ws,
                              size_t ws_size, hipStream_t stream) {
  const float* x = (const float*)d_in[0];
  const float* edge_attr = (const float*)d_in[1];
  const float* em_w1 = (const float*)d_in[2];
  const float* em_b1 = (const float*)d_in[3];
  const float* em_w2 = (const float*)d_in[4];
  const float* em_b2 = (const float*)d_in[5];
  const float* conv_w[3] = {(const float*)d_in[6], (const float*)d_in[8],
                            (const float*)d_in[10]};
  const float* conv_b[3] = {(const float*)d_in[7], (const float*)d_in[9],
                            (const float*)d_in[11]};
  const float* gn_w[3] = {(const float*)d_in[12], (const float*)d_in[15],
                          (const float*)d_in[18]};
  const float* gn_b[3] = {(const float*)d_in[13], (const float*)d_in[16],
                          (const float*)d_in[19]};
  const float* gn_ms[3] = {(const float*)d_in[14], (const float*)d_in[17],
                           (const float*)d_in[20]};
  const float* lin_w0 = (const float*)d_in[21];
  const float* lin_b0 = (const float*)d_in[22];
  const float* bn_g0 = (const float*)d_in[23];
  const float* bn_b0 = (const float*)d_in[24];
  const float* lin_w1 = (const float*)d_in[25];
  const float* lin_b1 = (const float*)d_in[26];
  const float* bn_g1 = (const float*)d_in[27];
  const float* bn_b1 = (const float*)d_in[28];
  const float* out_w = (const float*)d_in[29];
  const float* out_b = (const float*)d_in[30];
  const int* edge_index = (const int*)d_in[31];
  const int* batch = (const int*)d_in[32];
  const int* src = edge_index;
  const int* tgt = edge_index + N_EDGES;

  char* w = (char*)d_ws;
  size_t off = 0;
  auto carve = [&](size_t bytes) {
    void* p = w + off;
    off = (off + bytes + 511) & ~(size_t)511;
    return p;
  };
  float* ew = (float*)carve((size_t)N_EDGES * 4);
  int* rank = (int*)carve((size_t)N_EDGES * 4);
  float* dinv = (float*)carve((size_t)N_NODES * 4);
  int* rowcnt = (int*)carve((size_t)N_NODES * 4);
  int* rowstart = (int*)carve((size_t)(N_NODES + 1) * 4);
  int* bsum = (int*)carve((size_t)SCAN_BLOCKS * 4);
  int* boff = (int*)carve((size_t)512 * 4);
  int* src_s = (int*)carve((size_t)N_EDGES * 4);
  float* ew_s = (float*)carve((size_t)N_EDGES * 4);
  int* start = (int*)carve((N_GRAPHS + 1) * 4);
  float* big0 = (float*)carve((size_t)N_NODES * 128 * 4);
  float* big1 = (float*)carve((size_t)N_NODES * 128 * 4);
  float* big2 = (float*)carve((size_t)N_NODES * 128 * 4);
  float* pooled = (float*)carve((size_t)N_GRAPHS * 128 * 4);

  hipMemsetAsync(rowcnt, 0, (size_t)N_NODES * 4, stream);

  k_edge_mlp<<<(N_EDGES + 255) / 256, 256, 0, stream>>>(
      edge_attr, em_w1, em_b1, em_w2, em_b2, tgt, ew, rowcnt, rank);
  k_scan1<<<SCAN_BLOCKS, 256, 0, stream>>>(rowcnt, bsum);
  k_scan2<<<1, 512, 0, stream>>>(bsum, boff);
  k_scan3<<<SCAN_BLOCKS, 256, 0, stream>>>(rowcnt, boff, rowstart);
  k_fill<<<(N_EDGES + 255) / 256, 256, 0, stream>>>(src, tgt, ew, rank,
                                                    rowstart, src_s, ew_s);
  k_deg<<<(N_NODES + 255) / 256, 256, 0, stream>>>(ew_s, rowstart, dinv);
  k_scale<<<(N_NODES + 3) / 4, 256, 0, stream>>>(ew_s, src_s, rowstart, dinv);
  k_starts<<<1, 512, 0, stream>>>(batch, start);

  const float* h_in[3] = {x, big1, big2};
  float* agg[3] = {big1, big2, big1};

  for (int l = 0; l < 3; ++l) {
    dim3 gw_grid((N_NODES + 63) / 64, 2);
    if (l == 0)
      k_hw<64><<<gw_grid, 256, 0, stream>>>(h_in[l], conv_w[l], big0);
    else
      k_hw<128><<<gw_grid, 256, 0, stream>>>(h_in[l], conv_w[l], big0);
    k_gather<<<(N_NODES + 3) / 4, 256, 0, stream>>>(
        big0, ew_s, src_s, rowstart, dinv, conv_b[l], agg[l]);
    k_gnorm<<<N_GRAPHS, 512, 0, stream>>>(agg[l], start, gn_w[l], gn_b[l],
                                          gn_ms[l]);
  }

  k_pool<<<N_GRAPHS, 512, 0, stream>>>(big1, start, pooled);
  k_head<<<N_GRAPHS, 256, 0, stream>>>(pooled, lin_w0, lin_b0, bn_g0, bn_b0,
                                       lin_w1, lin_b1, bn_g1, bn_b1, out_w,
                                       out_b, (float*)d_out);
}

// Round 5
// 842.368 us; speedup vs baseline: 3.3439x; 1.2566x over previous
//
#include <hip/hip_runtime.h>

#define N_NODES 100000
#define N_EDGES 1600000
#define N_GRAPHS 256
#define EPS 1e-5f

#define SCAN_BLOCKS ((N_NODES + 255) / 256)  // 391

__device__ __forceinline__ void fma4(float4& a, float s, const float4& w) {
  a.x += s * w.x; a.y += s * w.y; a.z += s * w.z; a.w += s * w.w;
}

// ---------------------------------------------------------------------------
// Edge MLP: ew[e] = Linear(16,1)(ReLU(Linear(8,16)(edge_attr[e])))
// + within-row rank via rowcnt histogram (the ONLY atomic pass).
// ---------------------------------------------------------------------------
__global__ __launch_bounds__(256) void k_edge_mlp(
    const float* __restrict__ ea, const float* __restrict__ w1,
    const float* __restrict__ b1, const float* __restrict__ w2,
    const float* __restrict__ b2, const int* __restrict__ tgt,
    float* __restrict__ ew, int* __restrict__ rowcnt,
    int* __restrict__ rank) {
  __shared__ float W1[128], B1[16], W2[16];
  int t = threadIdx.x;
  if (t < 128) W1[t] = w1[t];
  if (t < 16) { B1[t] = b1[t]; W2[t] = w2[t]; }
  __syncthreads();
  int e = blockIdx.x * 256 + t;
  if (e >= N_EDGES) return;
  const float4* ap = (const float4*)(ea + (size_t)e * 8);
  float4 a0 = ap[0], a1 = ap[1];
  float a[8] = {a0.x, a0.y, a0.z, a0.w, a1.x, a1.y, a1.z, a1.w};
  float out = b2[0];
#pragma unroll
  for (int i = 0; i < 16; ++i) {
    float h = B1[i];
#pragma unroll
    for (int j = 0; j < 8; ++j) h += a[j] * W1[i * 8 + j];
    out += fmaxf(h, 0.f) * W2[i];
  }
  ew[e] = out;
  rank[e] = atomicAdd(&rowcnt[tgt[e]], 1);
}

// ---------------------------------------------------------------------------
// Parallel 3-phase exclusive scan of rowcnt -> rowstart[0..N]
// ---------------------------------------------------------------------------
__global__ __launch_bounds__(256) void k_scan1(const int* __restrict__ cnt,
                                               int* __restrict__ bsum) {
  int i = blockIdx.x * 256 + threadIdx.x;
  int v = (i < N_NODES) ? cnt[i] : 0;
#pragma unroll
  for (int off = 32; off; off >>= 1) v += __shfl_down(v, off);
  __shared__ int ws[4];
  if ((threadIdx.x & 63) == 0) ws[threadIdx.x >> 6] = v;
  __syncthreads();
  if (threadIdx.x == 0) bsum[blockIdx.x] = ws[0] + ws[1] + ws[2] + ws[3];
}

__global__ __launch_bounds__(512) void k_scan2(const int* __restrict__ bsum,
                                               int* __restrict__ boff) {
  __shared__ int s[512];
  int t = threadIdx.x;
  s[t] = (t < SCAN_BLOCKS) ? bsum[t] : 0;
  __syncthreads();
  for (int off = 1; off < 512; off <<= 1) {
    int u = (t >= off) ? s[t - off] : 0;
    __syncthreads();
    s[t] += u;
    __syncthreads();
  }
  boff[t] = (t == 0) ? 0 : s[t - 1];
}

__global__ __launch_bounds__(256) void k_scan3(const int* __restrict__ cnt,
                                               const int* __restrict__ boff,
                                               int* __restrict__ rowstart) {
  __shared__ int s[256];
  int t = threadIdx.x;
  int i = blockIdx.x * 256 + t;
  int v = (i < N_NODES) ? cnt[i] : 0;
  s[t] = v;
  __syncthreads();
  for (int off = 1; off < 256; off <<= 1) {
    int u = (t >= off) ? s[t - off] : 0;
    __syncthreads();
    s[t] += u;
    __syncthreads();
  }
  if (i < N_NODES) {
    int pre = boff[blockIdx.x] + s[t] - v;  // exclusive
    rowstart[i] = pre;
    if (i == N_NODES - 1) rowstart[N_NODES] = pre + v;
  }
}

// Atomic-free CSR fill: slot = rowstart[tgt] + rank (unique by construction).
__global__ __launch_bounds__(256) void k_fill(
    const int* __restrict__ src, const int* __restrict__ tgt,
    const float* __restrict__ ew, const int* __restrict__ rank,
    const int* __restrict__ rowstart, int* __restrict__ src_s,
    float* __restrict__ ew_s) {
  int e = blockIdx.x * 256 + threadIdx.x;
  if (e >= N_EDGES) return;
  int p = rowstart[tgt[e]] + rank[e];
  src_s[p] = src[e];
  ew_s[p] = ew[e];
}

// deg row-sum (atomic-free) fused with dinv: dinv[n] = rsqrt(1 + sum ew_row)
__global__ __launch_bounds__(256) void k_deg(const float* __restrict__ ew_s,
                                             const int* __restrict__ rowstart,
                                             float* __restrict__ dinv) {
  int n = blockIdx.x * 256 + threadIdx.x;
  if (n >= N_NODES) return;
  int rs = rowstart[n], re = rowstart[n + 1];
  float d = 1.f;
  for (int j = rs; j < re; ++j) d += ew_s[j];
  dinv[n] = d > 0.f ? rsqrtf(d) : 0.f;
}

// ew_s[j] *= dinv[src_s[j]] * dinv[row]; wave per node.
__global__ __launch_bounds__(256) void k_scale(float* __restrict__ ew_s,
                                               const int* __restrict__ src_s,
                                               const int* __restrict__ rowstart,
                                               const float* __restrict__ dinv) {
  int n = blockIdx.x * 4 + (threadIdx.x >> 6);
  if (n >= N_NODES) return;
  int lane = threadIdx.x & 63;
  int rs = rowstart[n], re = rowstart[n + 1];
  float dv = dinv[n];
  for (int j = rs + lane; j < re; j += 64) ew_s[j] *= dinv[src_s[j]] * dv;
}

// graph segment starts: start[g] = lower_bound(batch, g); start[256] = N
__global__ void k_starts(const int* __restrict__ batch, int* __restrict__ start) {
  int g = blockIdx.x * blockDim.x + threadIdx.x;
  if (g > N_GRAPHS) return;
  int lo = 0, hi = N_NODES;
  while (lo < hi) {
    int mid = (lo + hi) >> 1;
    if (batch[mid] < g) lo = mid + 1; else hi = mid;
  }
  start[g] = lo;
}

// ---------------------------------------------------------------------------
// hw = h @ W  -- register-tiled GEMM.
// Block: 256 thr, 64-node x 128-channel output tile.
// Thread: 4 nodes (tn + 16i) x 8 channels (tc*4..+3 and 64+tc*4..+3).
// K staged in KT=32 tiles: hs[64][36] (pad), Ws[32][128]. 25.6 KB LDS.
// Inner: 12 ds_read_b128 per 128 FMA -> VALU-bound.
// ---------------------------------------------------------------------------
template <int CIN>
__global__ __launch_bounds__(256) void k_hw(const float* __restrict__ h,
                                            const float* __restrict__ W,
                                            float* __restrict__ hw) {
  constexpr int KT = 32;
  __shared__ float hs[64][36];
  __shared__ float Ws[KT][128];
  const int t = threadIdx.x;
  const int tn = t & 15, tc = t >> 4;
  const int base = blockIdx.x * 64;

  float acc[4][8];
#pragma unroll
  for (int i = 0; i < 4; ++i)
#pragma unroll
    for (int j = 0; j < 8; ++j) acc[i][j] = 0.f;

  const int ln = t >> 2;        // staging: node 0..63
  const int lk = (t & 3) * 8;   // staging: k offset
  const int wk = t >> 3;        // staging: k row 0..31
  const int wc = (t & 7) * 16;  // staging: c offset

  for (int k0 = 0; k0 < CIN; k0 += KT) {
    __syncthreads();
    {
      int n = base + ln;
      float4 v0 = make_float4(0.f, 0.f, 0.f, 0.f), v1 = v0;
      if (n < N_NODES) {
        const float4* hp = (const float4*)(h + (size_t)n * CIN + k0 + lk);
        v0 = hp[0];
        v1 = hp[1];
      }
      *(float4*)&hs[ln][lk] = v0;
      *(float4*)&hs[ln][lk + 4] = v1;
      const float4* wp = (const float4*)(W + (size_t)(k0 + wk) * 128 + wc);
#pragma unroll
      for (int q = 0; q < 4; ++q) *(float4*)&Ws[wk][wc + q * 4] = wp[q];
    }
    __syncthreads();
#pragma unroll
    for (int kk = 0; kk < KT; kk += 4) {
      float4 hv[4];
#pragma unroll
      for (int i = 0; i < 4; ++i) hv[i] = *(const float4*)&hs[tn + 16 * i][kk];
#pragma unroll
      for (int dk = 0; dk < 4; ++dk) {
        float4 wa = *(const float4*)&Ws[kk + dk][tc * 4];
        float4 wb = *(const float4*)&Ws[kk + dk][64 + tc * 4];
#pragma unroll
        for (int i = 0; i < 4; ++i) {
          float hvv = (&hv[i].x)[dk];
          acc[i][0] += hvv * wa.x; acc[i][1] += hvv * wa.y;
          acc[i][2] += hvv * wa.z; acc[i][3] += hvv * wa.w;
          acc[i][4] += hvv * wb.x; acc[i][5] += hvv * wb.y;
          acc[i][6] += hvv * wb.z; acc[i][7] += hvv * wb.w;
        }
      }
    }
  }
#pragma unroll
  for (int i = 0; i < 4; ++i) {
    int n = base + tn + 16 * i;
    if (n < N_NODES) {
      float* op = hw + (size_t)n * 128;
      *(float4*)&op[tc * 4] =
          make_float4(acc[i][0], acc[i][1], acc[i][2], acc[i][3]);
      *(float4*)&op[64 + tc * 4] =
          make_float4(acc[i][4], acc[i][5], acc[i][6], acc[i][7]);
    }
  }
}

// ---------------------------------------------------------------------------
// CSR gather: one wave per node; lanes = 2 edges x 32 float4-channel-groups.
// agg[n,c] = dinv[n]^2*hw[n,c] + bias[c] + sum_j ew_s[j]*hw[src_s[j],c]
// ---------------------------------------------------------------------------
__global__ __launch_bounds__(256) void k_gather(
    const float* __restrict__ hw, const float* __restrict__ ew_s,
    const int* __restrict__ src_s, const int* __restrict__ rowstart,
    const float* __restrict__ dinv, const float* __restrict__ bias,
    float* __restrict__ agg) {
  const int t = threadIdx.x;
  const int n = blockIdx.x * 4 + (t >> 6);
  if (n >= N_NODES) return;
  const int lane = t & 63;
  const int q = lane >> 5;   // edge-of-pair selector
  const int cl = lane & 31;  // float4 channel group (128 ch)
  const int rs = rowstart[n], re = rowstart[n + 1];
  const float4* hw4 = (const float4*)hw;
  float4 a0 = make_float4(0.f, 0.f, 0.f, 0.f);
  float4 a1 = make_float4(0.f, 0.f, 0.f, 0.f);
  int j = rs;
  for (; j + 4 <= re; j += 4) {
    int i0 = j + q, i1 = j + 2 + q;
    int s0 = src_s[i0], s1 = src_s[i1];
    float w0 = ew_s[i0], w1 = ew_s[i1];
    float4 v0 = hw4[(size_t)s0 * 32 + cl];
    float4 v1 = hw4[(size_t)s1 * 32 + cl];
    fma4(a0, w0, v0);
    fma4(a1, w1, v1);
  }
  for (; j + 2 <= re; j += 2) {
    int i0 = j + q;
    int s0 = src_s[i0];
    float w0 = ew_s[i0];
    float4 v0 = hw4[(size_t)s0 * 32 + cl];
    fma4(a0, w0, v0);
  }
  if (q == 0 && j < re) {
    int s0 = src_s[j];
    float w0 = ew_s[j];
    fma4(a0, w0, hw4[(size_t)s0 * 32 + cl]);
  }
  a0.x += a1.x; a0.y += a1.y; a0.z += a1.z; a0.w += a1.w;
  a0.x += __shfl_xor(a0.x, 32);
  a0.y += __shfl_xor(a0.y, 32);
  a0.z += __shfl_xor(a0.z, 32);
  a0.w += __shfl_xor(a0.w, 32);
  if (q == 0) {
    float dv = dinv[n];
    float4 hv = hw4[(size_t)n * 32 + cl];
    float4 bv = ((const float4*)bias)[cl];
    float4 r = make_float4(a0.x + dv * dv * hv.x + bv.x,
                           a0.y + dv * dv * hv.y + bv.y,
                           a0.z + dv * dv * hv.z + bv.z,
                           a0.w + dv * dv * hv.w + bv.w);
    ((float4*)agg)[(size_t)n * 32 + cl] = r;
  }
}

// ---------------------------------------------------------------------------
// GraphNorm (in-place) + ReLU. One block (512 thr) per graph; batch sorted.
// ---------------------------------------------------------------------------
__global__ __launch_bounds__(512) void k_gnorm(float* __restrict__ h,
                                               const int* __restrict__ start,
                                               const float* __restrict__ gw,
                                               const float* __restrict__ gb,
                                               const float* __restrict__ gms) {
  int g = blockIdx.x;
  int s = start[g], e = start[g + 1];
  int t = threadIdx.x, p = t >> 7, c = t & 127;
  float sum = 0.f, sq = 0.f;
  for (int n = s + p; n < e; n += 4) {
    float v = h[(size_t)n * 128 + c];
    sum += v;
    sq += v * v;
  }
  __shared__ float S[4][128], Q[4][128], A[128], B[128];
  S[p][c] = sum;
  Q[p][c] = sq;
  __syncthreads();
  if (t < 128) {
    float cnt = (float)max(e - s, 1);
    float mean = (S[0][t] + S[1][t] + S[2][t] + S[3][t]) / cnt;
    float e2 = (Q[0][t] + Q[1][t] + Q[2][t] + Q[3][t]) / cnt;
    float ms = gms[t];
    float var = fmaxf(e2 - ms * (2.f - ms) * mean * mean, 0.f);
    float scale = gw[t] / sqrtf(var + EPS);
    A[t] = scale;
    B[t] = gb[t] - scale * ms * mean;
  }
  __syncthreads();
  for (int n = s + p; n < e; n += 4) {
    size_t idx = (size_t)n * 128 + c;
    h[idx] = fmaxf(A[c] * h[idx] + B[c], 0.f);
  }
}

// pooled[g,c] = mean over graph nodes
__global__ __launch_bounds__(512) void k_pool(const float* __restrict__ h,
                                              const int* __restrict__ start,
                                              float* __restrict__ pooled) {
  int g = blockIdx.x;
  int s = start[g], e = start[g + 1];
  int t = threadIdx.x, p = t >> 7, c = t & 127;
  float sum = 0.f;
  for (int n = s + p; n < e; n += 4) sum += h[(size_t)n * 128 + c];
  __shared__ float S[4][128];
  S[p][c] = sum;
  __syncthreads();
  if (t < 128) {
    float cnt = (float)max(e - s, 1);
    pooled[g * 128 + t] = (S[0][t] + S[1][t] + S[2][t] + S[3][t]) / cnt;
  }
}

// MLP head: 128 ->256 (BN,ReLU) ->128 (BN,ReLU) ->1; writes out[g] and h2.
__global__ __launch_bounds__(256) void k_head(
    const float* __restrict__ pooled, const float* __restrict__ w0,
    const float* __restrict__ b0, const float* __restrict__ g0,
    const float* __restrict__ bb0, const float* __restrict__ w1,
    const float* __restrict__ b1, const float* __restrict__ g1,
    const float* __restrict__ bb1, const float* __restrict__ ow,
    const float* __restrict__ ob, float* __restrict__ out) {
  __shared__ float p[128], h1[256], h2[128];
  int g = blockIdx.x, t = threadIdx.x;
  const float inv = 1.0f / sqrtf(1.0f + EPS);
  if (t < 128) p[t] = pooled[g * 128 + t];
  __syncthreads();
  {
    float acc = b0[t];
#pragma unroll 8
    for (int k = 0; k < 128; ++k) acc += p[k] * w0[k * 256 + t];
    h1[t] = fmaxf(acc * inv * g0[t] + bb0[t], 0.f);
  }
  __syncthreads();
  if (t < 128) {
    float acc = b1[t];
#pragma unroll 8
    for (int k = 0; k < 256; ++k) acc += h1[k] * w1[k * 128 + t];
    float v = fmaxf(acc * inv * g1[t] + bb1[t], 0.f);
    h2[t] = v;
    out[N_GRAPHS + g * 128 + t] = v;
  }
  __syncthreads();
  if (t < 64) {
    float v = h2[t] * ow[t] + h2[t + 64] * ow[t + 64];
#pragma unroll
    for (int off = 32; off; off >>= 1) v += __shfl_down(v, off);
    if (t == 0) out[g] = v + ob[0];
  }
}

// ---------------------------------------------------------------------------
extern "C" void kernel_launch(void* const* d_in, const int* in_sizes, int n_in,
                              void* d_out, int out_size, void* d_ws,
                              size_t ws_size, hipStream_t stream) {
  const float* x = (const float*)d_in[0];
  const float* edge_attr = (const float*)d_in[1];
  const float* em_w1 = (const float*)d_in[2];
  const float* em_b1 = (const float*)d_in[3];
  const float* em_w2 = (const float*)d_in[4];
  const float* em_b2 = (const float*)d_in[5];
  const float* conv_w[3] = {(const float*)d_in[6], (const float*)d_in[8],
                            (const float*)d_in[10]};
  const float* conv_b[3] = {(const float*)d_in[7], (const float*)d_in[9],
                            (const float*)d_in[11]};
  const float* gn_w[3] = {(const float*)d_in[12], (const float*)d_in[15],
                          (const float*)d_in[18]};
  const float* gn_b[3] = {(const float*)d_in[13], (const float*)d_in[16],
                          (const float*)d_in[19]};
  const float* gn_ms[3] = {(const float*)d_in[14], (const float*)d_in[17],
                           (const float*)d_in[20]};
  const float* lin_w0 = (const float*)d_in[21];
  const float* lin_b0 = (const float*)d_in[22];
  const float* bn_g0 = (const float*)d_in[23];
  const float* bn_b0 = (const float*)d_in[24];
  const float* lin_w1 = (const float*)d_in[25];
  const float* lin_b1 = (const float*)d_in[26];
  const float* bn_g1 = (const float*)d_in[27];
  const float* bn_b1 = (const float*)d_in[28];
  const float* out_w = (const float*)d_in[29];
  const float* out_b = (const float*)d_in[30];
  const int* edge_index = (const int*)d_in[31];
  const int* batch = (const int*)d_in[32];
  const int* src = edge_index;
  const int* tgt = edge_index + N_EDGES;

  char* w = (char*)d_ws;
  size_t off = 0;
  auto carve = [&](size_t bytes) {
    void* p = w + off;
    off = (off + bytes + 511) & ~(size_t)511;
    return p;
  };
  float* ew = (float*)carve((size_t)N_EDGES * 4);
  int* rank = (int*)carve((size_t)N_EDGES * 4);
  float* dinv = (float*)carve((size_t)N_NODES * 4);
  int* rowcnt = (int*)carve((size_t)N_NODES * 4);
  int* rowstart = (int*)carve((size_t)(N_NODES + 1) * 4);
  int* bsum = (int*)carve((size_t)SCAN_BLOCKS * 4);
  int* boff = (int*)carve((size_t)512 * 4);
  int* src_s = (int*)carve((size_t)N_EDGES * 4);
  float* ew_s = (float*)carve((size_t)N_EDGES * 4);
  int* start = (int*)carve((N_GRAPHS + 1) * 4);
  float* big0 = (float*)carve((size_t)N_NODES * 128 * 4);
  float* big1 = (float*)carve((size_t)N_NODES * 128 * 4);
  float* big2 = (float*)carve((size_t)N_NODES * 128 * 4);
  float* pooled = (float*)carve((size_t)N_GRAPHS * 128 * 4);

  hipMemsetAsync(rowcnt, 0, (size_t)N_NODES * 4, stream);

  k_edge_mlp<<<(N_EDGES + 255) / 256, 256, 0, stream>>>(
      edge_attr, em_w1, em_b1, em_w2, em_b2, tgt, ew, rowcnt, rank);
  k_scan1<<<SCAN_BLOCKS, 256, 0, stream>>>(rowcnt, bsum);
  k_scan2<<<1, 512, 0, stream>>>(bsum, boff);
  k_scan3<<<SCAN_BLOCKS, 256, 0, stream>>>(rowcnt, boff, rowstart);
  k_fill<<<(N_EDGES + 255) / 256, 256, 0, stream>>>(src, tgt, ew, rank,
                                                    rowstart, src_s, ew_s);
  k_deg<<<(N_NODES + 255) / 256, 256, 0, stream>>>(ew_s, rowstart, dinv);
  k_scale<<<(N_NODES + 3) / 4, 256, 0, stream>>>(ew_s, src_s, rowstart, dinv);
  k_starts<<<1, 512, 0, stream>>>(batch, start);

  const float* h_in[3] = {x, big1, big2};
  float* agg[3] = {big1, big2, big1};

  for (int l = 0; l < 3; ++l) {
    int gw_grid = (N_NODES + 63) / 64;
    if (l == 0)
      k_hw<64><<<gw_grid, 256, 0, stream>>>(h_in[l], conv_w[l], big0);
    else
      k_hw<128><<<gw_grid, 256, 0, stream>>>(h_in[l], conv_w[l], big0);
    k_gather<<<(N_NODES + 3) / 4, 256, 0, stream>>>(
        big0, ew_s, src_s, rowstart, dinv, conv_b[l], agg[l]);
    k_gnorm<<<N_GRAPHS, 512, 0, stream>>>(agg[l], start, gn_w[l], gn_b[l],
                                          gn_ms[l]);
  }

  k_pool<<<N_GRAPHS, 512, 0, stream>>>(big1, start, pooled);
  k_head<<<N_GRAPHS, 256, 0, stream>>>(pooled, lin_w0, lin_b0, bn_g0, bn_b0,
                                       lin_w1, lin_b1, bn_g1, bn_b1, out_w,
                                       out_b, (float*)d_out);
}

// Round 6
// 741.787 us; speedup vs baseline: 3.7973x; 1.1356x over previous
//
#include <hip/hip_runtime.h>

#define N_NODES 100000
#define N_EDGES 1600000
#define N_GRAPHS 256
#define EPS 1e-5f

#define SCAN_BLOCKS ((N_NODES + 255) / 256)  // 391

__device__ __forceinline__ void fma4(float4& a, float s, const float4& w) {
  a.x += s * w.x; a.y += s * w.y; a.z += s * w.z; a.w += s * w.w;
}

// ---------------------------------------------------------------------------
// Edge MLP + within-row rank histogram (the only atomic pass).
// ---------------------------------------------------------------------------
__global__ __launch_bounds__(256) void k_edge_mlp(
    const float* __restrict__ ea, const float* __restrict__ w1,
    const float* __restrict__ b1, const float* __restrict__ w2,
    const float* __restrict__ b2, const int* __restrict__ tgt,
    float* __restrict__ ew, int* __restrict__ rowcnt,
    int* __restrict__ rank) {
  __shared__ float W1[128], B1[16], W2[16];
  int t = threadIdx.x;
  if (t < 128) W1[t] = w1[t];
  if (t < 16) { B1[t] = b1[t]; W2[t] = w2[t]; }
  __syncthreads();
  int e = blockIdx.x * 256 + t;
  if (e >= N_EDGES) return;
  const float4* ap = (const float4*)(ea + (size_t)e * 8);
  float4 a0 = ap[0], a1 = ap[1];
  float a[8] = {a0.x, a0.y, a0.z, a0.w, a1.x, a1.y, a1.z, a1.w};
  float out = b2[0];
#pragma unroll
  for (int i = 0; i < 16; ++i) {
    float h = B1[i];
#pragma unroll
    for (int j = 0; j < 8; ++j) h += a[j] * W1[i * 8 + j];
    out += fmaxf(h, 0.f) * W2[i];
  }
  ew[e] = out;
  rank[e] = atomicAdd(&rowcnt[tgt[e]], 1);
}

// ---------------------------------------------------------------------------
// Parallel 3-phase exclusive scan of rowcnt -> rowstart[0..N]
// ---------------------------------------------------------------------------
__global__ __launch_bounds__(256) void k_scan1(const int* __restrict__ cnt,
                                               int* __restrict__ bsum) {
  int i = blockIdx.x * 256 + threadIdx.x;
  int v = (i < N_NODES) ? cnt[i] : 0;
#pragma unroll
  for (int off = 32; off; off >>= 1) v += __shfl_down(v, off);
  __shared__ int ws[4];
  if ((threadIdx.x & 63) == 0) ws[threadIdx.x >> 6] = v;
  __syncthreads();
  if (threadIdx.x == 0) bsum[blockIdx.x] = ws[0] + ws[1] + ws[2] + ws[3];
}

__global__ __launch_bounds__(512) void k_scan2(const int* __restrict__ bsum,
                                               int* __restrict__ boff) {
  __shared__ int s[512];
  int t = threadIdx.x;
  s[t] = (t < SCAN_BLOCKS) ? bsum[t] : 0;
  __syncthreads();
  for (int off = 1; off < 512; off <<= 1) {
    int u = (t >= off) ? s[t - off] : 0;
    __syncthreads();
    s[t] += u;
    __syncthreads();
  }
  boff[t] = (t == 0) ? 0 : s[t - 1];
}

__global__ __launch_bounds__(256) void k_scan3(const int* __restrict__ cnt,
                                               const int* __restrict__ boff,
                                               int* __restrict__ rowstart) {
  __shared__ int s[256];
  int t = threadIdx.x;
  int i = blockIdx.x * 256 + t;
  int v = (i < N_NODES) ? cnt[i] : 0;
  s[t] = v;
  __syncthreads();
  for (int off = 1; off < 256; off <<= 1) {
    int u = (t >= off) ? s[t - off] : 0;
    __syncthreads();
    s[t] += u;
    __syncthreads();
  }
  if (i < N_NODES) {
    int pre = boff[blockIdx.x] + s[t] - v;  // exclusive
    rowstart[i] = pre;
    if (i == N_NODES - 1) rowstart[N_NODES] = pre + v;
  }
}

// Atomic-free CSR fill: slot = rowstart[tgt] + rank (unique by construction).
__global__ __launch_bounds__(256) void k_fill(
    const int* __restrict__ src, const int* __restrict__ tgt,
    const float* __restrict__ ew, const int* __restrict__ rank,
    const int* __restrict__ rowstart, int* __restrict__ src_s,
    float* __restrict__ ew_s) {
  int e = blockIdx.x * 256 + threadIdx.x;
  if (e >= N_EDGES) return;
  int p = rowstart[tgt[e]] + rank[e];
  src_s[p] = src[e];
  ew_s[p] = ew[e];
}

// deg row-sum fused with dinv: dinv[n] = rsqrt(1 + sum ew_row)
__global__ __launch_bounds__(256) void k_deg(const float* __restrict__ ew_s,
                                             const int* __restrict__ rowstart,
                                             float* __restrict__ dinv) {
  int n = blockIdx.x * 256 + threadIdx.x;
  if (n >= N_NODES) return;
  int rs = rowstart[n], re = rowstart[n + 1];
  float d = 1.f;
  for (int j = rs; j < re; ++j) d += ew_s[j];
  dinv[n] = d > 0.f ? rsqrtf(d) : 0.f;
}

// ew_s[j] *= dinv[src_s[j]] * dinv[row]; wave per node.
__global__ __launch_bounds__(256) void k_scale(float* __restrict__ ew_s,
                                               const int* __restrict__ src_s,
                                               const int* __restrict__ rowstart,
                                               const float* __restrict__ dinv) {
  int n = blockIdx.x * 4 + (threadIdx.x >> 6);
  if (n >= N_NODES) return;
  int lane = threadIdx.x & 63;
  int rs = rowstart[n], re = rowstart[n + 1];
  float dv = dinv[n];
  for (int j = rs + lane; j < re; j += 64) ew_s[j] *= dinv[src_s[j]] * dv;
}

// graph segment starts
__global__ void k_starts(const int* __restrict__ batch, int* __restrict__ start) {
  int g = blockIdx.x * blockDim.x + threadIdx.x;
  if (g > N_GRAPHS) return;
  int lo = 0, hi = N_NODES;
  while (lo < hi) {
    int mid = (lo + hi) >> 1;
    if (batch[mid] < g) lo = mid + 1; else hi = mid;
  }
  start[g] = lo;
}

// ---------------------------------------------------------------------------
// 64-channel CSR gather on raw x (layer-0 aggregate-before-transform):
// aggx[n] = dinv[n]^2 * x[n] + sum_j ew_s[j] * x[src_s[j]]
// wave per node; 4 edges x 16 float4-lanes.
// ---------------------------------------------------------------------------
__global__ __launch_bounds__(256) void k_gather64(
    const float* __restrict__ x, const float* __restrict__ ew_s,
    const int* __restrict__ src_s, const int* __restrict__ rowstart,
    const float* __restrict__ dinv, float* __restrict__ out) {
  const int t = threadIdx.x;
  const int n = blockIdx.x * 4 + (t >> 6);
  if (n >= N_NODES) return;
  const int lane = t & 63;
  const int q = lane >> 4;   // edge slot 0..3
  const int cl = lane & 15;  // float4 group over 64 ch
  const int rs = rowstart[n], re = rowstart[n + 1];
  const float4* x4 = (const float4*)x;
  float4 a0 = make_float4(0.f, 0.f, 0.f, 0.f);
  float4 a1 = make_float4(0.f, 0.f, 0.f, 0.f);
  int j = rs;
  for (; j + 8 <= re; j += 8) {
    int i0 = j + q, i1 = j + 4 + q;
    float w0 = ew_s[i0], w1 = ew_s[i1];
    float4 v0 = x4[(size_t)src_s[i0] * 16 + cl];
    float4 v1 = x4[(size_t)src_s[i1] * 16 + cl];
    fma4(a0, w0, v0);
    fma4(a1, w1, v1);
  }
  for (; j + 4 <= re; j += 4) {
    int i0 = j + q;
    fma4(a0, ew_s[i0], x4[(size_t)src_s[i0] * 16 + cl]);
  }
  if (j + q < re) {
    fma4(a1, ew_s[j + q], x4[(size_t)src_s[j + q] * 16 + cl]);
  }
  a0.x += a1.x; a0.y += a1.y; a0.z += a1.z; a0.w += a1.w;
#pragma unroll
  for (int m = 16; m <= 32; m <<= 1) {
    a0.x += __shfl_xor(a0.x, m);
    a0.y += __shfl_xor(a0.y, m);
    a0.z += __shfl_xor(a0.z, m);
    a0.w += __shfl_xor(a0.w, m);
  }
  if (q == 0) {
    float dv = dinv[n];
    float4 hv = x4[(size_t)n * 16 + cl];
    float4 r = make_float4(a0.x + dv * dv * hv.x, a0.y + dv * dv * hv.y,
                           a0.z + dv * dv * hv.z, a0.w + dv * dv * hv.w);
    ((float4*)out)[(size_t)n * 16 + cl] = r;
  }
}

// ---------------------------------------------------------------------------
// hw = f(h) @ W  -- register-tiled GEMM, optional fused input transform
// f(h) = relu(A[batch[n]][c]*h + B[batch[n]][c]) (NORM) and output +bias.
// Block: 64-node x 128-ch tile; thread: 4 nodes x 8 ch.
// ---------------------------------------------------------------------------
template <int CIN, bool NORM, bool BIAS>
__global__ __launch_bounds__(256) void k_hw(
    const float* __restrict__ h, const float* __restrict__ W,
    const int* __restrict__ batch, const float* __restrict__ An,
    const float* __restrict__ Bn, const float* __restrict__ bias,
    float* __restrict__ hw) {
  constexpr int KT = 32;
  __shared__ float hs[64][36];
  __shared__ float Ws[KT][128];
  const int t = threadIdx.x;
  const int tn = t & 15, tc = t >> 4;
  const int base = blockIdx.x * 64;

  float acc[4][8];
#pragma unroll
  for (int i = 0; i < 4; ++i)
#pragma unroll
    for (int j = 0; j < 8; ++j) acc[i][j] = 0.f;

  const int ln = t >> 2;        // staging node 0..63
  const int lk = (t & 3) * 8;   // staging k offset within tile
  const int wk = t >> 3;        // staging k row 0..31
  const int wc = (t & 7) * 16;  // staging c offset

  for (int k0 = 0; k0 < CIN; k0 += KT) {
    __syncthreads();
    {
      int n = base + ln;
      float4 v0 = make_float4(0.f, 0.f, 0.f, 0.f), v1 = v0;
      if (n < N_NODES) {
        const float4* hp = (const float4*)(h + (size_t)n * CIN + k0 + lk);
        v0 = hp[0];
        v1 = hp[1];
        if (NORM) {
          int g = batch[n];
          const float4* Ap = (const float4*)(An + (size_t)g * 128 + k0 + lk);
          const float4* Bp = (const float4*)(Bn + (size_t)g * 128 + k0 + lk);
          float4 A0 = Ap[0], A1 = Ap[1], B0 = Bp[0], B1 = Bp[1];
          v0.x = fmaxf(A0.x * v0.x + B0.x, 0.f);
          v0.y = fmaxf(A0.y * v0.y + B0.y, 0.f);
          v0.z = fmaxf(A0.z * v0.z + B0.z, 0.f);
          v0.w = fmaxf(A0.w * v0.w + B0.w, 0.f);
          v1.x = fmaxf(A1.x * v1.x + B1.x, 0.f);
          v1.y = fmaxf(A1.y * v1.y + B1.y, 0.f);
          v1.z = fmaxf(A1.z * v1.z + B1.z, 0.f);
          v1.w = fmaxf(A1.w * v1.w + B1.w, 0.f);
        }
      }
      *(float4*)&hs[ln][lk] = v0;
      *(float4*)&hs[ln][lk + 4] = v1;
      const float4* wp = (const float4*)(W + (size_t)(k0 + wk) * 128 + wc);
#pragma unroll
      for (int q = 0; q < 4; ++q) *(float4*)&Ws[wk][wc + q * 4] = wp[q];
    }
    __syncthreads();
#pragma unroll
    for (int kk = 0; kk < KT; kk += 4) {
      float4 hv[4];
#pragma unroll
      for (int i = 0; i < 4; ++i) hv[i] = *(const float4*)&hs[tn + 16 * i][kk];
#pragma unroll
      for (int dk = 0; dk < 4; ++dk) {
        float4 wa = *(const float4*)&Ws[kk + dk][tc * 4];
        float4 wb = *(const float4*)&Ws[kk + dk][64 + tc * 4];
#pragma unroll
        for (int i = 0; i < 4; ++i) {
          float hvv = (&hv[i].x)[dk];
          acc[i][0] += hvv * wa.x; acc[i][1] += hvv * wa.y;
          acc[i][2] += hvv * wa.z; acc[i][3] += hvv * wa.w;
          acc[i][4] += hvv * wb.x; acc[i][5] += hvv * wb.y;
          acc[i][6] += hvv * wb.z; acc[i][7] += hvv * wb.w;
        }
      }
    }
  }
  float4 b_lo = make_float4(0.f, 0.f, 0.f, 0.f), b_hi = b_lo;
  if (BIAS) {
    b_lo = *(const float4*)&bias[tc * 4];
    b_hi = *(const float4*)&bias[64 + tc * 4];
  }
#pragma unroll
  for (int i = 0; i < 4; ++i) {
    int n = base + tn + 16 * i;
    if (n < N_NODES) {
      float* op = hw + (size_t)n * 128;
      *(float4*)&op[tc * 4] =
          make_float4(acc[i][0] + b_lo.x, acc[i][1] + b_lo.y,
                      acc[i][2] + b_lo.z, acc[i][3] + b_lo.w);
      *(float4*)&op[64 + tc * 4] =
          make_float4(acc[i][4] + b_hi.x, acc[i][5] + b_hi.y,
                      acc[i][6] + b_hi.z, acc[i][7] + b_hi.w);
    }
  }
}

// ---------------------------------------------------------------------------
// 128-ch CSR gather: wave per node; 2 edges x 32 float4-lanes, 8-deep unroll.
// agg[n,c] = dinv[n]^2*hw[n,c] + bias[c] + sum_j ew_s[j]*hw[src_s[j],c]
// ---------------------------------------------------------------------------
__global__ __launch_bounds__(256) void k_gather(
    const float* __restrict__ hw, const float* __restrict__ ew_s,
    const int* __restrict__ src_s, const int* __restrict__ rowstart,
    const float* __restrict__ dinv, const float* __restrict__ bias,
    float* __restrict__ agg) {
  const int t = threadIdx.x;
  const int n = blockIdx.x * 4 + (t >> 6);
  if (n >= N_NODES) return;
  const int lane = t & 63;
  const int q = lane >> 5;   // edge-of-pair selector
  const int cl = lane & 31;  // float4 channel group (128 ch)
  const int rs = rowstart[n], re = rowstart[n + 1];
  const float4* hw4 = (const float4*)hw;
  float4 a0 = make_float4(0.f, 0.f, 0.f, 0.f);
  float4 a1 = make_float4(0.f, 0.f, 0.f, 0.f);
  float4 a2 = make_float4(0.f, 0.f, 0.f, 0.f);
  float4 a3 = make_float4(0.f, 0.f, 0.f, 0.f);
  int j = rs;
  for (; j + 8 <= re; j += 8) {
    int i0 = j + q, i1 = j + 2 + q, i2 = j + 4 + q, i3 = j + 6 + q;
    float w0 = ew_s[i0], w1 = ew_s[i1], w2 = ew_s[i2], w3 = ew_s[i3];
    float4 v0 = hw4[(size_t)src_s[i0] * 32 + cl];
    float4 v1 = hw4[(size_t)src_s[i1] * 32 + cl];
    float4 v2 = hw4[(size_t)src_s[i2] * 32 + cl];
    float4 v3 = hw4[(size_t)src_s[i3] * 32 + cl];
    fma4(a0, w0, v0);
    fma4(a1, w1, v1);
    fma4(a2, w2, v2);
    fma4(a3, w3, v3);
  }
  for (; j + 2 <= re; j += 2) {
    int i0 = j + q;
    fma4(a0, ew_s[i0], hw4[(size_t)src_s[i0] * 32 + cl]);
  }
  if (q == 0 && j < re) {
    fma4(a1, ew_s[j], hw4[(size_t)src_s[j] * 32 + cl]);
  }
  a0.x += a1.x + a2.x + a3.x;
  a0.y += a1.y + a2.y + a3.y;
  a0.z += a1.z + a2.z + a3.z;
  a0.w += a1.w + a2.w + a3.w;
  a0.x += __shfl_xor(a0.x, 32);
  a0.y += __shfl_xor(a0.y, 32);
  a0.z += __shfl_xor(a0.z, 32);
  a0.w += __shfl_xor(a0.w, 32);
  if (q == 0) {
    float dv = dinv[n];
    float4 hv = hw4[(size_t)n * 32 + cl];
    float4 bv = ((const float4*)bias)[cl];
    float4 r = make_float4(a0.x + dv * dv * hv.x + bv.x,
                           a0.y + dv * dv * hv.y + bv.y,
                           a0.z + dv * dv * hv.z + bv.z,
                           a0.w + dv * dv * hv.w + bv.w);
    ((float4*)agg)[(size_t)n * 32 + cl] = r;
  }
}

// ---------------------------------------------------------------------------
// GraphNorm stats only: A[g,c] = gw/sqrt(var+eps), B[g,c] = gb - A*ms*mean.
// One block (512 thr) per graph; batch sorted.
// ---------------------------------------------------------------------------
__global__ __launch_bounds__(512) void k_gstats(
    const float* __restrict__ h, const int* __restrict__ start,
    const float* __restrict__ gw, const float* __restrict__ gb,
    const float* __restrict__ gms, float* __restrict__ An,
    float* __restrict__ Bn) {
  int g = blockIdx.x;
  int s = start[g], e = start[g + 1];
  int t = threadIdx.x, p = t >> 7, c = t & 127;
  float sum = 0.f, sq = 0.f;
  for (int n = s + p; n < e; n += 4) {
    float v = h[(size_t)n * 128 + c];
    sum += v;
    sq += v * v;
  }
  __shared__ float S[4][128], Q[4][128];
  S[p][c] = sum;
  Q[p][c] = sq;
  __syncthreads();
  if (t < 128) {
    float cnt = (float)max(e - s, 1);
    float mean = (S[0][t] + S[1][t] + S[2][t] + S[3][t]) / cnt;
    float e2 = (Q[0][t] + Q[1][t] + Q[2][t] + Q[3][t]) / cnt;
    float ms = gms[t];
    float var = fmaxf(e2 - ms * (2.f - ms) * mean * mean, 0.f);
    float scale = gw[t] / sqrtf(var + EPS);
    An[(size_t)g * 128 + t] = scale;
    Bn[(size_t)g * 128 + t] = gb[t] - scale * ms * mean;
  }
}

// pooled[g,c] = mean over graph nodes of relu(A*h+B)
__global__ __launch_bounds__(512) void k_pool(
    const float* __restrict__ h, const int* __restrict__ start,
    const float* __restrict__ An, const float* __restrict__ Bn,
    float* __restrict__ pooled) {
  int g = blockIdx.x;
  int s = start[g], e = start[g + 1];
  int t = threadIdx.x, p = t >> 7, c = t & 127;
  float A = An[(size_t)g * 128 + c], B = Bn[(size_t)g * 128 + c];
  float sum = 0.f;
  for (int n = s + p; n < e; n += 4)
    sum += fmaxf(A * h[(size_t)n * 128 + c] + B, 0.f);
  __shared__ float S[4][128];
  S[p][c] = sum;
  __syncthreads();
  if (t < 128) {
    float cnt = (float)max(e - s, 1);
    pooled[g * 128 + t] = (S[0][t] + S[1][t] + S[2][t] + S[3][t]) / cnt;
  }
}

// MLP head: 128 ->256 (BN,ReLU) ->128 (BN,ReLU) ->1; writes out[g] and h2.
__global__ __launch_bounds__(256) void k_head(
    const float* __restrict__ pooled, const float* __restrict__ w0,
    const float* __restrict__ b0, const float* __restrict__ g0,
    const float* __restrict__ bb0, const float* __restrict__ w1,
    const float* __restrict__ b1, const float* __restrict__ g1,
    const float* __restrict__ bb1, const float* __restrict__ ow,
    const float* __restrict__ ob, float* __restrict__ out) {
  __shared__ float p[128], h1[256], h2[128];
  int g = blockIdx.x, t = threadIdx.x;
  const float inv = 1.0f / sqrtf(1.0f + EPS);
  if (t < 128) p[t] = pooled[g * 128 + t];
  __syncthreads();
  {
    float acc = b0[t];
#pragma unroll 8
    for (int k = 0; k < 128; ++k) acc += p[k] * w0[k * 256 + t];
    h1[t] = fmaxf(acc * inv * g0[t] + bb0[t], 0.f);
  }
  __syncthreads();
  if (t < 128) {
    float acc = b1[t];
#pragma unroll 8
    for (int k = 0; k < 256; ++k) acc += h1[k] * w1[k * 128 + t];
    float v = fmaxf(acc * inv * g1[t] + bb1[t], 0.f);
    h2[t] = v;
    out[N_GRAPHS + g * 128 + t] = v;
  }
  __syncthreads();
  if (t < 64) {
    float v = h2[t] * ow[t] + h2[t + 64] * ow[t + 64];
#pragma unroll
    for (int off = 32; off; off >>= 1) v += __shfl_down(v, off);
    if (t == 0) out[g] = v + ob[0];
  }
}

// ---------------------------------------------------------------------------
extern "C" void kernel_launch(void* const* d_in, const int* in_sizes, int n_in,
                              void* d_out, int out_size, void* d_ws,
                              size_t ws_size, hipStream_t stream) {
  const float* x = (const float*)d_in[0];
  const float* edge_attr = (const float*)d_in[1];
  const float* em_w1 = (const float*)d_in[2];
  const float* em_b1 = (const float*)d_in[3];
  const float* em_w2 = (const float*)d_in[4];
  const float* em_b2 = (const float*)d_in[5];
  const float* conv_w[3] = {(const float*)d_in[6], (const float*)d_in[8],
                            (const float*)d_in[10]};
  const float* conv_b[3] = {(const float*)d_in[7], (const float*)d_in[9],
                            (const float*)d_in[11]};
  const float* gn_w[3] = {(const float*)d_in[12], (const float*)d_in[15],
                          (const float*)d_in[18]};
  const float* gn_b[3] = {(const float*)d_in[13], (const float*)d_in[16],
                          (const float*)d_in[19]};
  const float* gn_ms[3] = {(const float*)d_in[14], (const float*)d_in[17],
                           (const float*)d_in[20]};
  const float* lin_w0 = (const float*)d_in[21];
  const float* lin_b0 = (const float*)d_in[22];
  const float* bn_g0 = (const float*)d_in[23];
  const float* bn_b0 = (const float*)d_in[24];
  const float* lin_w1 = (const float*)d_in[25];
  const float* lin_b1 = (const float*)d_in[26];
  const float* bn_g1 = (const float*)d_in[27];
  const float* bn_b1 = (const float*)d_in[28];
  const float* out_w = (const float*)d_in[29];
  const float* out_b = (const float*)d_in[30];
  const int* edge_index = (const int*)d_in[31];
  const int* batch = (const int*)d_in[32];
  const int* src = edge_index;
  const int* tgt = edge_index + N_EDGES;

  char* w = (char*)d_ws;
  size_t off = 0;
  auto carve = [&](size_t bytes) {
    void* p = w + off;
    off = (off + bytes + 511) & ~(size_t)511;
    return p;
  };
  float* ew = (float*)carve((size_t)N_EDGES * 4);
  int* rank = (int*)carve((size_t)N_EDGES * 4);
  float* dinv = (float*)carve((size_t)N_NODES * 4);
  int* rowcnt = (int*)carve((size_t)N_NODES * 4);
  int* rowstart = (int*)carve((size_t)(N_NODES + 1) * 4);
  int* bsum = (int*)carve((size_t)SCAN_BLOCKS * 4);
  int* boff = (int*)carve((size_t)512 * 4);
  int* src_s = (int*)carve((size_t)N_EDGES * 4);
  float* ew_s = (float*)carve((size_t)N_EDGES * 4);
  int* start = (int*)carve((N_GRAPHS + 1) * 4);
  float* AB = (float*)carve((size_t)6 * N_GRAPHS * 128 * 4);
  float* big0 = (float*)carve((size_t)N_NODES * 128 * 4);
  float* big1 = (float*)carve((size_t)N_NODES * 128 * 4);
  float* big2 = (float*)carve((size_t)N_NODES * 128 * 4);
  float* pooled = (float*)carve((size_t)N_GRAPHS * 128 * 4);

  float* A0 = AB, *B0 = AB + N_GRAPHS * 128;
  float* A1 = AB + 2 * N_GRAPHS * 128, *B1 = AB + 3 * N_GRAPHS * 128;
  float* A2 = AB + 4 * N_GRAPHS * 128, *B2 = AB + 5 * N_GRAPHS * 128;

  hipMemsetAsync(rowcnt, 0, (size_t)N_NODES * 4, stream);

  k_edge_mlp<<<(N_EDGES + 255) / 256, 256, 0, stream>>>(
      edge_attr, em_w1, em_b1, em_w2, em_b2, tgt, ew, rowcnt, rank);
  k_scan1<<<SCAN_BLOCKS, 256, 0, stream>>>(rowcnt, bsum);
  k_scan2<<<1, 512, 0, stream>>>(bsum, boff);
  k_scan3<<<SCAN_BLOCKS, 256, 0, stream>>>(rowcnt, boff, rowstart);
  k_fill<<<(N_EDGES + 255) / 256, 256, 0, stream>>>(src, tgt, ew, rank,
                                                    rowstart, src_s, ew_s);
  k_deg<<<(N_NODES + 255) / 256, 256, 0, stream>>>(ew_s, rowstart, dinv);
  k_scale<<<(N_NODES + 3) / 4, 256, 0, stream>>>(ew_s, src_s, rowstart, dinv);
  k_starts<<<1, 512, 0, stream>>>(batch, start);

  const int ggrid = (N_NODES + 3) / 4;
  const int hwgrid = (N_NODES + 63) / 64;

  // layer 0: aggregate-first (exact: (A_hat x) W = A_hat (x W)).
  // aggx aliases big2 (64-ch, 25.6 MB).
  k_gather64<<<ggrid, 256, 0, stream>>>(x, ew_s, src_s, rowstart, dinv, big2);
  k_hw<64, false, true><<<hwgrid, 256, 0, stream>>>(
      big2, conv_w[0], nullptr, nullptr, nullptr, conv_b[0], big1);
  k_gstats<<<N_GRAPHS, 512, 0, stream>>>(big1, start, gn_w[0], gn_b[0],
                                         gn_ms[0], A0, B0);
  // layer 1: transform fused into GEMM staging; gather-after.
  k_hw<128, true, false><<<hwgrid, 256, 0, stream>>>(
      big1, conv_w[1], batch, A0, B0, nullptr, big0);
  k_gather<<<ggrid, 256, 0, stream>>>(big0, ew_s, src_s, rowstart, dinv,
                                      conv_b[1], big2);
  k_gstats<<<N_GRAPHS, 512, 0, stream>>>(big2, start, gn_w[1], gn_b[1],
                                         gn_ms[1], A1, B1);
  // layer 2
  k_hw<128, true, false><<<hwgrid, 256, 0, stream>>>(
      big2, conv_w[2], batch, A1, B1, nullptr, big0);
  k_gather<<<ggrid, 256, 0, stream>>>(big0, ew_s, src_s, rowstart, dinv,
                                      conv_b[2], big1);
  k_gstats<<<N_GRAPHS, 512, 0, stream>>>(big1, start, gn_w[2], gn_b[2],
                                         gn_ms[2], A2, B2);

  k_pool<<<N_GRAPHS, 512, 0, stream>>>(big1, start, A2, B2, pooled);
  k_head<<<N_GRAPHS, 256, 0, stream>>>(pooled, lin_w0, lin_b0, bn_g0, bn_b0,
                                       lin_w1, lin_b1, bn_g1, bn_b1, out_w,
                                       out_b, (float*)d_out);
}

// Round 7
// 636.704 us; speedup vs baseline: 4.4240x; 1.1650x over previous
//
#include <hip/hip_runtime.h>

#define N_NODES 100000
#define N_EDGES 1600000
#define N_GRAPHS 256
#define EPS 1e-5f

#define SCAN_BLOCKS ((N_NODES + 255) / 256)  // 391

__device__ __forceinline__ void fma4(float4& a, float s, const float4& w) {
  a.x += s * w.x; a.y += s * w.y; a.z += s * w.z; a.w += s * w.w;
}

__device__ __forceinline__ unsigned short f2bf(float f) {
  union { float f; unsigned u; } x;
  x.f = f;
  unsigned r = x.u + 0x7FFF + ((x.u >> 16) & 1);  // RNE
  return (unsigned short)(r >> 16);
}
__device__ __forceinline__ unsigned packbf(float a, float b) {
  return (unsigned)f2bf(a) | ((unsigned)f2bf(b) << 16);
}
__device__ __forceinline__ float4 bf4(uint2 v) {
  union { unsigned u; float f; } a, b, c, d;
  a.u = v.x << 16;
  b.u = v.x & 0xFFFF0000u;
  c.u = v.y << 16;
  d.u = v.y & 0xFFFF0000u;
  return make_float4(a.f, b.f, c.f, d.f);
}

// ---------------------------------------------------------------------------
// Edge MLP + within-row rank histogram (the only atomic pass).
// ---------------------------------------------------------------------------
__global__ __launch_bounds__(256) void k_edge_mlp(
    const float* __restrict__ ea, const float* __restrict__ w1,
    const float* __restrict__ b1, const float* __restrict__ w2,
    const float* __restrict__ b2, const int* __restrict__ tgt,
    float* __restrict__ ew, int* __restrict__ rowcnt,
    int* __restrict__ rank) {
  __shared__ float W1[128], B1[16], W2[16];
  int t = threadIdx.x;
  if (t < 128) W1[t] = w1[t];
  if (t < 16) { B1[t] = b1[t]; W2[t] = w2[t]; }
  __syncthreads();
  int e = blockIdx.x * 256 + t;
  if (e >= N_EDGES) return;
  const float4* ap = (const float4*)(ea + (size_t)e * 8);
  float4 a0 = ap[0], a1 = ap[1];
  float a[8] = {a0.x, a0.y, a0.z, a0.w, a1.x, a1.y, a1.z, a1.w};
  float out = b2[0];
#pragma unroll
  for (int i = 0; i < 16; ++i) {
    float h = B1[i];
#pragma unroll
    for (int j = 0; j < 8; ++j) h += a[j] * W1[i * 8 + j];
    out += fmaxf(h, 0.f) * W2[i];
  }
  ew[e] = out;
  rank[e] = atomicAdd(&rowcnt[tgt[e]], 1);
}

// x (f32) -> xb (bf16), 8 elems/thread
__global__ __launch_bounds__(256) void k_cvt(const float* __restrict__ x,
                                             unsigned* __restrict__ xb) {
  int i = blockIdx.x * 256 + threadIdx.x;
  if (i >= N_NODES * 64 / 8) return;
  const float4* p = (const float4*)(x + (size_t)i * 8);
  float4 a = p[0], b = p[1];
  uint4 o;
  o.x = packbf(a.x, a.y);
  o.y = packbf(a.z, a.w);
  o.z = packbf(b.x, b.y);
  o.w = packbf(b.z, b.w);
  ((uint4*)xb)[i] = o;
}

// ---------------------------------------------------------------------------
// Parallel 3-phase exclusive scan of rowcnt -> rowstart[0..N]
// ---------------------------------------------------------------------------
__global__ __launch_bounds__(256) void k_scan1(const int* __restrict__ cnt,
                                               int* __restrict__ bsum) {
  int i = blockIdx.x * 256 + threadIdx.x;
  int v = (i < N_NODES) ? cnt[i] : 0;
#pragma unroll
  for (int off = 32; off; off >>= 1) v += __shfl_down(v, off);
  __shared__ int ws[4];
  if ((threadIdx.x & 63) == 0) ws[threadIdx.x >> 6] = v;
  __syncthreads();
  if (threadIdx.x == 0) bsum[blockIdx.x] = ws[0] + ws[1] + ws[2] + ws[3];
}

__global__ __launch_bounds__(512) void k_scan2(const int* __restrict__ bsum,
                                               int* __restrict__ boff) {
  __shared__ int s[512];
  int t = threadIdx.x;
  s[t] = (t < SCAN_BLOCKS) ? bsum[t] : 0;
  __syncthreads();
  for (int off = 1; off < 512; off <<= 1) {
    int u = (t >= off) ? s[t - off] : 0;
    __syncthreads();
    s[t] += u;
    __syncthreads();
  }
  boff[t] = (t == 0) ? 0 : s[t - 1];
}

__global__ __launch_bounds__(256) void k_scan3(const int* __restrict__ cnt,
                                               const int* __restrict__ boff,
                                               int* __restrict__ rowstart) {
  __shared__ int s[256];
  int t = threadIdx.x;
  int i = blockIdx.x * 256 + t;
  int v = (i < N_NODES) ? cnt[i] : 0;
  s[t] = v;
  __syncthreads();
  for (int off = 1; off < 256; off <<= 1) {
    int u = (t >= off) ? s[t - off] : 0;
    __syncthreads();
    s[t] += u;
    __syncthreads();
  }
  if (i < N_NODES) {
    int pre = boff[blockIdx.x] + s[t] - v;  // exclusive
    rowstart[i] = pre;
    if (i == N_NODES - 1) rowstart[N_NODES] = pre + v;
  }
}

// Atomic-free CSR fill: slot = rowstart[tgt] + rank (unique by construction).
__global__ __launch_bounds__(256) void k_fill(
    const int* __restrict__ src, const int* __restrict__ tgt,
    const float* __restrict__ ew, const int* __restrict__ rank,
    const int* __restrict__ rowstart, int* __restrict__ src_s,
    float* __restrict__ ew_s) {
  int e = blockIdx.x * 256 + threadIdx.x;
  if (e >= N_EDGES) return;
  int p = rowstart[tgt[e]] + rank[e];
  src_s[p] = src[e];
  ew_s[p] = ew[e];
}

// deg row-sum fused with dinv: dinv[n] = rsqrt(1 + sum ew_row)
__global__ __launch_bounds__(256) void k_deg(const float* __restrict__ ew_s,
                                             const int* __restrict__ rowstart,
                                             float* __restrict__ dinv) {
  int n = blockIdx.x * 256 + threadIdx.x;
  if (n >= N_NODES) return;
  int rs = rowstart[n], re = rowstart[n + 1];
  float d = 1.f;
  for (int j = rs; j < re; ++j) d += ew_s[j];
  dinv[n] = d > 0.f ? rsqrtf(d) : 0.f;
}

// ew_s[j] *= dinv[src_s[j]] * dinv[row]; wave per node.
__global__ __launch_bounds__(256) void k_scale(float* __restrict__ ew_s,
                                               const int* __restrict__ src_s,
                                               const int* __restrict__ rowstart,
                                               const float* __restrict__ dinv) {
  int n = blockIdx.x * 4 + (threadIdx.x >> 6);
  if (n >= N_NODES) return;
  int lane = threadIdx.x & 63;
  int rs = rowstart[n], re = rowstart[n + 1];
  float dv = dinv[n];
  for (int j = rs + lane; j < re; j += 64) ew_s[j] *= dinv[src_s[j]] * dv;
}

// graph segment starts
__global__ void k_starts(const int* __restrict__ batch, int* __restrict__ start) {
  int g = blockIdx.x * blockDim.x + threadIdx.x;
  if (g > N_GRAPHS) return;
  int lo = 0, hi = N_NODES;
  while (lo < hi) {
    int mid = (lo + hi) >> 1;
    if (batch[mid] < g) lo = mid + 1; else hi = mid;
  }
  start[g] = lo;
}

// ---------------------------------------------------------------------------
// 64-ch CSR gather on bf16 x: aggx[n] = dinv^2*x[n] + sum ew*x[src]
// wave/node; 4 edges x 16 uint2-lanes (4 ch each).
// ---------------------------------------------------------------------------
__global__ __launch_bounds__(256) void k_gather64b(
    const unsigned* __restrict__ xb, const float* __restrict__ ew_s,
    const int* __restrict__ src_s, const int* __restrict__ rowstart,
    const float* __restrict__ dinv, float* __restrict__ out) {
  const int t = threadIdx.x;
  const int n = blockIdx.x * 4 + (t >> 6);
  if (n >= N_NODES) return;
  const int lane = t & 63;
  const int q = lane >> 4;   // edge slot 0..3
  const int cl = lane & 15;  // uint2 group over 64 ch
  const int rs = rowstart[n], re = rowstart[n + 1];
  const uint2* x2 = (const uint2*)xb;
  float4 a0 = make_float4(0.f, 0.f, 0.f, 0.f);
  float4 a1 = make_float4(0.f, 0.f, 0.f, 0.f);
  int j = rs;
  for (; j + 8 <= re; j += 8) {
    int i0 = j + q, i1 = j + 4 + q;
    float w0 = ew_s[i0], w1 = ew_s[i1];
    float4 v0 = bf4(x2[(size_t)src_s[i0] * 16 + cl]);
    float4 v1 = bf4(x2[(size_t)src_s[i1] * 16 + cl]);
    fma4(a0, w0, v0);
    fma4(a1, w1, v1);
  }
  for (; j + 4 <= re; j += 4) {
    int i0 = j + q;
    fma4(a0, ew_s[i0], bf4(x2[(size_t)src_s[i0] * 16 + cl]));
  }
  if (j + q < re) {
    fma4(a1, ew_s[j + q], bf4(x2[(size_t)src_s[j + q] * 16 + cl]));
  }
  a0.x += a1.x; a0.y += a1.y; a0.z += a1.z; a0.w += a1.w;
#pragma unroll
  for (int m = 16; m <= 32; m <<= 1) {
    a0.x += __shfl_xor(a0.x, m);
    a0.y += __shfl_xor(a0.y, m);
    a0.z += __shfl_xor(a0.z, m);
    a0.w += __shfl_xor(a0.w, m);
  }
  if (q == 0) {
    float dv = dinv[n];
    float4 hv = bf4(x2[(size_t)n * 16 + cl]);
    float4 r = make_float4(a0.x + dv * dv * hv.x, a0.y + dv * dv * hv.y,
                           a0.z + dv * dv * hv.z, a0.w + dv * dv * hv.w);
    ((float4*)out)[(size_t)n * 16 + cl] = r;
  }
}

// ---------------------------------------------------------------------------
// hw = f(h) @ W  -- register-tiled GEMM, optional fused NORM input transform,
// optional +bias, optional bf16 output (for gather consumption).
// ---------------------------------------------------------------------------
template <int CIN, bool NORM, bool BIAS, bool BFOUT>
__global__ __launch_bounds__(256) void k_hw(
    const float* __restrict__ h, const float* __restrict__ W,
    const int* __restrict__ batch, const float* __restrict__ An,
    const float* __restrict__ Bn, const float* __restrict__ bias,
    void* __restrict__ hw) {
  constexpr int KT = 32;
  __shared__ float hs[64][36];
  __shared__ float Ws[KT][128];
  const int t = threadIdx.x;
  const int tn = t & 15, tc = t >> 4;
  const int base = blockIdx.x * 64;

  float acc[4][8];
#pragma unroll
  for (int i = 0; i < 4; ++i)
#pragma unroll
    for (int j = 0; j < 8; ++j) acc[i][j] = 0.f;

  const int ln = t >> 2;        // staging node 0..63
  const int lk = (t & 3) * 8;   // staging k offset within tile
  const int wk = t >> 3;        // staging k row 0..31
  const int wc = (t & 7) * 16;  // staging c offset

  for (int k0 = 0; k0 < CIN; k0 += KT) {
    __syncthreads();
    {
      int n = base + ln;
      float4 v0 = make_float4(0.f, 0.f, 0.f, 0.f), v1 = v0;
      if (n < N_NODES) {
        const float4* hp = (const float4*)(h + (size_t)n * CIN + k0 + lk);
        v0 = hp[0];
        v1 = hp[1];
        if (NORM) {
          int g = batch[n];
          const float4* Ap = (const float4*)(An + (size_t)g * 128 + k0 + lk);
          const float4* Bp = (const float4*)(Bn + (size_t)g * 128 + k0 + lk);
          float4 A0 = Ap[0], A1 = Ap[1], B0 = Bp[0], B1 = Bp[1];
          v0.x = fmaxf(A0.x * v0.x + B0.x, 0.f);
          v0.y = fmaxf(A0.y * v0.y + B0.y, 0.f);
          v0.z = fmaxf(A0.z * v0.z + B0.z, 0.f);
          v0.w = fmaxf(A0.w * v0.w + B0.w, 0.f);
          v1.x = fmaxf(A1.x * v1.x + B1.x, 0.f);
          v1.y = fmaxf(A1.y * v1.y + B1.y, 0.f);
          v1.z = fmaxf(A1.z * v1.z + B1.z, 0.f);
          v1.w = fmaxf(A1.w * v1.w + B1.w, 0.f);
        }
      }
      *(float4*)&hs[ln][lk] = v0;
      *(float4*)&hs[ln][lk + 4] = v1;
      const float4* wp = (const float4*)(W + (size_t)(k0 + wk) * 128 + wc);
#pragma unroll
      for (int q = 0; q < 4; ++q) *(float4*)&Ws[wk][wc + q * 4] = wp[q];
    }
    __syncthreads();
#pragma unroll
    for (int kk = 0; kk < KT; kk += 4) {
      float4 hv[4];
#pragma unroll
      for (int i = 0; i < 4; ++i) hv[i] = *(const float4*)&hs[tn + 16 * i][kk];
#pragma unroll
      for (int dk = 0; dk < 4; ++dk) {
        float4 wa = *(const float4*)&Ws[kk + dk][tc * 4];
        float4 wb = *(const float4*)&Ws[kk + dk][64 + tc * 4];
#pragma unroll
        for (int i = 0; i < 4; ++i) {
          float hvv = (&hv[i].x)[dk];
          acc[i][0] += hvv * wa.x; acc[i][1] += hvv * wa.y;
          acc[i][2] += hvv * wa.z; acc[i][3] += hvv * wa.w;
          acc[i][4] += hvv * wb.x; acc[i][5] += hvv * wb.y;
          acc[i][6] += hvv * wb.z; acc[i][7] += hvv * wb.w;
        }
      }
    }
  }
  float4 b_lo = make_float4(0.f, 0.f, 0.f, 0.f), b_hi = b_lo;
  if (BIAS) {
    b_lo = *(const float4*)&bias[tc * 4];
    b_hi = *(const float4*)&bias[64 + tc * 4];
  }
#pragma unroll
  for (int i = 0; i < 4; ++i) {
    int n = base + tn + 16 * i;
    if (n < N_NODES) {
      if (BFOUT) {
        unsigned* op = (unsigned*)hw + (size_t)n * 64;  // 128 bf16 = 64 u32
        uint2 lo, hi;
        lo.x = packbf(acc[i][0] + b_lo.x, acc[i][1] + b_lo.y);
        lo.y = packbf(acc[i][2] + b_lo.z, acc[i][3] + b_lo.w);
        hi.x = packbf(acc[i][4] + b_hi.x, acc[i][5] + b_hi.y);
        hi.y = packbf(acc[i][6] + b_hi.z, acc[i][7] + b_hi.w);
        ((uint2*)op)[tc] = lo;
        ((uint2*)op)[16 + tc] = hi;
      } else {
        float* op = (float*)hw + (size_t)n * 128;
        *(float4*)&op[tc * 4] =
            make_float4(acc[i][0] + b_lo.x, acc[i][1] + b_lo.y,
                        acc[i][2] + b_lo.z, acc[i][3] + b_lo.w);
        *(float4*)&op[64 + tc * 4] =
            make_float4(acc[i][4] + b_hi.x, acc[i][5] + b_hi.y,
                        acc[i][6] + b_hi.z, acc[i][7] + b_hi.w);
      }
    }
  }
}

// ---------------------------------------------------------------------------
// 128-ch CSR gather on bf16 table: wave/node; 2 edges x 32 uint2-lanes,
// 8-deep unroll. agg f32 = dinv^2*hw[n] + bias + sum ew*hw[src]
// ---------------------------------------------------------------------------
__global__ __launch_bounds__(256) void k_gatherb(
    const unsigned* __restrict__ hwb, const float* __restrict__ ew_s,
    const int* __restrict__ src_s, const int* __restrict__ rowstart,
    const float* __restrict__ dinv, const float* __restrict__ bias,
    float* __restrict__ agg) {
  const int t = threadIdx.x;
  const int n = blockIdx.x * 4 + (t >> 6);
  if (n >= N_NODES) return;
  const int lane = t & 63;
  const int q = lane >> 5;   // edge-of-pair selector
  const int cl = lane & 31;  // uint2 group (4 ch) over 128 ch
  const int rs = rowstart[n], re = rowstart[n + 1];
  const uint2* hb = (const uint2*)hwb;
  float4 a0 = make_float4(0.f, 0.f, 0.f, 0.f);
  float4 a1 = make_float4(0.f, 0.f, 0.f, 0.f);
  float4 a2 = make_float4(0.f, 0.f, 0.f, 0.f);
  float4 a3 = make_float4(0.f, 0.f, 0.f, 0.f);
  int j = rs;
  for (; j + 8 <= re; j += 8) {
    int i0 = j + q, i1 = j + 2 + q, i2 = j + 4 + q, i3 = j + 6 + q;
    float w0 = ew_s[i0], w1 = ew_s[i1], w2 = ew_s[i2], w3 = ew_s[i3];
    float4 v0 = bf4(hb[(size_t)src_s[i0] * 32 + cl]);
    float4 v1 = bf4(hb[(size_t)src_s[i1] * 32 + cl]);
    float4 v2 = bf4(hb[(size_t)src_s[i2] * 32 + cl]);
    float4 v3 = bf4(hb[(size_t)src_s[i3] * 32 + cl]);
    fma4(a0, w0, v0);
    fma4(a1, w1, v1);
    fma4(a2, w2, v2);
    fma4(a3, w3, v3);
  }
  for (; j + 2 <= re; j += 2) {
    int i0 = j + q;
    fma4(a0, ew_s[i0], bf4(hb[(size_t)src_s[i0] * 32 + cl]));
  }
  if (q == 0 && j < re) {
    fma4(a1, ew_s[j], bf4(hb[(size_t)src_s[j] * 32 + cl]));
  }
  a0.x += a1.x + a2.x + a3.x;
  a0.y += a1.y + a2.y + a3.y;
  a0.z += a1.z + a2.z + a3.z;
  a0.w += a1.w + a2.w + a3.w;
  a0.x += __shfl_xor(a0.x, 32);
  a0.y += __shfl_xor(a0.y, 32);
  a0.z += __shfl_xor(a0.z, 32);
  a0.w += __shfl_xor(a0.w, 32);
  if (q == 0) {
    float dv = dinv[n];
    float4 hv = bf4(hb[(size_t)n * 32 + cl]);
    float4 bv = ((const float4*)bias)[cl];
    float4 r = make_float4(a0.x + dv * dv * hv.x + bv.x,
                           a0.y + dv * dv * hv.y + bv.y,
                           a0.z + dv * dv * hv.z + bv.z,
                           a0.w + dv * dv * hv.w + bv.w);
    ((float4*)agg)[(size_t)n * 32 + cl] = r;
  }
}

// ---------------------------------------------------------------------------
// GraphNorm stats only: A[g,c] = gw/sqrt(var+eps), B[g,c] = gb - A*ms*mean.
// ---------------------------------------------------------------------------
__global__ __launch_bounds__(512) void k_gstats(
    const float* __restrict__ h, const int* __restrict__ start,
    const float* __restrict__ gw, const float* __restrict__ gb,
    const float* __restrict__ gms, float* __restrict__ An,
    float* __restrict__ Bn) {
  int g = blockIdx.x;
  int s = start[g], e = start[g + 1];
  int t = threadIdx.x, p = t >> 7, c = t & 127;
  float sum = 0.f, sq = 0.f;
  for (int n = s + p; n < e; n += 4) {
    float v = h[(size_t)n * 128 + c];
    sum += v;
    sq += v * v;
  }
  __shared__ float S[4][128], Q[4][128];
  S[p][c] = sum;
  Q[p][c] = sq;
  __syncthreads();
  if (t < 128) {
    float cnt = (float)max(e - s, 1);
    float mean = (S[0][t] + S[1][t] + S[2][t] + S[3][t]) / cnt;
    float e2 = (Q[0][t] + Q[1][t] + Q[2][t] + Q[3][t]) / cnt;
    float ms = gms[t];
    float var = fmaxf(e2 - ms * (2.f - ms) * mean * mean, 0.f);
    float scale = gw[t] / sqrtf(var + EPS);
    An[(size_t)g * 128 + t] = scale;
    Bn[(size_t)g * 128 + t] = gb[t] - scale * ms * mean;
  }
}

// pooled[g,c] = mean over graph nodes of relu(A*h+B)
__global__ __launch_bounds__(512) void k_pool(
    const float* __restrict__ h, const int* __restrict__ start,
    const float* __restrict__ An, const float* __restrict__ Bn,
    float* __restrict__ pooled) {
  int g = blockIdx.x;
  int s = start[g], e = start[g + 1];
  int t = threadIdx.x, p = t >> 7, c = t & 127;
  float A = An[(size_t)g * 128 + c], B = Bn[(size_t)g * 128 + c];
  float sum = 0.f;
  for (int n = s + p; n < e; n += 4)
    sum += fmaxf(A * h[(size_t)n * 128 + c] + B, 0.f);
  __shared__ float S[4][128];
  S[p][c] = sum;
  __syncthreads();
  if (t < 128) {
    float cnt = (float)max(e - s, 1);
    pooled[g * 128 + t] = (S[0][t] + S[1][t] + S[2][t] + S[3][t]) / cnt;
  }
}

// MLP head: 128 ->256 (BN,ReLU) ->128 (BN,ReLU) ->1; writes out[g] and h2.
__global__ __launch_bounds__(256) void k_head(
    const float* __restrict__ pooled, const float* __restrict__ w0,
    const float* __restrict__ b0, const float* __restrict__ g0,
    const float* __restrict__ bb0, const float* __restrict__ w1,
    const float* __restrict__ b1, const float* __restrict__ g1,
    const float* __restrict__ bb1, const float* __restrict__ ow,
    const float* __restrict__ ob, float* __restrict__ out) {
  __shared__ float p[128], h1[256], h2[128];
  int g = blockIdx.x, t = threadIdx.x;
  const float inv = 1.0f / sqrtf(1.0f + EPS);
  if (t < 128) p[t] = pooled[g * 128 + t];
  __syncthreads();
  {
    float acc = b0[t];
#pragma unroll 8
    for (int k = 0; k < 128; ++k) acc += p[k] * w0[k * 256 + t];
    h1[t] = fmaxf(acc * inv * g0[t] + bb0[t], 0.f);
  }
  __syncthreads();
  if (t < 128) {
    float acc = b1[t];
#pragma unroll 8
    for (int k = 0; k < 256; ++k) acc += h1[k] * w1[k * 128 + t];
    float v = fmaxf(acc * inv * g1[t] + bb1[t], 0.f);
    h2[t] = v;
    out[N_GRAPHS + g * 128 + t] = v;
  }
  __syncthreads();
  if (t < 64) {
    float v = h2[t] * ow[t] + h2[t + 64] * ow[t + 64];
#pragma unroll
    for (int off = 32; off; off >>= 1) v += __shfl_down(v, off);
    if (t == 0) out[g] = v + ob[0];
  }
}

// ---------------------------------------------------------------------------
extern "C" void kernel_launch(void* const* d_in, const int* in_sizes, int n_in,
                              void* d_out, int out_size, void* d_ws,
                              size_t ws_size, hipStream_t stream) {
  const float* x = (const float*)d_in[0];
  const float* edge_attr = (const float*)d_in[1];
  const float* em_w1 = (const float*)d_in[2];
  const float* em_b1 = (const float*)d_in[3];
  const float* em_w2 = (const float*)d_in[4];
  const float* em_b2 = (const float*)d_in[5];
  const float* conv_w[3] = {(const float*)d_in[6], (const float*)d_in[8],
                            (const float*)d_in[10]};
  const float* conv_b[3] = {(const float*)d_in[7], (const float*)d_in[9],
                            (const float*)d_in[11]};
  const float* gn_w[3] = {(const float*)d_in[12], (const float*)d_in[15],
                          (const float*)d_in[18]};
  const float* gn_b[3] = {(const float*)d_in[13], (const float*)d_in[16],
                          (const float*)d_in[19]};
  const float* gn_ms[3] = {(const float*)d_in[14], (const float*)d_in[17],
                           (const float*)d_in[20]};
  const float* lin_w0 = (const float*)d_in[21];
  const float* lin_b0 = (const float*)d_in[22];
  const float* bn_g0 = (const float*)d_in[23];
  const float* bn_b0 = (const float*)d_in[24];
  const float* lin_w1 = (const float*)d_in[25];
  const float* lin_b1 = (const float*)d_in[26];
  const float* bn_g1 = (const float*)d_in[27];
  const float* bn_b1 = (const float*)d_in[28];
  const float* out_w = (const float*)d_in[29];
  const float* out_b = (const float*)d_in[30];
  const int* edge_index = (const int*)d_in[31];
  const int* batch = (const int*)d_in[32];
  const int* src = edge_index;
  const int* tgt = edge_index + N_EDGES;

  char* w = (char*)d_ws;
  size_t off = 0;
  auto carve = [&](size_t bytes) {
    void* p = w + off;
    off = (off + bytes + 511) & ~(size_t)511;
    return p;
  };
  float* ew = (float*)carve((size_t)N_EDGES * 4);
  int* rank = (int*)carve((size_t)N_EDGES * 4);
  float* dinv = (float*)carve((size_t)N_NODES * 4);
  int* rowcnt = (int*)carve((size_t)N_NODES * 4);
  int* rowstart = (int*)carve((size_t)(N_NODES + 1) * 4);
  int* bsum = (int*)carve((size_t)SCAN_BLOCKS * 4);
  int* boff = (int*)carve((size_t)512 * 4);
  int* src_s = (int*)carve((size_t)N_EDGES * 4);
  float* ew_s = (float*)carve((size_t)N_EDGES * 4);
  int* start = (int*)carve((N_GRAPHS + 1) * 4);
  float* AB = (float*)carve((size_t)6 * N_GRAPHS * 128 * 4);
  unsigned* xb = (unsigned*)carve((size_t)N_NODES * 64 * 2);   // bf16 x
  unsigned* hwb = (unsigned*)carve((size_t)N_NODES * 128 * 2); // bf16 hw
  float* big1 = (float*)carve((size_t)N_NODES * 128 * 4);
  float* big2 = (float*)carve((size_t)N_NODES * 128 * 4);
  float* pooled = (float*)carve((size_t)N_GRAPHS * 128 * 4);

  float* A0 = AB, *B0 = AB + N_GRAPHS * 128;
  float* A1 = AB + 2 * N_GRAPHS * 128, *B1 = AB + 3 * N_GRAPHS * 128;
  float* A2 = AB + 4 * N_GRAPHS * 128, *B2 = AB + 5 * N_GRAPHS * 128;

  hipMemsetAsync(rowcnt, 0, (size_t)N_NODES * 4, stream);

  k_edge_mlp<<<(N_EDGES + 255) / 256, 256, 0, stream>>>(
      edge_attr, em_w1, em_b1, em_w2, em_b2, tgt, ew, rowcnt, rank);
  k_cvt<<<(N_NODES * 64 / 8 + 255) / 256, 256, 0, stream>>>(x, xb);
  k_scan1<<<SCAN_BLOCKS, 256, 0, stream>>>(rowcnt, bsum);
  k_scan2<<<1, 512, 0, stream>>>(bsum, boff);
  k_scan3<<<SCAN_BLOCKS, 256, 0, stream>>>(rowcnt, boff, rowstart);
  k_fill<<<(N_EDGES + 255) / 256, 256, 0, stream>>>(src, tgt, ew, rank,
                                                    rowstart, src_s, ew_s);
  k_deg<<<(N_NODES + 255) / 256, 256, 0, stream>>>(ew_s, rowstart, dinv);
  k_scale<<<(N_NODES + 3) / 4, 256, 0, stream>>>(ew_s, src_s, rowstart, dinv);
  k_starts<<<1, 512, 0, stream>>>(batch, start);

  const int ggrid = (N_NODES + 3) / 4;
  const int hwgrid = (N_NODES + 63) / 64;

  // layer 0: aggregate-first on bf16 x; GEMM f32 out (big1 = pre-norm h1).
  k_gather64b<<<ggrid, 256, 0, stream>>>(xb, ew_s, src_s, rowstart, dinv,
                                         big2);
  k_hw<64, false, true, false><<<hwgrid, 256, 0, stream>>>(
      big2, conv_w[0], nullptr, nullptr, nullptr, conv_b[0], big1);
  k_gstats<<<N_GRAPHS, 512, 0, stream>>>(big1, start, gn_w[0], gn_b[0],
                                         gn_ms[0], A0, B0);
  // layer 1: norm fused into GEMM staging; bf16 hw table; gather-after.
  k_hw<128, true, false, true><<<hwgrid, 256, 0, stream>>>(
      big1, conv_w[1], batch, A0, B0, nullptr, hwb);
  k_gatherb<<<ggrid, 256, 0, stream>>>(hwb, ew_s, src_s, rowstart, dinv,
                                       conv_b[1], big2);
  k_gstats<<<N_GRAPHS, 512, 0, stream>>>(big2, start, gn_w[1], gn_b[1],
                                         gn_ms[1], A1, B1);
  // layer 2
  k_hw<128, true, false, true><<<hwgrid, 256, 0, stream>>>(
      big2, conv_w[2], batch, A1, B1, nullptr, hwb);
  k_gatherb<<<ggrid, 256, 0, stream>>>(hwb, ew_s, src_s, rowstart, dinv,
                                       conv_b[2], big1);
  k_gstats<<<N_GRAPHS, 512, 0, stream>>>(big1, start, gn_w[2], gn_b[2],
                                         gn_ms[2], A2, B2);

  k_pool<<<N_GRAPHS, 512, 0, stream>>>(big1, start, A2, B2, pooled);
  k_head<<<N_GRAPHS, 256, 0, stream>>>(pooled, lin_w0, lin_b0, bn_g0, bn_b0,
                                       lin_w1, lin_b1, bn_g1, bn_b1, out_w,
                                       out_b, (float*)d_out);
}

// Round 8
// 594.234 us; speedup vs baseline: 4.7402x; 1.0715x over previous
//
#include <hip/hip_runtime.h>

#define N_NODES 100000
#define N_EDGES 1600000
#define N_GRAPHS 256
#define EPS 1e-5f

#define SCAN_BLOCKS ((N_NODES + 255) / 256)  // 391

typedef __attribute__((ext_vector_type(8))) short bfrag8;  // 8 bf16
typedef __attribute__((ext_vector_type(4))) float facc4;   // 4 f32 acc

__device__ __forceinline__ void fma4(float4& a, float s, const float4& w) {
  a.x += s * w.x; a.y += s * w.y; a.z += s * w.z; a.w += s * w.w;
}

__device__ __forceinline__ unsigned short f2bf(float f) {
  union { float f; unsigned u; } x;
  x.f = f;
  unsigned r = x.u + 0x7FFF + ((x.u >> 16) & 1);  // RNE
  return (unsigned short)(r >> 16);
}
__device__ __forceinline__ unsigned packbf(float a, float b) {
  return (unsigned)f2bf(a) | ((unsigned)f2bf(b) << 16);
}
__device__ __forceinline__ float4 bf4(uint2 v) {
  union { unsigned u; float f; } a, b, c, d;
  a.u = v.x << 16;
  b.u = v.x & 0xFFFF0000u;
  c.u = v.y << 16;
  d.u = v.y & 0xFFFF0000u;
  return make_float4(a.f, b.f, c.f, d.f);
}

// ---------------------------------------------------------------------------
// Edge MLP + within-row rank histogram (the only atomic pass).
// ---------------------------------------------------------------------------
__global__ __launch_bounds__(256) void k_edge_mlp(
    const float* __restrict__ ea, const float* __restrict__ w1,
    const float* __restrict__ b1, const float* __restrict__ w2,
    const float* __restrict__ b2, const int* __restrict__ tgt,
    float* __restrict__ ew, int* __restrict__ rowcnt,
    int* __restrict__ rank) {
  __shared__ float W1[128], B1[16], W2[16];
  int t = threadIdx.x;
  if (t < 128) W1[t] = w1[t];
  if (t < 16) { B1[t] = b1[t]; W2[t] = w2[t]; }
  __syncthreads();
  int e = blockIdx.x * 256 + t;
  if (e >= N_EDGES) return;
  const float4* ap = (const float4*)(ea + (size_t)e * 8);
  float4 a0 = ap[0], a1 = ap[1];
  float a[8] = {a0.x, a0.y, a0.z, a0.w, a1.x, a1.y, a1.z, a1.w};
  float out = b2[0];
#pragma unroll
  for (int i = 0; i < 16; ++i) {
    float h = B1[i];
#pragma unroll
    for (int j = 0; j < 8; ++j) h += a[j] * W1[i * 8 + j];
    out += fmaxf(h, 0.f) * W2[i];
  }
  ew[e] = out;
  rank[e] = atomicAdd(&rowcnt[tgt[e]], 1);
}

// x (f32) -> xb (bf16), 8 elems/thread
__global__ __launch_bounds__(256) void k_cvt(const float* __restrict__ x,
                                             unsigned* __restrict__ xb) {
  int i = blockIdx.x * 256 + threadIdx.x;
  if (i >= N_NODES * 64 / 8) return;
  const float4* p = (const float4*)(x + (size_t)i * 8);
  float4 a = p[0], b = p[1];
  uint4 o;
  o.x = packbf(a.x, a.y);
  o.y = packbf(a.z, a.w);
  o.z = packbf(b.x, b.y);
  o.w = packbf(b.z, b.w);
  ((uint4*)xb)[i] = o;
}

// conv weights (in,out) f32 -> transposed bf16 WT[n][k] for MFMA B-frags.
__global__ __launch_bounds__(256) void k_cvtw(
    const float* __restrict__ w1, const float* __restrict__ w2,
    unsigned short* __restrict__ o1, unsigned short* __restrict__ o2) {
  int id = blockIdx.x * 256 + threadIdx.x;  // 0..16383
  const float* w = blockIdx.y ? w2 : w1;
  unsigned short* o = blockIdx.y ? o2 : o1;
  int n = id >> 7, k = id & 127;
  o[n * 128 + k] = f2bf(w[k * 128 + n]);
}

// ---------------------------------------------------------------------------
// Parallel 3-phase exclusive scan of rowcnt -> rowstart[0..N]
// ---------------------------------------------------------------------------
__global__ __launch_bounds__(256) void k_scan1(const int* __restrict__ cnt,
                                               int* __restrict__ bsum) {
  int i = blockIdx.x * 256 + threadIdx.x;
  int v = (i < N_NODES) ? cnt[i] : 0;
#pragma unroll
  for (int off = 32; off; off >>= 1) v += __shfl_down(v, off);
  __shared__ int ws[4];
  if ((threadIdx.x & 63) == 0) ws[threadIdx.x >> 6] = v;
  __syncthreads();
  if (threadIdx.x == 0) bsum[blockIdx.x] = ws[0] + ws[1] + ws[2] + ws[3];
}

__global__ __launch_bounds__(512) void k_scan2(const int* __restrict__ bsum,
                                               int* __restrict__ boff) {
  __shared__ int s[512];
  int t = threadIdx.x;
  s[t] = (t < SCAN_BLOCKS) ? bsum[t] : 0;
  __syncthreads();
  for (int off = 1; off < 512; off <<= 1) {
    int u = (t >= off) ? s[t - off] : 0;
    __syncthreads();
    s[t] += u;
    __syncthreads();
  }
  boff[t] = (t == 0) ? 0 : s[t - 1];
}

__global__ __launch_bounds__(256) void k_scan3(const int* __restrict__ cnt,
                                               const int* __restrict__ boff,
                                               int* __restrict__ rowstart) {
  __shared__ int s[256];
  int t = threadIdx.x;
  int i = blockIdx.x * 256 + t;
  int v = (i < N_NODES) ? cnt[i] : 0;
  s[t] = v;
  __syncthreads();
  for (int off = 1; off < 256; off <<= 1) {
    int u = (t >= off) ? s[t - off] : 0;
    __syncthreads();
    s[t] += u;
    __syncthreads();
  }
  if (i < N_NODES) {
    int pre = boff[blockIdx.x] + s[t] - v;  // exclusive
    rowstart[i] = pre;
    if (i == N_NODES - 1) rowstart[N_NODES] = pre + v;
  }
}

// Atomic-free CSR fill: slot = rowstart[tgt] + rank (unique by construction).
__global__ __launch_bounds__(256) void k_fill(
    const int* __restrict__ src, const int* __restrict__ tgt,
    const float* __restrict__ ew, const int* __restrict__ rank,
    const int* __restrict__ rowstart, int* __restrict__ src_s,
    float* __restrict__ ew_s) {
  int e = blockIdx.x * 256 + threadIdx.x;
  if (e >= N_EDGES) return;
  int p = rowstart[tgt[e]] + rank[e];
  src_s[p] = src[e];
  ew_s[p] = ew[e];
}

// deg row-sum fused with dinv: dinv[n] = rsqrt(1 + sum ew_row)
__global__ __launch_bounds__(256) void k_deg(const float* __restrict__ ew_s,
                                             const int* __restrict__ rowstart,
                                             float* __restrict__ dinv) {
  int n = blockIdx.x * 256 + threadIdx.x;
  if (n >= N_NODES) return;
  int rs = rowstart[n], re = rowstart[n + 1];
  float d = 1.f;
  for (int j = rs; j < re; ++j) d += ew_s[j];
  dinv[n] = d > 0.f ? rsqrtf(d) : 0.f;
}

// ew_s[j] *= dinv[src_s[j]] * dinv[row]; wave per node.
__global__ __launch_bounds__(256) void k_scale(float* __restrict__ ew_s,
                                               const int* __restrict__ src_s,
                                               const int* __restrict__ rowstart,
                                               const float* __restrict__ dinv) {
  int n = blockIdx.x * 4 + (threadIdx.x >> 6);
  if (n >= N_NODES) return;
  int lane = threadIdx.x & 63;
  int rs = rowstart[n], re = rowstart[n + 1];
  float dv = dinv[n];
  for (int j = rs + lane; j < re; j += 64) ew_s[j] *= dinv[src_s[j]] * dv;
}

// graph segment starts
__global__ void k_starts(const int* __restrict__ batch, int* __restrict__ start) {
  int g = blockIdx.x * blockDim.x + threadIdx.x;
  if (g > N_GRAPHS) return;
  int lo = 0, hi = N_NODES;
  while (lo < hi) {
    int mid = (lo + hi) >> 1;
    if (batch[mid] < g) lo = mid + 1; else hi = mid;
  }
  start[g] = lo;
}

// ---------------------------------------------------------------------------
// 64-ch CSR gather on bf16 x: aggx[n] = dinv^2*x[n] + sum ew*x[src]
// ---------------------------------------------------------------------------
__global__ __launch_bounds__(256) void k_gather64b(
    const unsigned* __restrict__ xb, const float* __restrict__ ew_s,
    const int* __restrict__ src_s, const int* __restrict__ rowstart,
    const float* __restrict__ dinv, float* __restrict__ out) {
  const int t = threadIdx.x;
  const int n = blockIdx.x * 4 + (t >> 6);
  if (n >= N_NODES) return;
  const int lane = t & 63;
  const int q = lane >> 4;   // edge slot 0..3
  const int cl = lane & 15;  // uint2 group over 64 ch
  const int rs = rowstart[n], re = rowstart[n + 1];
  const uint2* x2 = (const uint2*)xb;
  float4 a0 = make_float4(0.f, 0.f, 0.f, 0.f);
  float4 a1 = make_float4(0.f, 0.f, 0.f, 0.f);
  int j = rs;
  for (; j + 8 <= re; j += 8) {
    int i0 = j + q, i1 = j + 4 + q;
    float w0 = ew_s[i0], w1 = ew_s[i1];
    float4 v0 = bf4(x2[(size_t)src_s[i0] * 16 + cl]);
    float4 v1 = bf4(x2[(size_t)src_s[i1] * 16 + cl]);
    fma4(a0, w0, v0);
    fma4(a1, w1, v1);
  }
  for (; j + 4 <= re; j += 4) {
    int i0 = j + q;
    fma4(a0, ew_s[i0], bf4(x2[(size_t)src_s[i0] * 16 + cl]));
  }
  if (j + q < re) {
    fma4(a1, ew_s[j + q], bf4(x2[(size_t)src_s[j + q] * 16 + cl]));
  }
  a0.x += a1.x; a0.y += a1.y; a0.z += a1.z; a0.w += a1.w;
#pragma unroll
  for (int m = 16; m <= 32; m <<= 1) {
    a0.x += __shfl_xor(a0.x, m);
    a0.y += __shfl_xor(a0.y, m);
    a0.z += __shfl_xor(a0.z, m);
    a0.w += __shfl_xor(a0.w, m);
  }
  if (q == 0) {
    float dv = dinv[n];
    float4 hv = bf4(x2[(size_t)n * 16 + cl]);
    float4 r = make_float4(a0.x + dv * dv * hv.x, a0.y + dv * dv * hv.y,
                           a0.z + dv * dv * hv.z, a0.w + dv * dv * hv.w);
    ((float4*)out)[(size_t)n * 16 + cl] = r;
  }
}

// ---------------------------------------------------------------------------
// Layer-0 GEMM (vector f32): hw = aggx @ W + bias, CIN=64, f32 out.
// ---------------------------------------------------------------------------
template <int CIN>
__global__ __launch_bounds__(256) void k_hw0(
    const float* __restrict__ h, const float* __restrict__ W,
    const float* __restrict__ bias, float* __restrict__ hw) {
  constexpr int KT = 32;
  __shared__ float hs[64][36];
  __shared__ float Ws[KT][128];
  const int t = threadIdx.x;
  const int tn = t & 15, tc = t >> 4;
  const int base = blockIdx.x * 64;

  float acc[4][8];
#pragma unroll
  for (int i = 0; i < 4; ++i)
#pragma unroll
    for (int j = 0; j < 8; ++j) acc[i][j] = 0.f;

  const int ln = t >> 2;
  const int lk = (t & 3) * 8;
  const int wk = t >> 3;
  const int wc = (t & 7) * 16;

  for (int k0 = 0; k0 < CIN; k0 += KT) {
    __syncthreads();
    {
      int n = base + ln;
      float4 v0 = make_float4(0.f, 0.f, 0.f, 0.f), v1 = v0;
      if (n < N_NODES) {
        const float4* hp = (const float4*)(h + (size_t)n * CIN + k0 + lk);
        v0 = hp[0];
        v1 = hp[1];
      }
      *(float4*)&hs[ln][lk] = v0;
      *(float4*)&hs[ln][lk + 4] = v1;
      const float4* wp = (const float4*)(W + (size_t)(k0 + wk) * 128 + wc);
#pragma unroll
      for (int q = 0; q < 4; ++q) *(float4*)&Ws[wk][wc + q * 4] = wp[q];
    }
    __syncthreads();
#pragma unroll
    for (int kk = 0; kk < KT; kk += 4) {
      float4 hv[4];
#pragma unroll
      for (int i = 0; i < 4; ++i) hv[i] = *(const float4*)&hs[tn + 16 * i][kk];
#pragma unroll
      for (int dk = 0; dk < 4; ++dk) {
        float4 wa = *(const float4*)&Ws[kk + dk][tc * 4];
        float4 wb = *(const float4*)&Ws[kk + dk][64 + tc * 4];
#pragma unroll
        for (int i = 0; i < 4; ++i) {
          float hvv = (&hv[i].x)[dk];
          acc[i][0] += hvv * wa.x; acc[i][1] += hvv * wa.y;
          acc[i][2] += hvv * wa.z; acc[i][3] += hvv * wa.w;
          acc[i][4] += hvv * wb.x; acc[i][5] += hvv * wb.y;
          acc[i][6] += hvv * wb.z; acc[i][7] += hvv * wb.w;
        }
      }
    }
  }
  float4 b_lo = *(const float4*)&bias[tc * 4];
  float4 b_hi = *(const float4*)&bias[64 + tc * 4];
#pragma unroll
  for (int i = 0; i < 4; ++i) {
    int n = base + tn + 16 * i;
    if (n < N_NODES) {
      float* op = hw + (size_t)n * 128;
      *(float4*)&op[tc * 4] =
          make_float4(acc[i][0] + b_lo.x, acc[i][1] + b_lo.y,
                      acc[i][2] + b_lo.z, acc[i][3] + b_lo.w);
      *(float4*)&op[64 + tc * 4] =
          make_float4(acc[i][4] + b_hi.x, acc[i][5] + b_hi.y,
                      acc[i][6] + b_hi.z, acc[i][7] + b_hi.w);
    }
  }
}

// ---------------------------------------------------------------------------
// MFMA GEMM for layers 1-2: hwb = bf16( relu(A*h+B) @ W ), bf16 in/out,
// f32 accumulate. Block = 64 nodes x 128 out-ch, 4 waves (16 rows each).
// A-tile [64][136] bf16 LDS (pad 8 -> 2-way-free); WT [128][136] bf16 LDS.
// MFMA: mfma_f32_16x16x32_bf16; lane l: A[m=l&15][k=(l>>4)*8+j],
// B[n=l&15][k=(l>>4)*8+j] (from WT), D[m=(l>>4)*4+r][n=l&15]  (m89 layout).
// ---------------------------------------------------------------------------
__global__ __launch_bounds__(256) void k_hw_mfma(
    const float* __restrict__ h, const unsigned short* __restrict__ wt,
    const int* __restrict__ batch, const float* __restrict__ An,
    const float* __restrict__ Bn, unsigned short* __restrict__ hwb) {
  __shared__ unsigned short Asb[64][136];
  __shared__ unsigned short Wsb[128][136];
  const int t = threadIdx.x;
  const int base = blockIdx.x * 64;

  // stage WT: 128x128 bf16
  for (int i = t; i < 2048; i += 256) {
    int nr = i >> 4, k8 = (i & 15) * 8;
    *(uint4*)&Wsb[nr][k8] = *(const uint4*)&wt[nr * 128 + k8];
  }
  // stage A-tile with fused norm+relu+bf16: thread = (node t>>2, 32ch group)
  {
    const int ln = t >> 2;
    const int cg = (t & 3) * 32;
    const int n = base + ln;
    if (n < N_NODES) {
      const int g = batch[n];
      const float* hp = h + (size_t)n * 128;
      const float* Ap = An + (size_t)g * 128;
      const float* Bp = Bn + (size_t)g * 128;
#pragma unroll
      for (int c4 = 0; c4 < 8; ++c4) {
        int c = cg + c4 * 4;
        float4 v = *(const float4*)&hp[c];
        float4 Af = *(const float4*)&Ap[c];
        float4 Bf = *(const float4*)&Bp[c];
        uint2 o;
        o.x = packbf(fmaxf(Af.x * v.x + Bf.x, 0.f),
                     fmaxf(Af.y * v.y + Bf.y, 0.f));
        o.y = packbf(fmaxf(Af.z * v.z + Bf.z, 0.f),
                     fmaxf(Af.w * v.w + Bf.w, 0.f));
        *(uint2*)&Asb[ln][c] = o;
      }
    } else {
#pragma unroll
      for (int c4 = 0; c4 < 8; ++c4) {
        uint2 o;
        o.x = 0; o.y = 0;
        *(uint2*)&Asb[ln][cg + c4 * 4] = o;
      }
    }
  }
  __syncthreads();

  const int wv = t >> 6;        // wave 0..3 -> rows m0..m0+15
  const int lr = t & 15;        // row (A) / col (B,D)
  const int lk = (t >> 4) & 3;  // k-chunk selector
  const int m0 = wv * 16;

  bfrag8 af[4];
#pragma unroll
  for (int kc = 0; kc < 4; ++kc)
    af[kc] = *(const bfrag8*)&Asb[m0 + lr][kc * 32 + lk * 8];

#pragma unroll
  for (int nt = 0; nt < 8; ++nt) {
    facc4 c = {0.f, 0.f, 0.f, 0.f};
#pragma unroll
    for (int kc = 0; kc < 4; ++kc) {
      bfrag8 bf = *(const bfrag8*)&Wsb[nt * 16 + lr][kc * 32 + lk * 8];
      c = __builtin_amdgcn_mfma_f32_16x16x32_bf16(af[kc], bf, c, 0, 0, 0);
    }
    int col = nt * 16 + lr;
#pragma unroll
    for (int r = 0; r < 4; ++r) {
      int n = base + m0 + lk * 4 + r;
      if (n < N_NODES) hwb[(size_t)n * 128 + col] = f2bf(c[r]);
    }
  }
}

// ---------------------------------------------------------------------------
// 128-ch CSR gather on bf16 table -> f32 agg (+bias, +self-loop).
// ---------------------------------------------------------------------------
__global__ __launch_bounds__(256) void k_gatherb(
    const unsigned* __restrict__ hwb, const float* __restrict__ ew_s,
    const int* __restrict__ src_s, const int* __restrict__ rowstart,
    const float* __restrict__ dinv, const float* __restrict__ bias,
    float* __restrict__ agg) {
  const int t = threadIdx.x;
  const int n = blockIdx.x * 4 + (t >> 6);
  if (n >= N_NODES) return;
  const int lane = t & 63;
  const int q = lane >> 5;   // edge-of-pair selector
  const int cl = lane & 31;  // uint2 group (4 ch) over 128 ch
  const int rs = rowstart[n], re = rowstart[n + 1];
  const uint2* hb = (const uint2*)hwb;
  float4 a0 = make_float4(0.f, 0.f, 0.f, 0.f);
  float4 a1 = make_float4(0.f, 0.f, 0.f, 0.f);
  float4 a2 = make_float4(0.f, 0.f, 0.f, 0.f);
  float4 a3 = make_float4(0.f, 0.f, 0.f, 0.f);
  int j = rs;
  for (; j + 8 <= re; j += 8) {
    int i0 = j + q, i1 = j + 2 + q, i2 = j + 4 + q, i3 = j + 6 + q;
    float w0 = ew_s[i0], w1 = ew_s[i1], w2 = ew_s[i2], w3 = ew_s[i3];
    float4 v0 = bf4(hb[(size_t)src_s[i0] * 32 + cl]);
    float4 v1 = bf4(hb[(size_t)src_s[i1] * 32 + cl]);
    float4 v2 = bf4(hb[(size_t)src_s[i2] * 32 + cl]);
    float4 v3 = bf4(hb[(size_t)src_s[i3] * 32 + cl]);
    fma4(a0, w0, v0);
    fma4(a1, w1, v1);
    fma4(a2, w2, v2);
    fma4(a3, w3, v3);
  }
  for (; j + 2 <= re; j += 2) {
    int i0 = j + q;
    fma4(a0, ew_s[i0], bf4(hb[(size_t)src_s[i0] * 32 + cl]));
  }
  if (q == 0 && j < re) {
    fma4(a1, ew_s[j], bf4(hb[(size_t)src_s[j] * 32 + cl]));
  }
  a0.x += a1.x + a2.x + a3.x;
  a0.y += a1.y + a2.y + a3.y;
  a0.z += a1.z + a2.z + a3.z;
  a0.w += a1.w + a2.w + a3.w;
  a0.x += __shfl_xor(a0.x, 32);
  a0.y += __shfl_xor(a0.y, 32);
  a0.z += __shfl_xor(a0.z, 32);
  a0.w += __shfl_xor(a0.w, 32);
  if (q == 0) {
    float dv = dinv[n];
    float4 hv = bf4(hb[(size_t)n * 32 + cl]);
    float4 bv = ((const float4*)bias)[cl];
    float4 r = make_float4(a0.x + dv * dv * hv.x + bv.x,
                           a0.y + dv * dv * hv.y + bv.y,
                           a0.z + dv * dv * hv.z + bv.z,
                           a0.w + dv * dv * hv.w + bv.w);
    ((float4*)agg)[(size_t)n * 32 + cl] = r;
  }
}

// ---------------------------------------------------------------------------
// GraphNorm stats only: A[g,c] = gw/sqrt(var+eps), B[g,c] = gb - A*ms*mean.
// ---------------------------------------------------------------------------
__global__ __launch_bounds__(512) void k_gstats(
    const float* __restrict__ h, const int* __restrict__ start,
    const float* __restrict__ gw, const float* __restrict__ gb,
    const float* __restrict__ gms, float* __restrict__ An,
    float* __restrict__ Bn) {
  int g = blockIdx.x;
  int s = start[g], e = start[g + 1];
  int t = threadIdx.x, p = t >> 7, c = t & 127;
  float sum = 0.f, sq = 0.f;
  for (int n = s + p; n < e; n += 4) {
    float v = h[(size_t)n * 128 + c];
    sum += v;
    sq += v * v;
  }
  __shared__ float S[4][128], Q[4][128];
  S[p][c] = sum;
  Q[p][c] = sq;
  __syncthreads();
  if (t < 128) {
    float cnt = (float)max(e - s, 1);
    float mean = (S[0][t] + S[1][t] + S[2][t] + S[3][t]) / cnt;
    float e2 = (Q[0][t] + Q[1][t] + Q[2][t] + Q[3][t]) / cnt;
    float ms = gms[t];
    float var = fmaxf(e2 - ms * (2.f - ms) * mean * mean, 0.f);
    float scale = gw[t] / sqrtf(var + EPS);
    An[(size_t)g * 128 + t] = scale;
    Bn[(size_t)g * 128 + t] = gb[t] - scale * ms * mean;
  }
}

// pooled[g,c] = mean over graph nodes of relu(A*h+B)
__global__ __launch_bounds__(512) void k_pool(
    const float* __restrict__ h, const int* __restrict__ start,
    const float* __restrict__ An, const float* __restrict__ Bn,
    float* __restrict__ pooled) {
  int g = blockIdx.x;
  int s = start[g], e = start[g + 1];
  int t = threadIdx.x, p = t >> 7, c = t & 127;
  float A = An[(size_t)g * 128 + c], B = Bn[(size_t)g * 128 + c];
  float sum = 0.f;
  for (int n = s + p; n < e; n += 4)
    sum += fmaxf(A * h[(size_t)n * 128 + c] + B, 0.f);
  __shared__ float S[4][128];
  S[p][c] = sum;
  __syncthreads();
  if (t < 128) {
    float cnt = (float)max(e - s, 1);
    pooled[g * 128 + t] = (S[0][t] + S[1][t] + S[2][t] + S[3][t]) / cnt;
  }
}

// MLP head: 128 ->256 (BN,ReLU) ->128 (BN,ReLU) ->1; writes out[g] and h2.
__global__ __launch_bounds__(256) void k_head(
    const float* __restrict__ pooled, const float* __restrict__ w0,
    const float* __restrict__ b0, const float* __restrict__ g0,
    const float* __restrict__ bb0, const float* __restrict__ w1,
    const float* __restrict__ b1, const float* __restrict__ g1,
    const float* __restrict__ bb1, const float* __restrict__ ow,
    const float* __restrict__ ob, float* __restrict__ out) {
  __shared__ float p[128], h1[256], h2[128];
  int g = blockIdx.x, t = threadIdx.x;
  const float inv = 1.0f / sqrtf(1.0f + EPS);
  if (t < 128) p[t] = pooled[g * 128 + t];
  __syncthreads();
  {
    float acc = b0[t];
#pragma unroll 8
    for (int k = 0; k < 128; ++k) acc += p[k] * w0[k * 256 + t];
    h1[t] = fmaxf(acc * inv * g0[t] + bb0[t], 0.f);
  }
  __syncthreads();
  if (t < 128) {
    float acc = b1[t];
#pragma unroll 8
    for (int k = 0; k < 256; ++k) acc += h1[k] * w1[k * 128 + t];
    float v = fmaxf(acc * inv * g1[t] + bb1[t], 0.f);
    h2[t] = v;
    out[N_GRAPHS + g * 128 + t] = v;
  }
  __syncthreads();
  if (t < 64) {
    float v = h2[t] * ow[t] + h2[t + 64] * ow[t + 64];
#pragma unroll
    for (int off = 32; off; off >>= 1) v += __shfl_down(v, off);
    if (t == 0) out[g] = v + ob[0];
  }
}

// ---------------------------------------------------------------------------
extern "C" void kernel_launch(void* const* d_in, const int* in_sizes, int n_in,
                              void* d_out, int out_size, void* d_ws,
                              size_t ws_size, hipStream_t stream) {
  const float* x = (const float*)d_in[0];
  const float* edge_attr = (const float*)d_in[1];
  const float* em_w1 = (const float*)d_in[2];
  const float* em_b1 = (const float*)d_in[3];
  const float* em_w2 = (const float*)d_in[4];
  const float* em_b2 = (const float*)d_in[5];
  const float* conv_w[3] = {(const float*)d_in[6], (const float*)d_in[8],
                            (const float*)d_in[10]};
  const float* conv_b[3] = {(const float*)d_in[7], (const float*)d_in[9],
                            (const float*)d_in[11]};
  const float* gn_w[3] = {(const float*)d_in[12], (const float*)d_in[15],
                          (const float*)d_in[18]};
  const float* gn_b[3] = {(const float*)d_in[13], (const float*)d_in[16],
                          (const float*)d_in[19]};
  const float* gn_ms[3] = {(const float*)d_in[14], (const float*)d_in[17],
                           (const float*)d_in[20]};
  const float* lin_w0 = (const float*)d_in[21];
  const float* lin_b0 = (const float*)d_in[22];
  const float* bn_g0 = (const float*)d_in[23];
  const float* bn_b0 = (const float*)d_in[24];
  const float* lin_w1 = (const float*)d_in[25];
  const float* lin_b1 = (const float*)d_in[26];
  const float* bn_g1 = (const float*)d_in[27];
  const float* bn_b1 = (const float*)d_in[28];
  const float* out_w = (const float*)d_in[29];
  const float* out_b = (const float*)d_in[30];
  const int* edge_index = (const int*)d_in[31];
  const int* batch = (const int*)d_in[32];
  const int* src = edge_index;
  const int* tgt = edge_index + N_EDGES;

  char* w = (char*)d_ws;
  size_t off = 0;
  auto carve = [&](size_t bytes) {
    void* p = w + off;
    off = (off + bytes + 511) & ~(size_t)511;
    return p;
  };
  float* ew = (float*)carve((size_t)N_EDGES * 4);
  int* rank = (int*)carve((size_t)N_EDGES * 4);
  float* dinv = (float*)carve((size_t)N_NODES * 4);
  int* rowcnt = (int*)carve((size_t)N_NODES * 4);
  int* rowstart = (int*)carve((size_t)(N_NODES + 1) * 4);
  int* bsum = (int*)carve((size_t)SCAN_BLOCKS * 4);
  int* boff = (int*)carve((size_t)512 * 4);
  int* src_s = (int*)carve((size_t)N_EDGES * 4);
  float* ew_s = (float*)carve((size_t)N_EDGES * 4);
  int* start = (int*)carve((N_GRAPHS + 1) * 4);
  float* AB = (float*)carve((size_t)6 * N_GRAPHS * 128 * 4);
  unsigned* xb = (unsigned*)carve((size_t)N_NODES * 64 * 2);   // bf16 x
  unsigned* hwb = (unsigned*)carve((size_t)N_NODES * 128 * 2); // bf16 hw
  unsigned short* wt1 = (unsigned short*)carve((size_t)128 * 128 * 2);
  unsigned short* wt2 = (unsigned short*)carve((size_t)128 * 128 * 2);
  float* big1 = (float*)carve((size_t)N_NODES * 128 * 4);
  float* big2 = (float*)carve((size_t)N_NODES * 128 * 4);
  float* pooled = (float*)carve((size_t)N_GRAPHS * 128 * 4);

  float* A0 = AB, *B0 = AB + N_GRAPHS * 128;
  float* A1 = AB + 2 * N_GRAPHS * 128, *B1 = AB + 3 * N_GRAPHS * 128;
  float* A2 = AB + 4 * N_GRAPHS * 128, *B2 = AB + 5 * N_GRAPHS * 128;

  hipMemsetAsync(rowcnt, 0, (size_t)N_NODES * 4, stream);

  k_edge_mlp<<<(N_EDGES + 255) / 256, 256, 0, stream>>>(
      edge_attr, em_w1, em_b1, em_w2, em_b2, tgt, ew, rowcnt, rank);
  k_cvt<<<(N_NODES * 64 / 8 + 255) / 256, 256, 0, stream>>>(x, xb);
  k_cvtw<<<dim3(64, 2), 256, 0, stream>>>(conv_w[1], conv_w[2], wt1, wt2);
  k_scan1<<<SCAN_BLOCKS, 256, 0, stream>>>(rowcnt, bsum);
  k_scan2<<<1, 512, 0, stream>>>(bsum, boff);
  k_scan3<<<SCAN_BLOCKS, 256, 0, stream>>>(rowcnt, boff, rowstart);
  k_fill<<<(N_EDGES + 255) / 256, 256, 0, stream>>>(src, tgt, ew, rank,
                                                    rowstart, src_s, ew_s);
  k_deg<<<(N_NODES + 255) / 256, 256, 0, stream>>>(ew_s, rowstart, dinv);
  k_scale<<<(N_NODES + 3) / 4, 256, 0, stream>>>(ew_s, src_s, rowstart, dinv);
  k_starts<<<1, 512, 0, stream>>>(batch, start);

  const int ggrid = (N_NODES + 3) / 4;
  const int hwgrid = (N_NODES + 63) / 64;

  // layer 0: aggregate-first on bf16 x; vector GEMM f32 out.
  k_gather64b<<<ggrid, 256, 0, stream>>>(xb, ew_s, src_s, rowstart, dinv,
                                         big2);
  k_hw0<64><<<hwgrid, 256, 0, stream>>>(big2, conv_w[0], conv_b[0], big1);
  k_gstats<<<N_GRAPHS, 512, 0, stream>>>(big1, start, gn_w[0], gn_b[0],
                                         gn_ms[0], A0, B0);
  // layer 1: MFMA GEMM (norm fused into staging, bf16 table out).
  k_hw_mfma<<<hwgrid, 256, 0, stream>>>(big1, wt1, batch, A0, B0,
                                        (unsigned short*)hwb);
  k_gatherb<<<ggrid, 256, 0, stream>>>(hwb, ew_s, src_s, rowstart, dinv,
                                       conv_b[1], big2);
  k_gstats<<<N_GRAPHS, 512, 0, stream>>>(big2, start, gn_w[1], gn_b[1],
                                         gn_ms[1], A1, B1);
  // layer 2
  k_hw_mfma<<<hwgrid, 256, 0, stream>>>(big2, wt2, batch, A1, B1,
                                        (unsigned short*)hwb);
  k_gatherb<<<ggrid, 256, 0, stream>>>(hwb, ew_s, src_s, rowstart, dinv,
                                       conv_b[2], big1);
  k_gstats<<<N_GRAPHS, 512, 0, stream>>>(big1, start, gn_w[2], gn_b[2],
                                         gn_ms[2], A2, B2);

  k_pool<<<N_GRAPHS, 512, 0, stream>>>(big1, start, A2, B2, pooled);
  k_head<<<N_GRAPHS, 256, 0, stream>>>(pooled, lin_w0, lin_b0, bn_g0, bn_b0,
                                       lin_w1, lin_b1, bn_g1, bn_b1, out_w,
                                       out_b, (float*)d_out);
}

// Round 9
// 530.972 us; speedup vs baseline: 5.3049x; 1.1191x over previous
//
#include <hip/hip_runtime.h>

#define N_NODES 100000
#define N_EDGES 1600000
#define N_GRAPHS 256
#define EPS 1e-5f

#define SCAN_BLOCKS ((N_NODES + 255) / 256)  // 391

typedef __attribute__((ext_vector_type(8))) short bfrag8;  // 8 bf16
typedef __attribute__((ext_vector_type(4))) float facc4;   // 4 f32 acc

__device__ __forceinline__ void fma4(float4& a, float s, const float4& w) {
  a.x += s * w.x; a.y += s * w.y; a.z += s * w.z; a.w += s * w.w;
}

__device__ __forceinline__ unsigned short f2bf(float f) {
  union { float f; unsigned u; } x;
  x.f = f;
  unsigned r = x.u + 0x7FFF + ((x.u >> 16) & 1);  // RNE
  return (unsigned short)(r >> 16);
}
__device__ __forceinline__ unsigned packbf(float a, float b) {
  return (unsigned)f2bf(a) | ((unsigned)f2bf(b) << 16);
}
__device__ __forceinline__ float4 bf4(unsigned lo, unsigned hi) {
  union { unsigned u; float f; } a, b, c, d;
  a.u = lo << 16;
  b.u = lo & 0xFFFF0000u;
  c.u = hi << 16;
  d.u = hi & 0xFFFF0000u;
  return make_float4(a.f, b.f, c.f, d.f);
}
__device__ __forceinline__ float bfat(const unsigned* tb, int idx) {
  unsigned u = tb[idx >> 1];
  union { unsigned u; float f; } v;
  v.u = (idx & 1) ? (u & 0xFFFF0000u) : (u << 16);
  return v.f;
}

// ---------------------------------------------------------------------------
// Edge MLP + within-row rank histogram (the only atomic pass).
// ---------------------------------------------------------------------------
__global__ __launch_bounds__(256) void k_edge_mlp(
    const float* __restrict__ ea, const float* __restrict__ w1,
    const float* __restrict__ b1, const float* __restrict__ w2,
    const float* __restrict__ b2, const int* __restrict__ tgt,
    float* __restrict__ ew, int* __restrict__ rowcnt,
    int* __restrict__ rank) {
  __shared__ float W1[128], B1[16], W2[16];
  int t = threadIdx.x;
  if (t < 128) W1[t] = w1[t];
  if (t < 16) { B1[t] = b1[t]; W2[t] = w2[t]; }
  __syncthreads();
  int e = blockIdx.x * 256 + t;
  if (e >= N_EDGES) return;
  const float4* ap = (const float4*)(ea + (size_t)e * 8);
  float4 a0 = ap[0], a1 = ap[1];
  float a[8] = {a0.x, a0.y, a0.z, a0.w, a1.x, a1.y, a1.z, a1.w};
  float out = b2[0];
#pragma unroll
  for (int i = 0; i < 16; ++i) {
    float h = B1[i];
#pragma unroll
    for (int j = 0; j < 8; ++j) h += a[j] * W1[i * 8 + j];
    out += fmaxf(h, 0.f) * W2[i];
  }
  ew[e] = out;
  rank[e] = atomicAdd(&rowcnt[tgt[e]], 1);
}

// x (f32) -> xb (bf16), 8 elems/thread
__global__ __launch_bounds__(256) void k_cvt(const float* __restrict__ x,
                                             unsigned* __restrict__ xb) {
  int i = blockIdx.x * 256 + threadIdx.x;
  if (i >= N_NODES * 64 / 8) return;
  const float4* p = (const float4*)(x + (size_t)i * 8);
  float4 a = p[0], b = p[1];
  uint4 o;
  o.x = packbf(a.x, a.y);
  o.y = packbf(a.z, a.w);
  o.z = packbf(b.x, b.y);
  o.w = packbf(b.z, b.w);
  ((uint4*)xb)[i] = o;
}

// W1,W2 (128,128) f32 -> transposed bf16 WT[n][k]
__global__ __launch_bounds__(256) void k_cvtw(
    const float* __restrict__ w1, const float* __restrict__ w2,
    unsigned short* __restrict__ o1, unsigned short* __restrict__ o2) {
  int id = blockIdx.x * 256 + threadIdx.x;  // 0..16383
  const float* w = blockIdx.y ? w2 : w1;
  unsigned short* o = blockIdx.y ? o2 : o1;
  int n = id >> 7, k = id & 127;
  o[n * 128 + k] = f2bf(w[k * 128 + n]);
}

// W0 (64,128) f32 -> transposed bf16 WT0[n=128][k=64]
__global__ __launch_bounds__(256) void k_cvtw0(const float* __restrict__ w0,
                                               unsigned short* __restrict__ o) {
  int id = blockIdx.x * 256 + threadIdx.x;  // 0..8191
  if (id >= 8192) return;
  int n = id >> 6, k = id & 63;
  o[n * 64 + k] = f2bf(w0[k * 128 + n]);
}

// ---------------------------------------------------------------------------
// Parallel 3-phase exclusive scan of rowcnt -> rowstart[0..N]
// ---------------------------------------------------------------------------
__global__ __launch_bounds__(256) void k_scan1(const int* __restrict__ cnt,
                                               int* __restrict__ bsum) {
  int i = blockIdx.x * 256 + threadIdx.x;
  int v = (i < N_NODES) ? cnt[i] : 0;
#pragma unroll
  for (int off = 32; off; off >>= 1) v += __shfl_down(v, off);
  __shared__ int ws[4];
  if ((threadIdx.x & 63) == 0) ws[threadIdx.x >> 6] = v;
  __syncthreads();
  if (threadIdx.x == 0) bsum[blockIdx.x] = ws[0] + ws[1] + ws[2] + ws[3];
}

__global__ __launch_bounds__(512) void k_scan2(const int* __restrict__ bsum,
                                               int* __restrict__ boff) {
  __shared__ int s[512];
  int t = threadIdx.x;
  s[t] = (t < SCAN_BLOCKS) ? bsum[t] : 0;
  __syncthreads();
  for (int off = 1; off < 512; off <<= 1) {
    int u = (t >= off) ? s[t - off] : 0;
    __syncthreads();
    s[t] += u;
    __syncthreads();
  }
  boff[t] = (t == 0) ? 0 : s[t - 1];
}

__global__ __launch_bounds__(256) void k_scan3(const int* __restrict__ cnt,
                                               const int* __restrict__ boff,
                                               int* __restrict__ rowstart) {
  __shared__ int s[256];
  int t = threadIdx.x;
  int i = blockIdx.x * 256 + t;
  int v = (i < N_NODES) ? cnt[i] : 0;
  s[t] = v;
  __syncthreads();
  for (int off = 1; off < 256; off <<= 1) {
    int u = (t >= off) ? s[t - off] : 0;
    __syncthreads();
    s[t] += u;
    __syncthreads();
  }
  if (i < N_NODES) {
    int pre = boff[blockIdx.x] + s[t] - v;  // exclusive
    rowstart[i] = pre;
    if (i == N_NODES - 1) rowstart[N_NODES] = pre + v;
  }
}

// Atomic-free CSR fill with INTERLEAVED payload: meta[p] = {bits(w), src}.
__global__ __launch_bounds__(256) void k_fill(
    const int* __restrict__ src, const int* __restrict__ tgt,
    const float* __restrict__ ew, const int* __restrict__ rank,
    const int* __restrict__ rowstart, uint2* __restrict__ meta) {
  int e = blockIdx.x * 256 + threadIdx.x;
  if (e >= N_EDGES) return;
  int p = rowstart[tgt[e]] + rank[e];
  union { float f; unsigned u; } w;
  w.f = ew[e];
  meta[p] = make_uint2(w.u, (unsigned)src[e]);
}

// deg row-sum fused with dinv: dinv[n] = rsqrt(1 + sum ew_row)
__global__ __launch_bounds__(256) void k_deg(const uint2* __restrict__ meta,
                                             const int* __restrict__ rowstart,
                                             float* __restrict__ dinv) {
  int n = blockIdx.x * 256 + threadIdx.x;
  if (n >= N_NODES) return;
  int rs = rowstart[n], re = rowstart[n + 1];
  float d = 1.f;
  for (int j = rs; j < re; ++j) {
    union { unsigned u; float f; } w;
    w.u = meta[j].x;
    d += w.f;
  }
  dinv[n] = d > 0.f ? rsqrtf(d) : 0.f;
}

// meta[j].w *= dinv[src] * dinv[row]; wave per node.
__global__ __launch_bounds__(256) void k_scale(uint2* __restrict__ meta,
                                               const int* __restrict__ rowstart,
                                               const float* __restrict__ dinv) {
  int n = blockIdx.x * 4 + (threadIdx.x >> 6);
  if (n >= N_NODES) return;
  int lane = threadIdx.x & 63;
  int rs = rowstart[n], re = rowstart[n + 1];
  float dv = dinv[n];
  for (int j = rs + lane; j < re; j += 64) {
    uint2 m = meta[j];
    union { unsigned u; float f; } w;
    w.u = m.x;
    w.f *= dinv[m.y] * dv;
    meta[j].x = w.u;
  }
}

// graph segment starts
__global__ void k_starts(const int* __restrict__ batch, int* __restrict__ start) {
  int g = blockIdx.x * blockDim.x + threadIdx.x;
  if (g > N_GRAPHS) return;
  int lo = 0, hi = N_NODES;
  while (lo < hi) {
    int mid = (lo + hi) >> 1;
    if (batch[mid] < g) lo = mid + 1; else hi = mid;
  }
  start[g] = lo;
}

// ---------------------------------------------------------------------------
// 64-ch CSR gather on bf16 x -> bf16 aggx: aggx[n]=dinv^2*x[n]+sum w*x[src]
// wave/node; 4 edge slots x 16 uint2-lanes (4 ch each).
// ---------------------------------------------------------------------------
__global__ __launch_bounds__(256) void k_gather64b(
    const unsigned* __restrict__ xb, const uint2* __restrict__ meta,
    const int* __restrict__ rowstart, const float* __restrict__ dinv,
    unsigned* __restrict__ aggxb) {
  const int t = threadIdx.x;
  const int n = blockIdx.x * 4 + (t >> 6);
  if (n >= N_NODES) return;
  const int lane = t & 63;
  const int q = lane >> 4;   // edge slot 0..3
  const int cl = lane & 15;  // uint2 group over 64 ch
  const int rs = rowstart[n], re = rowstart[n + 1];
  const uint2* x2 = (const uint2*)xb;
  float4 a0 = make_float4(0.f, 0.f, 0.f, 0.f);
  float4 a1 = make_float4(0.f, 0.f, 0.f, 0.f);
  int j = rs;
  for (; j + 8 <= re; j += 8) {
    uint2 m0 = meta[j + q], m1 = meta[j + 4 + q];
    union { unsigned u; float f; } w0, w1;
    w0.u = m0.x; w1.u = m1.x;
    uint2 v0 = x2[(size_t)m0.y * 16 + cl];
    uint2 v1 = x2[(size_t)m1.y * 16 + cl];
    fma4(a0, w0.f, bf4(v0.x, v0.y));
    fma4(a1, w1.f, bf4(v1.x, v1.y));
  }
  for (; j + 4 <= re; j += 4) {
    uint2 m0 = meta[j + q];
    union { unsigned u; float f; } w0;
    w0.u = m0.x;
    uint2 v0 = x2[(size_t)m0.y * 16 + cl];
    fma4(a0, w0.f, bf4(v0.x, v0.y));
  }
  if (j + q < re) {
    uint2 m0 = meta[j + q];
    union { unsigned u; float f; } w0;
    w0.u = m0.x;
    uint2 v0 = x2[(size_t)m0.y * 16 + cl];
    fma4(a1, w0.f, bf4(v0.x, v0.y));
  }
  a0.x += a1.x; a0.y += a1.y; a0.z += a1.z; a0.w += a1.w;
#pragma unroll
  for (int m = 16; m <= 32; m <<= 1) {
    a0.x += __shfl_xor(a0.x, m);
    a0.y += __shfl_xor(a0.y, m);
    a0.z += __shfl_xor(a0.z, m);
    a0.w += __shfl_xor(a0.w, m);
  }
  if (q == 0) {
    float dv = dinv[n];
    uint2 hvb = x2[(size_t)n * 16 + cl];
    float4 hv = bf4(hvb.x, hvb.y);
    uint2 o;
    o.x = packbf(a0.x + dv * dv * hv.x, a0.y + dv * dv * hv.y);
    o.y = packbf(a0.z + dv * dv * hv.z, a0.w + dv * dv * hv.w);
    *(uint2*)&aggxb[(size_t)n * 32 + cl * 2] = o;
  }
}

// ---------------------------------------------------------------------------
// Layer-0 MFMA GEMM: h1b = bf16( aggxb @ W0 + b0 ).  CIN=64.
// Block = 64 nodes x 128 out-ch, 4 waves. Asb[64][72], Wsb[128][72] bf16.
// ---------------------------------------------------------------------------
__global__ __launch_bounds__(256) void k_hw_mfma0(
    const unsigned short* __restrict__ aggxb,
    const unsigned short* __restrict__ wt0, const float* __restrict__ bias,
    unsigned short* __restrict__ h1b) {
  __shared__ unsigned short Asb[64][72];
  __shared__ unsigned short Wsb[128][72];
  const int t = threadIdx.x;
  const int base = blockIdx.x * 64;

  // stage WT0: 128x64 bf16 = 1024 uint4
  for (int i = t; i < 1024; i += 256) {
    int nr = i >> 3, k8 = (i & 7) * 8;
    *(uint4*)&Wsb[nr][k8] = *(const uint4*)&wt0[nr * 64 + k8];
  }
  // stage A: 64 nodes x 64 ch; thread = node t>>2, 16-ch chunk (t&3)*16
  {
    const int ln = t >> 2;
    const int kp = (t & 3) * 16;
    const int n = base + ln;
    if (n < N_NODES) {
      *(uint4*)&Asb[ln][kp] = *(const uint4*)&aggxb[(size_t)n * 64 + kp];
      *(uint4*)&Asb[ln][kp + 8] = *(const uint4*)&aggxb[(size_t)n * 64 + kp + 8];
    } else {
      uint4 z = make_uint4(0, 0, 0, 0);
      *(uint4*)&Asb[ln][kp] = z;
      *(uint4*)&Asb[ln][kp + 8] = z;
    }
  }
  __syncthreads();

  const int wv = t >> 6;
  const int lr = t & 15;
  const int lk = (t >> 4) & 3;
  const int m0 = wv * 16;

  bfrag8 af[2];
#pragma unroll
  for (int kc = 0; kc < 2; ++kc)
    af[kc] = *(const bfrag8*)&Asb[m0 + lr][kc * 32 + lk * 8];

#pragma unroll
  for (int nt = 0; nt < 8; ++nt) {
    facc4 c = {0.f, 0.f, 0.f, 0.f};
#pragma unroll
    for (int kc = 0; kc < 2; ++kc) {
      bfrag8 bf = *(const bfrag8*)&Wsb[nt * 16 + lr][kc * 32 + lk * 8];
      c = __builtin_amdgcn_mfma_f32_16x16x32_bf16(af[kc], bf, c, 0, 0, 0);
    }
    int col = nt * 16 + lr;
    float bv = bias[col];
#pragma unroll
    for (int r = 0; r < 4; ++r) {
      int n = base + m0 + lk * 4 + r;
      if (n < N_NODES) h1b[(size_t)n * 128 + col] = f2bf(c[r] + bv);
    }
  }
}

// ---------------------------------------------------------------------------
// Layers 1-2 MFMA GEMM: hwb = bf16( relu(A*h+B) @ W ), h bf16 in.
// Asb[64][136], Wsb[128][136]. (R8-proven layout.)
// ---------------------------------------------------------------------------
__global__ __launch_bounds__(256) void k_hw_mfma(
    const unsigned* __restrict__ hb, const unsigned short* __restrict__ wt,
    const int* __restrict__ batch, const float* __restrict__ An,
    const float* __restrict__ Bn, unsigned short* __restrict__ hwb) {
  __shared__ unsigned short Asb[64][136];
  __shared__ unsigned short Wsb[128][136];
  const int t = threadIdx.x;
  const int base = blockIdx.x * 64;

  for (int i = t; i < 2048; i += 256) {
    int nr = i >> 4, k8 = (i & 15) * 8;
    *(uint4*)&Wsb[nr][k8] = *(const uint4*)&wt[nr * 128 + k8];
  }
  {
    const int ln = t >> 2;
    const int cg = (t & 3) * 32;
    const int n = base + ln;
    if (n < N_NODES) {
      const int g = batch[n];
      const uint4* hp = (const uint4*)(hb + (size_t)n * 64);
      const float* Ap = An + (size_t)g * 128;
      const float* Bp = Bn + (size_t)g * 128;
#pragma unroll
      for (int qq = 0; qq < 4; ++qq) {
        int c = cg + qq * 8;
        uint4 v = hp[(t & 3) * 4 + qq];
        float4 lo = bf4(v.x, v.y);
        float4 hi = bf4(v.z, v.w);
        float4 Alo = *(const float4*)&Ap[c], Blo = *(const float4*)&Bp[c];
        float4 Ahi = *(const float4*)&Ap[c + 4], Bhi = *(const float4*)&Bp[c + 4];
        uint4 o;
        o.x = packbf(fmaxf(Alo.x * lo.x + Blo.x, 0.f),
                     fmaxf(Alo.y * lo.y + Blo.y, 0.f));
        o.y = packbf(fmaxf(Alo.z * lo.z + Blo.z, 0.f),
                     fmaxf(Alo.w * lo.w + Blo.w, 0.f));
        o.z = packbf(fmaxf(Ahi.x * hi.x + Bhi.x, 0.f),
                     fmaxf(Ahi.y * hi.y + Bhi.y, 0.f));
        o.w = packbf(fmaxf(Ahi.z * hi.z + Bhi.z, 0.f),
                     fmaxf(Ahi.w * hi.w + Bhi.w, 0.f));
        *(uint4*)&Asb[ln][c] = o;
      }
    } else {
      uint4 z = make_uint4(0, 0, 0, 0);
#pragma unroll
      for (int qq = 0; qq < 4; ++qq) *(uint4*)&Asb[ln][cg + qq * 8] = z;
    }
  }
  __syncthreads();

  const int wv = t >> 6;
  const int lr = t & 15;
  const int lk = (t >> 4) & 3;
  const int m0 = wv * 16;

  bfrag8 af[4];
#pragma unroll
  for (int kc = 0; kc < 4; ++kc)
    af[kc] = *(const bfrag8*)&Asb[m0 + lr][kc * 32 + lk * 8];

#pragma unroll
  for (int nt = 0; nt < 8; ++nt) {
    facc4 c = {0.f, 0.f, 0.f, 0.f};
#pragma unroll
    for (int kc = 0; kc < 4; ++kc) {
      bfrag8 bf = *(const bfrag8*)&Wsb[nt * 16 + lr][kc * 32 + lk * 8];
      c = __builtin_amdgcn_mfma_f32_16x16x32_bf16(af[kc], bf, c, 0, 0, 0);
    }
    int col = nt * 16 + lr;
#pragma unroll
    for (int r = 0; r < 4; ++r) {
      int n = base + m0 + lk * 4 + r;
      if (n < N_NODES) hwb[(size_t)n * 128 + col] = f2bf(c[r]);
    }
  }
}

// ---------------------------------------------------------------------------
// 128-ch CSR gather on bf16 table -> bf16 agg (+bias, +self-loop), f32 math.
// ---------------------------------------------------------------------------
__global__ __launch_bounds__(256) void k_gatherb(
    const unsigned* __restrict__ hwb, const uint2* __restrict__ meta,
    const int* __restrict__ rowstart, const float* __restrict__ dinv,
    const float* __restrict__ bias, unsigned* __restrict__ aggb) {
  const int t = threadIdx.x;
  const int n = blockIdx.x * 4 + (t >> 6);
  if (n >= N_NODES) return;
  const int lane = t & 63;
  const int q = lane >> 5;   // edge-of-pair selector
  const int cl = lane & 31;  // uint2 group (4 ch) over 128 ch
  const int rs = rowstart[n], re = rowstart[n + 1];
  const uint2* hb = (const uint2*)hwb;
  float4 a0 = make_float4(0.f, 0.f, 0.f, 0.f);
  float4 a1 = make_float4(0.f, 0.f, 0.f, 0.f);
  float4 a2 = make_float4(0.f, 0.f, 0.f, 0.f);
  float4 a3 = make_float4(0.f, 0.f, 0.f, 0.f);
  int j = rs;
  for (; j + 8 <= re; j += 8) {
    uint2 m0 = meta[j + q], m1 = meta[j + 2 + q];
    uint2 m2 = meta[j + 4 + q], m3 = meta[j + 6 + q];
    union { unsigned u; float f; } w0, w1, w2, w3;
    w0.u = m0.x; w1.u = m1.x; w2.u = m2.x; w3.u = m3.x;
    uint2 v0 = hb[(size_t)m0.y * 32 + cl];
    uint2 v1 = hb[(size_t)m1.y * 32 + cl];
    uint2 v2 = hb[(size_t)m2.y * 32 + cl];
    uint2 v3 = hb[(size_t)m3.y * 32 + cl];
    fma4(a0, w0.f, bf4(v0.x, v0.y));
    fma4(a1, w1.f, bf4(v1.x, v1.y));
    fma4(a2, w2.f, bf4(v2.x, v2.y));
    fma4(a3, w3.f, bf4(v3.x, v3.y));
  }
  for (; j + 2 <= re; j += 2) {
    uint2 m0 = meta[j + q];
    union { unsigned u; float f; } w0;
    w0.u = m0.x;
    uint2 v0 = hb[(size_t)m0.y * 32 + cl];
    fma4(a0, w0.f, bf4(v0.x, v0.y));
  }
  if (q == 0 && j < re) {
    uint2 m0 = meta[j];
    union { unsigned u; float f; } w0;
    w0.u = m0.x;
    uint2 v0 = hb[(size_t)m0.y * 32 + cl];
    fma4(a1, w0.f, bf4(v0.x, v0.y));
  }
  a0.x += a1.x + a2.x + a3.x;
  a0.y += a1.y + a2.y + a3.y;
  a0.z += a1.z + a2.z + a3.z;
  a0.w += a1.w + a2.w + a3.w;
  a0.x += __shfl_xor(a0.x, 32);
  a0.y += __shfl_xor(a0.y, 32);
  a0.z += __shfl_xor(a0.z, 32);
  a0.w += __shfl_xor(a0.w, 32);
  if (q == 0) {
    float dv = dinv[n];
    uint2 hvb = hb[(size_t)n * 32 + cl];
    float4 hv = bf4(hvb.x, hvb.y);
    float4 bv = ((const float4*)bias)[cl];
    uint2 o;
    o.x = packbf(a0.x + dv * dv * hv.x + bv.x, a0.y + dv * dv * hv.y + bv.y);
    o.y = packbf(a0.z + dv * dv * hv.z + bv.z, a0.w + dv * dv * hv.w + bv.w);
    *(uint2*)&aggb[(size_t)n * 64 + cl * 2] = o;
  }
}

// ---------------------------------------------------------------------------
// GraphNorm stats on bf16 table: A = gw/sqrt(var+eps), B = gb - A*ms*mean.
// ---------------------------------------------------------------------------
__global__ __launch_bounds__(512) void k_gstats(
    const unsigned* __restrict__ hb, const int* __restrict__ start,
    const float* __restrict__ gw, const float* __restrict__ gb,
    const float* __restrict__ gms, float* __restrict__ An,
    float* __restrict__ Bn) {
  int g = blockIdx.x;
  int s = start[g], e = start[g + 1];
  int t = threadIdx.x, p = t >> 7, c = t & 127;
  float sum = 0.f, sq = 0.f;
  for (int n = s + p; n < e; n += 4) {
    float v = bfat(hb + (size_t)n * 64, c);
    sum += v;
    sq += v * v;
  }
  __shared__ float S[4][128], Q[4][128];
  S[p][c] = sum;
  Q[p][c] = sq;
  __syncthreads();
  if (t < 128) {
    float cnt = (float)max(e - s, 1);
    float mean = (S[0][t] + S[1][t] + S[2][t] + S[3][t]) / cnt;
    float e2 = (Q[0][t] + Q[1][t] + Q[2][t] + Q[3][t]) / cnt;
    float ms = gms[t];
    float var = fmaxf(e2 - ms * (2.f - ms) * mean * mean, 0.f);
    float scale = gw[t] / sqrtf(var + EPS);
    An[(size_t)g * 128 + t] = scale;
    Bn[(size_t)g * 128 + t] = gb[t] - scale * ms * mean;
  }
}

// pooled[g,c] = mean over graph nodes of relu(A*h+B), h bf16
__global__ __launch_bounds__(512) void k_pool(
    const unsigned* __restrict__ hb, const int* __restrict__ start,
    const float* __restrict__ An, const float* __restrict__ Bn,
    float* __restrict__ pooled) {
  int g = blockIdx.x;
  int s = start[g], e = start[g + 1];
  int t = threadIdx.x, p = t >> 7, c = t & 127;
  float A = An[(size_t)g * 128 + c], B = Bn[(size_t)g * 128 + c];
  float sum = 0.f;
  for (int n = s + p; n < e; n += 4)
    sum += fmaxf(A * bfat(hb + (size_t)n * 64, c) + B, 0.f);
  __shared__ float S[4][128];
  S[p][c] = sum;
  __syncthreads();
  if (t < 128) {
    float cnt = (float)max(e - s, 1);
    pooled[g * 128 + t] = (S[0][t] + S[1][t] + S[2][t] + S[3][t]) / cnt;
  }
}

// MLP head: 128 ->256 (BN,ReLU) ->128 (BN,ReLU) ->1; writes out[g] and h2.
__global__ __launch_bounds__(256) void k_head(
    const float* __restrict__ pooled, const float* __restrict__ w0,
    const float* __restrict__ b0, const float* __restrict__ g0,
    const float* __restrict__ bb0, const float* __restrict__ w1,
    const float* __restrict__ b1, const float* __restrict__ g1,
    const float* __restrict__ bb1, const float* __restrict__ ow,
    const float* __restrict__ ob, float* __restrict__ out) {
  __shared__ float p[128], h1[256], h2[128];
  int g = blockIdx.x, t = threadIdx.x;
  const float inv = 1.0f / sqrtf(1.0f + EPS);
  if (t < 128) p[t] = pooled[g * 128 + t];
  __syncthreads();
  {
    float acc = b0[t];
#pragma unroll 8
    for (int k = 0; k < 128; ++k) acc += p[k] * w0[k * 256 + t];
    h1[t] = fmaxf(acc * inv * g0[t] + bb0[t], 0.f);
  }
  __syncthreads();
  if (t < 128) {
    float acc = b1[t];
#pragma unroll 8
    for (int k = 0; k < 256; ++k) acc += h1[k] * w1[k * 128 + t];
    float v = fmaxf(acc * inv * g1[t] + bb1[t], 0.f);
    h2[t] = v;
    out[N_GRAPHS + g * 128 + t] = v;
  }
  __syncthreads();
  if (t < 64) {
    float v = h2[t] * ow[t] + h2[t + 64] * ow[t + 64];
#pragma unroll
    for (int off = 32; off; off >>= 1) v += __shfl_down(v, off);
    if (t == 0) out[g] = v + ob[0];
  }
}

// ---------------------------------------------------------------------------
extern "C" void kernel_launch(void* const* d_in, const int* in_sizes, int n_in,
                              void* d_out, int out_size, void* d_ws,
                              size_t ws_size, hipStream_t stream) {
  const float* x = (const float*)d_in[0];
  const float* edge_attr = (const float*)d_in[1];
  const float* em_w1 = (const float*)d_in[2];
  const float* em_b1 = (const float*)d_in[3];
  const float* em_w2 = (const float*)d_in[4];
  const float* em_b2 = (const float*)d_in[5];
  const float* conv_w[3] = {(const float*)d_in[6], (const float*)d_in[8],
                            (const float*)d_in[10]};
  const float* conv_b[3] = {(const float*)d_in[7], (const float*)d_in[9],
                            (const float*)d_in[11]};
  const float* gn_w[3] = {(const float*)d_in[12], (const float*)d_in[15],
                          (const float*)d_in[18]};
  const float* gn_b[3] = {(const float*)d_in[13], (const float*)d_in[16],
                          (const float*)d_in[19]};
  const float* gn_ms[3] = {(const float*)d_in[14], (const float*)d_in[17],
                           (const float*)d_in[20]};
  const float* lin_w0 = (const float*)d_in[21];
  const float* lin_b0 = (const float*)d_in[22];
  const float* bn_g0 = (const float*)d_in[23];
  const float* bn_b0 = (const float*)d_in[24];
  const float* lin_w1 = (const float*)d_in[25];
  const float* lin_b1 = (const float*)d_in[26];
  const float* bn_g1 = (const float*)d_in[27];
  const float* bn_b1 = (const float*)d_in[28];
  const float* out_w = (const float*)d_in[29];
  const float* out_b = (const float*)d_in[30];
  const int* edge_index = (const int*)d_in[31];
  const int* batch = (const int*)d_in[32];
  const int* src = edge_index;
  const int* tgt = edge_index + N_EDGES;

  char* w = (char*)d_ws;
  size_t off = 0;
  auto carve = [&](size_t bytes) {
    void* p = w + off;
    off = (off + bytes + 511) & ~(size_t)511;
    return p;
  };
  float* ew = (float*)carve((size_t)N_EDGES * 4);
  int* rank = (int*)carve((size_t)N_EDGES * 4);
  float* dinv = (float*)carve((size_t)N_NODES * 4);
  int* rowcnt = (int*)carve((size_t)N_NODES * 4);
  int* rowstart = (int*)carve((size_t)(N_NODES + 1) * 4);
  int* bsum = (int*)carve((size_t)SCAN_BLOCKS * 4);
  int* boff = (int*)carve((size_t)512 * 4);
  uint2* meta = (uint2*)carve((size_t)N_EDGES * 8);
  int* start = (int*)carve((N_GRAPHS + 1) * 4);
  float* AB = (float*)carve((size_t)6 * N_GRAPHS * 128 * 4);
  unsigned* xb = (unsigned*)carve((size_t)N_NODES * 64 * 2);
  unsigned* aggxb = (unsigned*)carve((size_t)N_NODES * 64 * 2);
  unsigned* h1b = (unsigned*)carve((size_t)N_NODES * 128 * 2);
  unsigned* hwb = (unsigned*)carve((size_t)N_NODES * 128 * 2);
  unsigned* agg1b = (unsigned*)carve((size_t)N_NODES * 128 * 2);
  unsigned* agg2b = (unsigned*)carve((size_t)N_NODES * 128 * 2);
  unsigned short* wt0 = (unsigned short*)carve((size_t)128 * 64 * 2);
  unsigned short* wt1 = (unsigned short*)carve((size_t)128 * 128 * 2);
  unsigned short* wt2 = (unsigned short*)carve((size_t)128 * 128 * 2);
  float* pooled = (float*)carve((size_t)N_GRAPHS * 128 * 4);

  float* A0 = AB, *B0 = AB + N_GRAPHS * 128;
  float* A1 = AB + 2 * N_GRAPHS * 128, *B1 = AB + 3 * N_GRAPHS * 128;
  float* A2 = AB + 4 * N_GRAPHS * 128, *B2 = AB + 5 * N_GRAPHS * 128;

  hipMemsetAsync(rowcnt, 0, (size_t)N_NODES * 4, stream);

  k_edge_mlp<<<(N_EDGES + 255) / 256, 256, 0, stream>>>(
      edge_attr, em_w1, em_b1, em_w2, em_b2, tgt, ew, rowcnt, rank);
  k_cvt<<<(N_NODES * 64 / 8 + 255) / 256, 256, 0, stream>>>(x, xb);
  k_cvtw<<<dim3(64, 2), 256, 0, stream>>>(conv_w[1], conv_w[2], wt1, wt2);
  k_cvtw0<<<32, 256, 0, stream>>>(conv_w[0], wt0);
  k_scan1<<<SCAN_BLOCKS, 256, 0, stream>>>(rowcnt, bsum);
  k_scan2<<<1, 512, 0, stream>>>(bsum, boff);
  k_scan3<<<SCAN_BLOCKS, 256, 0, stream>>>(rowcnt, boff, rowstart);
  k_fill<<<(N_EDGES + 255) / 256, 256, 0, stream>>>(src, tgt, ew, rank,
                                                    rowstart, meta);
  k_deg<<<(N_NODES + 255) / 256, 256, 0, stream>>>(meta, rowstart, dinv);
  k_scale<<<(N_NODES + 3) / 4, 256, 0, stream>>>(meta, rowstart, dinv);
  k_starts<<<1, 512, 0, stream>>>(batch, start);

  const int ggrid = (N_NODES + 3) / 4;
  const int hwgrid = (N_NODES + 63) / 64;

  // layer 0: aggregate-first (bf16), MFMA GEMM with bias -> h1b (pre-norm).
  k_gather64b<<<ggrid, 256, 0, stream>>>(xb, meta, rowstart, dinv, aggxb);
  k_hw_mfma0<<<hwgrid, 256, 0, stream>>>((unsigned short*)aggxb, wt0,
                                         conv_b[0], (unsigned short*)h1b);
  k_gstats<<<N_GRAPHS, 512, 0, stream>>>(h1b, start, gn_w[0], gn_b[0],
                                         gn_ms[0], A0, B0);
  // layer 1
  k_hw_mfma<<<hwgrid, 256, 0, stream>>>(h1b, wt1, batch, A0, B0,
                                        (unsigned short*)hwb);
  k_gatherb<<<ggrid, 256, 0, stream>>>(hwb, meta, rowstart, dinv, conv_b[1],
                                       agg1b);
  k_gstats<<<N_GRAPHS, 512, 0, stream>>>(agg1b, start, gn_w[1], gn_b[1],
                                         gn_ms[1], A1, B1);
  // layer 2
  k_hw_mfma<<<hwgrid, 256, 0, stream>>>(agg1b, wt2, batch, A1, B1,
                                        (unsigned short*)hwb);
  k_gatherb<<<ggrid, 256, 0, stream>>>(hwb, meta, rowstart, dinv, conv_b[2],
                                       agg2b);
  k_gstats<<<N_GRAPHS, 512, 0, stream>>>(agg2b, start, gn_w[2], gn_b[2],
                                         gn_ms[2], A2, B2);

  k_pool<<<N_GRAPHS, 512, 0, stream>>>(agg2b, start, A2, B2, pooled);
  k_head<<<N_GRAPHS, 256, 0, stream>>>(pooled, lin_w0, lin_b0, bn_g0, bn_b0,
                                       lin_w1, lin_b1, bn_g1, bn_b1, out_w,
                                       out_b, (float*)d_out);
}

// Round 10
// 520.330 us; speedup vs baseline: 5.4134x; 1.0205x over previous
//
#include <hip/hip_runtime.h>

#define N_NODES 100000
#define N_EDGES 1600000
#define N_GRAPHS 256
#define EPS 1e-5f

#define SCAN_BLOCKS ((N_NODES + 255) / 256)  // 391

// k_prep block ranges
#define EB 6250   // edge MLP blocks
#define CB 3125   // x->bf16 cvt blocks
#define WB 128    // W1/W2 transpose blocks
#define W0B 32    // W0 transpose blocks
#define PREP_BLOCKS (EB + CB + WB + W0B + 2)

typedef __attribute__((ext_vector_type(8))) short bfrag8;  // 8 bf16
typedef __attribute__((ext_vector_type(4))) float facc4;   // 4 f32 acc

__device__ __forceinline__ void fma4(float4& a, float s, const float4& w) {
  a.x += s * w.x; a.y += s * w.y; a.z += s * w.z; a.w += s * w.w;
}

__device__ __forceinline__ unsigned short f2bf(float f) {
  union { float f; unsigned u; } x;
  x.f = f;
  unsigned r = x.u + 0x7FFF + ((x.u >> 16) & 1);  // RNE
  return (unsigned short)(r >> 16);
}
__device__ __forceinline__ unsigned packbf(float a, float b) {
  return (unsigned)f2bf(a) | ((unsigned)f2bf(b) << 16);
}
__device__ __forceinline__ float4 bf4(unsigned lo, unsigned hi) {
  union { unsigned u; float f; } a, b, c, d;
  a.u = lo << 16;
  b.u = lo & 0xFFFF0000u;
  c.u = hi << 16;
  d.u = hi & 0xFFFF0000u;
  return make_float4(a.f, b.f, c.f, d.f);
}
__device__ __forceinline__ float bfat(const unsigned* tb, int idx) {
  unsigned u = tb[idx >> 1];
  union { unsigned u; float f; } v;
  v.u = (idx & 1) ? (u & 0xFFFF0000u) : (u << 16);
  return v.f;
}

// ---------------------------------------------------------------------------
// Mega-prep: [0,EB) edge MLP + rank histogram; [EB,EB+CB) x->bf16;
// then W1/W2 transpose, W0 transpose, graph starts. All independent.
// ---------------------------------------------------------------------------
__global__ __launch_bounds__(256) void k_prep(
    const float* __restrict__ ea, const float* __restrict__ w1,
    const float* __restrict__ b1, const float* __restrict__ w2,
    const float* __restrict__ b2, const int* __restrict__ tgt,
    float* __restrict__ ew, int* __restrict__ rowcnt, int* __restrict__ rank,
    const float* __restrict__ x, unsigned* __restrict__ xb,
    const float* __restrict__ cw1, const float* __restrict__ cw2,
    unsigned short* __restrict__ wt1, unsigned short* __restrict__ wt2,
    const float* __restrict__ cw0, unsigned short* __restrict__ wt0,
    const int* __restrict__ batch, int* __restrict__ start) {
  __shared__ float W1[128], B1[16], W2[16];
  const int b = blockIdx.x;
  const int t = threadIdx.x;
  if (b < EB) {
    // ---- edge MLP + atomic rank histogram ----
    if (t < 128) W1[t] = w1[t];
    if (t < 16) { B1[t] = b1[t]; W2[t] = w2[t]; }
    __syncthreads();
    int e = b * 256 + t;
    if (e >= N_EDGES) return;
    const float4* ap = (const float4*)(ea + (size_t)e * 8);
    float4 a0 = ap[0], a1 = ap[1];
    float a[8] = {a0.x, a0.y, a0.z, a0.w, a1.x, a1.y, a1.z, a1.w};
    float out = b2[0];
#pragma unroll
    for (int i = 0; i < 16; ++i) {
      float h = B1[i];
#pragma unroll
      for (int j = 0; j < 8; ++j) h += a[j] * W1[i * 8 + j];
      out += fmaxf(h, 0.f) * W2[i];
    }
    ew[e] = out;
    rank[e] = atomicAdd(&rowcnt[tgt[e]], 1);
  } else if (b < EB + CB) {
    // ---- x (f32) -> xb (bf16), 8 elems/thread ----
    int i = (b - EB) * 256 + t;
    if (i >= N_NODES * 64 / 8) return;
    const float4* p = (const float4*)(x + (size_t)i * 8);
    float4 a = p[0], bb = p[1];
    uint4 o;
    o.x = packbf(a.x, a.y);
    o.y = packbf(a.z, a.w);
    o.z = packbf(bb.x, bb.y);
    o.w = packbf(bb.z, bb.w);
    ((uint4*)xb)[i] = o;
  } else if (b < EB + CB + WB) {
    // ---- W1,W2 (128,128) -> transposed bf16 ----
    int lb = b - EB - CB;           // 0..127
    int half = lb >> 6;             // 0: w1, 1: w2
    int id = (lb & 63) * 256 + t;   // 0..16383
    const float* w = half ? cw2 : cw1;
    unsigned short* o = half ? wt2 : wt1;
    int n = id >> 7, k = id & 127;
    o[n * 128 + k] = f2bf(w[k * 128 + n]);
  } else if (b < EB + CB + WB + W0B) {
    // ---- W0 (64,128) -> transposed bf16 WT0[128][64] ----
    int id = (b - EB - CB - WB) * 256 + t;
    if (id >= 8192) return;
    int n = id >> 6, k = id & 63;
    wt0[n * 64 + k] = f2bf(cw0[k * 128 + n]);
  } else {
    // ---- graph segment starts ----
    int g = (b - EB - CB - WB - W0B) * 256 + t;
    if (g > N_GRAPHS) return;
    int lo = 0, hi = N_NODES;
    while (lo < hi) {
      int mid = (lo + hi) >> 1;
      if (batch[mid] < g) lo = mid + 1; else hi = mid;
    }
    start[g] = lo;
  }
}

// ---------------------------------------------------------------------------
// Parallel 3-phase exclusive scan of rowcnt -> rowstart[0..N]
// ---------------------------------------------------------------------------
__global__ __launch_bounds__(256) void k_scan1(const int* __restrict__ cnt,
                                               int* __restrict__ bsum) {
  int i = blockIdx.x * 256 + threadIdx.x;
  int v = (i < N_NODES) ? cnt[i] : 0;
#pragma unroll
  for (int off = 32; off; off >>= 1) v += __shfl_down(v, off);
  __shared__ int ws[4];
  if ((threadIdx.x & 63) == 0) ws[threadIdx.x >> 6] = v;
  __syncthreads();
  if (threadIdx.x == 0) bsum[blockIdx.x] = ws[0] + ws[1] + ws[2] + ws[3];
}

__global__ __launch_bounds__(512) void k_scan2(const int* __restrict__ bsum,
                                               int* __restrict__ boff) {
  __shared__ int s[512];
  int t = threadIdx.x;
  s[t] = (t < SCAN_BLOCKS) ? bsum[t] : 0;
  __syncthreads();
  for (int off = 1; off < 512; off <<= 1) {
    int u = (t >= off) ? s[t - off] : 0;
    __syncthreads();
    s[t] += u;
    __syncthreads();
  }
  boff[t] = (t == 0) ? 0 : s[t - 1];
}

__global__ __launch_bounds__(256) void k_scan3(const int* __restrict__ cnt,
                                               const int* __restrict__ boff,
                                               int* __restrict__ rowstart) {
  __shared__ int s[256];
  int t = threadIdx.x;
  int i = blockIdx.x * 256 + t;
  int v = (i < N_NODES) ? cnt[i] : 0;
  s[t] = v;
  __syncthreads();
  for (int off = 1; off < 256; off <<= 1) {
    int u = (t >= off) ? s[t - off] : 0;
    __syncthreads();
    s[t] += u;
    __syncthreads();
  }
  if (i < N_NODES) {
    int pre = boff[blockIdx.x] + s[t] - v;  // exclusive
    rowstart[i] = pre;
    if (i == N_NODES - 1) rowstart[N_NODES] = pre + v;
  }
}

// Atomic-free CSR fill with INTERLEAVED payload: meta[p] = {bits(w), src}.
__global__ __launch_bounds__(256) void k_fill(
    const int* __restrict__ src, const int* __restrict__ tgt,
    const float* __restrict__ ew, const int* __restrict__ rank,
    const int* __restrict__ rowstart, uint2* __restrict__ meta) {
  int e = blockIdx.x * 256 + threadIdx.x;
  if (e >= N_EDGES) return;
  int p = rowstart[tgt[e]] + rank[e];
  union { float f; unsigned u; } w;
  w.f = ew[e];
  meta[p] = make_uint2(w.u, (unsigned)src[e]);
}

// deg row-sum fused with dinv: dinv[n] = rsqrt(1 + sum ew_row)
__global__ __launch_bounds__(256) void k_deg(const uint2* __restrict__ meta,
                                             const int* __restrict__ rowstart,
                                             float* __restrict__ dinv) {
  int n = blockIdx.x * 256 + threadIdx.x;
  if (n >= N_NODES) return;
  int rs = rowstart[n], re = rowstart[n + 1];
  float d = 1.f;
  for (int j = rs; j < re; ++j) {
    union { unsigned u; float f; } w;
    w.u = meta[j].x;
    d += w.f;
  }
  dinv[n] = d > 0.f ? rsqrtf(d) : 0.f;
}

// meta[j].w *= dinv[src] * dinv[row]; wave per node.
__global__ __launch_bounds__(256) void k_scale(uint2* __restrict__ meta,
                                               const int* __restrict__ rowstart,
                                               const float* __restrict__ dinv) {
  int n = blockIdx.x * 4 + (threadIdx.x >> 6);
  if (n >= N_NODES) return;
  int lane = threadIdx.x & 63;
  int rs = rowstart[n], re = rowstart[n + 1];
  float dv = dinv[n];
  for (int j = rs + lane; j < re; j += 64) {
    uint2 m = meta[j];
    union { unsigned u; float f; } w;
    w.u = m.x;
    w.f *= dinv[m.y] * dv;
    meta[j].x = w.u;
  }
}

// ---------------------------------------------------------------------------
// 64-ch CSR gather on bf16 x -> bf16 aggx. wave/node; 4 edge slots x 16
// uint2-lanes. Unroll ladder 8/4/tail; 32-bit row indexing.
// ---------------------------------------------------------------------------
__global__ __launch_bounds__(256) void k_gather64b(
    const unsigned* __restrict__ xb, const uint2* __restrict__ meta,
    const int* __restrict__ rowstart, const float* __restrict__ dinv,
    unsigned* __restrict__ aggxb) {
  const int t = threadIdx.x;
  const int n = blockIdx.x * 4 + (t >> 6);
  if (n >= N_NODES) return;
  const unsigned lane = t & 63;
  const unsigned q = lane >> 4;   // edge slot 0..3
  const unsigned cl = lane & 15;  // uint2 group over 64 ch
  const int rs = rowstart[n], re = rowstart[n + 1];
  const uint2* x2 = (const uint2*)xb;
  float4 a0 = make_float4(0.f, 0.f, 0.f, 0.f);
  float4 a1 = make_float4(0.f, 0.f, 0.f, 0.f);
  int j = rs;
  for (; j + 8 <= re; j += 8) {
    uint2 m0 = meta[j + q], m1 = meta[j + 4 + q];
    union { unsigned u; float f; } w0, w1;
    w0.u = m0.x; w1.u = m1.x;
    uint2 v0 = x2[(m0.y << 4) + cl];
    uint2 v1 = x2[(m1.y << 4) + cl];
    fma4(a0, w0.f, bf4(v0.x, v0.y));
    fma4(a1, w1.f, bf4(v1.x, v1.y));
  }
  for (; j + 4 <= re; j += 4) {
    uint2 m0 = meta[j + q];
    union { unsigned u; float f; } w0;
    w0.u = m0.x;
    uint2 v0 = x2[(m0.y << 4) + cl];
    fma4(a0, w0.f, bf4(v0.x, v0.y));
  }
  if (j + (int)q < re) {
    uint2 m0 = meta[j + q];
    union { unsigned u; float f; } w0;
    w0.u = m0.x;
    uint2 v0 = x2[(m0.y << 4) + cl];
    fma4(a1, w0.f, bf4(v0.x, v0.y));
  }
  a0.x += a1.x; a0.y += a1.y; a0.z += a1.z; a0.w += a1.w;
#pragma unroll
  for (int m = 16; m <= 32; m <<= 1) {
    a0.x += __shfl_xor(a0.x, m);
    a0.y += __shfl_xor(a0.y, m);
    a0.z += __shfl_xor(a0.z, m);
    a0.w += __shfl_xor(a0.w, m);
  }
  if (q == 0) {
    float dv = dinv[n];
    uint2 hvb = x2[((unsigned)n << 4) + cl];
    float4 hv = bf4(hvb.x, hvb.y);
    uint2 o;
    o.x = packbf(a0.x + dv * dv * hv.x, a0.y + dv * dv * hv.y);
    o.y = packbf(a0.z + dv * dv * hv.z, a0.w + dv * dv * hv.w);
    *(uint2*)&aggxb[(size_t)n * 32 + cl * 2] = o;
  }
}

// ---------------------------------------------------------------------------
// Layer-0 MFMA GEMM: h1b = bf16( aggxb @ W0 + b0 ).  CIN=64.
// ---------------------------------------------------------------------------
__global__ __launch_bounds__(256) void k_hw_mfma0(
    const unsigned short* __restrict__ aggxb,
    const unsigned short* __restrict__ wt0, const float* __restrict__ bias,
    unsigned short* __restrict__ h1b) {
  __shared__ unsigned short Asb[64][72];
  __shared__ unsigned short Wsb[128][72];
  const int t = threadIdx.x;
  const int base = blockIdx.x * 64;

  for (int i = t; i < 1024; i += 256) {
    int nr = i >> 3, k8 = (i & 7) * 8;
    *(uint4*)&Wsb[nr][k8] = *(const uint4*)&wt0[nr * 64 + k8];
  }
  {
    const int ln = t >> 2;
    const int kp = (t & 3) * 16;
    const int n = base + ln;
    if (n < N_NODES) {
      *(uint4*)&Asb[ln][kp] = *(const uint4*)&aggxb[(size_t)n * 64 + kp];
      *(uint4*)&Asb[ln][kp + 8] = *(const uint4*)&aggxb[(size_t)n * 64 + kp + 8];
    } else {
      uint4 z = make_uint4(0, 0, 0, 0);
      *(uint4*)&Asb[ln][kp] = z;
      *(uint4*)&Asb[ln][kp + 8] = z;
    }
  }
  __syncthreads();

  const int wv = t >> 6;
  const int lr = t & 15;
  const int lk = (t >> 4) & 3;
  const int m0 = wv * 16;

  bfrag8 af[2];
#pragma unroll
  for (int kc = 0; kc < 2; ++kc)
    af[kc] = *(const bfrag8*)&Asb[m0 + lr][kc * 32 + lk * 8];

#pragma unroll
  for (int nt = 0; nt < 8; ++nt) {
    facc4 c = {0.f, 0.f, 0.f, 0.f};
#pragma unroll
    for (int kc = 0; kc < 2; ++kc) {
      bfrag8 bf = *(const bfrag8*)&Wsb[nt * 16 + lr][kc * 32 + lk * 8];
      c = __builtin_amdgcn_mfma_f32_16x16x32_bf16(af[kc], bf, c, 0, 0, 0);
    }
    int col = nt * 16 + lr;
    float bv = bias[col];
#pragma unroll
    for (int r = 0; r < 4; ++r) {
      int n = base + m0 + lk * 4 + r;
      if (n < N_NODES) h1b[(size_t)n * 128 + col] = f2bf(c[r] + bv);
    }
  }
}

// ---------------------------------------------------------------------------
// Layers 1-2 MFMA GEMM: hwb = bf16( relu(A*h+B) @ W ), h bf16 in.
// ---------------------------------------------------------------------------
__global__ __launch_bounds__(256) void k_hw_mfma(
    const unsigned* __restrict__ hb, const unsigned short* __restrict__ wt,
    const int* __restrict__ batch, const float* __restrict__ An,
    const float* __restrict__ Bn, unsigned short* __restrict__ hwb) {
  __shared__ unsigned short Asb[64][136];
  __shared__ unsigned short Wsb[128][136];
  const int t = threadIdx.x;
  const int base = blockIdx.x * 64;

  for (int i = t; i < 2048; i += 256) {
    int nr = i >> 4, k8 = (i & 15) * 8;
    *(uint4*)&Wsb[nr][k8] = *(const uint4*)&wt[nr * 128 + k8];
  }
  {
    const int ln = t >> 2;
    const int cg = (t & 3) * 32;
    const int n = base + ln;
    if (n < N_NODES) {
      const int g = batch[n];
      const uint4* hp = (const uint4*)(hb + (size_t)n * 64);
      const float* Ap = An + (size_t)g * 128;
      const float* Bp = Bn + (size_t)g * 128;
#pragma unroll
      for (int qq = 0; qq < 4; ++qq) {
        int c = cg + qq * 8;
        uint4 v = hp[(t & 3) * 4 + qq];
        float4 lo = bf4(v.x, v.y);
        float4 hi = bf4(v.z, v.w);
        float4 Alo = *(const float4*)&Ap[c], Blo = *(const float4*)&Bp[c];
        float4 Ahi = *(const float4*)&Ap[c + 4], Bhi = *(const float4*)&Bp[c + 4];
        uint4 o;
        o.x = packbf(fmaxf(Alo.x * lo.x + Blo.x, 0.f),
                     fmaxf(Alo.y * lo.y + Blo.y, 0.f));
        o.y = packbf(fmaxf(Alo.z * lo.z + Blo.z, 0.f),
                     fmaxf(Alo.w * lo.w + Blo.w, 0.f));
        o.z = packbf(fmaxf(Ahi.x * hi.x + Bhi.x, 0.f),
                     fmaxf(Ahi.y * hi.y + Bhi.y, 0.f));
        o.w = packbf(fmaxf(Ahi.z * hi.z + Bhi.z, 0.f),
                     fmaxf(Ahi.w * hi.w + Bhi.w, 0.f));
        *(uint4*)&Asb[ln][c] = o;
      }
    } else {
      uint4 z = make_uint4(0, 0, 0, 0);
#pragma unroll
      for (int qq = 0; qq < 4; ++qq) *(uint4*)&Asb[ln][cg + qq * 8] = z;
    }
  }
  __syncthreads();

  const int wv = t >> 6;
  const int lr = t & 15;
  const int lk = (t >> 4) & 3;
  const int m0 = wv * 16;

  bfrag8 af[4];
#pragma unroll
  for (int kc = 0; kc < 4; ++kc)
    af[kc] = *(const bfrag8*)&Asb[m0 + lr][kc * 32 + lk * 8];

#pragma unroll
  for (int nt = 0; nt < 8; ++nt) {
    facc4 c = {0.f, 0.f, 0.f, 0.f};
#pragma unroll
    for (int kc = 0; kc < 4; ++kc) {
      bfrag8 bf = *(const bfrag8*)&Wsb[nt * 16 + lr][kc * 32 + lk * 8];
      c = __builtin_amdgcn_mfma_f32_16x16x32_bf16(af[kc], bf, c, 0, 0, 0);
    }
    int col = nt * 16 + lr;
#pragma unroll
    for (int r = 0; r < 4; ++r) {
      int n = base + m0 + lk * 4 + r;
      if (n < N_NODES) hwb[(size_t)n * 128 + col] = f2bf(c[r]);
    }
  }
}

// ---------------------------------------------------------------------------
// 128-ch CSR gather on bf16 table -> bf16 agg. wave/node; 2 edges x 32
// uint2-lanes. Unroll ladder 8/4/2/1, 4 accumulators, 32-bit indexing.
// ---------------------------------------------------------------------------
__global__ __launch_bounds__(256) void k_gatherb(
    const unsigned* __restrict__ hwb, const uint2* __restrict__ meta,
    const int* __restrict__ rowstart, const float* __restrict__ dinv,
    const float* __restrict__ bias, unsigned* __restrict__ aggb) {
  const int t = threadIdx.x;
  const int n = blockIdx.x * 4 + (t >> 6);
  if (n >= N_NODES) return;
  const unsigned lane = t & 63;
  const unsigned q = lane >> 5;   // edge-of-pair selector
  const unsigned cl = lane & 31;  // uint2 group (4 ch) over 128 ch
  const int rs = rowstart[n], re = rowstart[n + 1];
  const uint2* hb = (const uint2*)hwb;
  float4 a0 = make_float4(0.f, 0.f, 0.f, 0.f);
  float4 a1 = make_float4(0.f, 0.f, 0.f, 0.f);
  float4 a2 = make_float4(0.f, 0.f, 0.f, 0.f);
  float4 a3 = make_float4(0.f, 0.f, 0.f, 0.f);
  int j = rs;
  for (; j + 8 <= re; j += 8) {
    uint2 m0 = meta[j + q], m1 = meta[j + 2 + q];
    uint2 m2 = meta[j + 4 + q], m3 = meta[j + 6 + q];
    union { unsigned u; float f; } w0, w1, w2, w3;
    w0.u = m0.x; w1.u = m1.x; w2.u = m2.x; w3.u = m3.x;
    uint2 v0 = hb[(m0.y << 5) + cl];
    uint2 v1 = hb[(m1.y << 5) + cl];
    uint2 v2 = hb[(m2.y << 5) + cl];
    uint2 v3 = hb[(m3.y << 5) + cl];
    fma4(a0, w0.f, bf4(v0.x, v0.y));
    fma4(a1, w1.f, bf4(v1.x, v1.y));
    fma4(a2, w2.f, bf4(v2.x, v2.y));
    fma4(a3, w3.f, bf4(v3.x, v3.y));
  }
  for (; j + 4 <= re; j += 4) {
    uint2 m0 = meta[j + q], m1 = meta[j + 2 + q];
    union { unsigned u; float f; } w0, w1;
    w0.u = m0.x; w1.u = m1.x;
    uint2 v0 = hb[(m0.y << 5) + cl];
    uint2 v1 = hb[(m1.y << 5) + cl];
    fma4(a0, w0.f, bf4(v0.x, v0.y));
    fma4(a1, w1.f, bf4(v1.x, v1.y));
  }
  for (; j + 2 <= re; j += 2) {
    uint2 m0 = meta[j + q];
    union { unsigned u; float f; } w0;
    w0.u = m0.x;
    uint2 v0 = hb[(m0.y << 5) + cl];
    fma4(a0, w0.f, bf4(v0.x, v0.y));
  }
  if (q == 0 && j < re) {
    uint2 m0 = meta[j];
    union { unsigned u; float f; } w0;
    w0.u = m0.x;
    uint2 v0 = hb[(m0.y << 5) + cl];
    fma4(a1, w0.f, bf4(v0.x, v0.y));
  }
  a0.x += a1.x + a2.x + a3.x;
  a0.y += a1.y + a2.y + a3.y;
  a0.z += a1.z + a2.z + a3.z;
  a0.w += a1.w + a2.w + a3.w;
  a0.x += __shfl_xor(a0.x, 32);
  a0.y += __shfl_xor(a0.y, 32);
  a0.z += __shfl_xor(a0.z, 32);
  a0.w += __shfl_xor(a0.w, 32);
  if (q == 0) {
    float dv = dinv[n];
    uint2 hvb = hb[((unsigned)n << 5) + cl];
    float4 hv = bf4(hvb.x, hvb.y);
    float4 bv = ((const float4*)bias)[cl];
    uint2 o;
    o.x = packbf(a0.x + dv * dv * hv.x + bv.x, a0.y + dv * dv * hv.y + bv.y);
    o.y = packbf(a0.z + dv * dv * hv.z + bv.z, a0.w + dv * dv * hv.w + bv.w);
    *(uint2*)&aggb[(size_t)n * 64 + cl * 2] = o;
  }
}

// ---------------------------------------------------------------------------
// GraphNorm stats on bf16 table: A = gw/sqrt(var+eps), B = gb - A*ms*mean.
// ---------------------------------------------------------------------------
__global__ __launch_bounds__(512) void k_gstats(
    const unsigned* __restrict__ hb, const int* __restrict__ start,
    const float* __restrict__ gw, const float* __restrict__ gb,
    const float* __restrict__ gms, float* __restrict__ An,
    float* __restrict__ Bn) {
  int g = blockIdx.x;
  int s = start[g], e = start[g + 1];
  int t = threadIdx.x, p = t >> 7, c = t & 127;
  float sum = 0.f, sq = 0.f;
  for (int n = s + p; n < e; n += 4) {
    float v = bfat(hb + (size_t)n * 64, c);
    sum += v;
    sq += v * v;
  }
  __shared__ float S[4][128], Q[4][128];
  S[p][c] = sum;
  Q[p][c] = sq;
  __syncthreads();
  if (t < 128) {
    float cnt = (float)max(e - s, 1);
    float mean = (S[0][t] + S[1][t] + S[2][t] + S[3][t]) / cnt;
    float e2 = (Q[0][t] + Q[1][t] + Q[2][t] + Q[3][t]) / cnt;
    float ms = gms[t];
    float var = fmaxf(e2 - ms * (2.f - ms) * mean * mean, 0.f);
    float scale = gw[t] / sqrtf(var + EPS);
    An[(size_t)g * 128 + t] = scale;
    Bn[(size_t)g * 128 + t] = gb[t] - scale * ms * mean;
  }
}

// pooled[g,c] = mean over graph nodes of relu(A*h+B), h bf16
__global__ __launch_bounds__(512) void k_pool(
    const unsigned* __restrict__ hb, const int* __restrict__ start,
    const float* __restrict__ An, const float* __restrict__ Bn,
    float* __restrict__ pooled) {
  int g = blockIdx.x;
  int s = start[g], e = start[g + 1];
  int t = threadIdx.x, p = t >> 7, c = t & 127;
  float A = An[(size_t)g * 128 + c], B = Bn[(size_t)g * 128 + c];
  float sum = 0.f;
  for (int n = s + p; n < e; n += 4)
    sum += fmaxf(A * bfat(hb + (size_t)n * 64, c) + B, 0.f);
  __shared__ float S[4][128];
  S[p][c] = sum;
  __syncthreads();
  if (t < 128) {
    float cnt = (float)max(e - s, 1);
    pooled[g * 128 + t] = (S[0][t] + S[1][t] + S[2][t] + S[3][t]) / cnt;
  }
}

// MLP head: 128 ->256 (BN,ReLU) ->128 (BN,ReLU) ->1; writes out[g] and h2.
__global__ __launch_bounds__(256) void k_head(
    const float* __restrict__ pooled, const float* __restrict__ w0,
    const float* __restrict__ b0, const float* __restrict__ g0,
    const float* __restrict__ bb0, const float* __restrict__ w1,
    const float* __restrict__ b1, const float* __restrict__ g1,
    const float* __restrict__ bb1, const float* __restrict__ ow,
    const float* __restrict__ ob, float* __restrict__ out) {
  __shared__ float p[128], h1[256], h2[128];
  int g = blockIdx.x, t = threadIdx.x;
  const float inv = 1.0f / sqrtf(1.0f + EPS);
  if (t < 128) p[t] = pooled[g * 128 + t];
  __syncthreads();
  {
    float acc = b0[t];
#pragma unroll 8
    for (int k = 0; k < 128; ++k) acc += p[k] * w0[k * 256 + t];
    h1[t] = fmaxf(acc * inv * g0[t] + bb0[t], 0.f);
  }
  __syncthreads();
  if (t < 128) {
    float acc = b1[t];
#pragma unroll 8
    for (int k = 0; k < 256; ++k) acc += h1[k] * w1[k * 128 + t];
    float v = fmaxf(acc * inv * g1[t] + bb1[t], 0.f);
    h2[t] = v;
    out[N_GRAPHS + g * 128 + t] = v;
  }
  __syncthreads();
  if (t < 64) {
    float v = h2[t] * ow[t] + h2[t + 64] * ow[t + 64];
#pragma unroll
    for (int off = 32; off; off >>= 1) v += __shfl_down(v, off);
    if (t == 0) out[g] = v + ob[0];
  }
}

// ---------------------------------------------------------------------------
extern "C" void kernel_launch(void* const* d_in, const int* in_sizes, int n_in,
                              void* d_out, int out_size, void* d_ws,
                              size_t ws_size, hipStream_t stream) {
  const float* x = (const float*)d_in[0];
  const float* edge_attr = (const float*)d_in[1];
  const float* em_w1 = (const float*)d_in[2];
  const float* em_b1 = (const float*)d_in[3];
  const float* em_w2 = (const float*)d_in[4];
  const float* em_b2 = (const float*)d_in[5];
  const float* conv_w[3] = {(const float*)d_in[6], (const float*)d_in[8],
                            (const float*)d_in[10]};
  const float* conv_b[3] = {(const float*)d_in[7], (const float*)d_in[9],
                            (const float*)d_in[11]};
  const float* gn_w[3] = {(const float*)d_in[12], (const float*)d_in[15],
                          (const float*)d_in[18]};
  const float* gn_b[3] = {(const float*)d_in[13], (const float*)d_in[16],
                          (const float*)d_in[19]};
  const float* gn_ms[3] = {(const float*)d_in[14], (const float*)d_in[17],
                           (const float*)d_in[20]};
  const float* lin_w0 = (const float*)d_in[21];
  const float* lin_b0 = (const float*)d_in[22];
  const float* bn_g0 = (const float*)d_in[23];
  const float* bn_b0 = (const float*)d_in[24];
  const float* lin_w1 = (const float*)d_in[25];
  const float* lin_b1 = (const float*)d_in[26];
  const float* bn_g1 = (const float*)d_in[27];
  const float* bn_b1 = (const float*)d_in[28];
  const float* out_w = (const float*)d_in[29];
  const float* out_b = (const float*)d_in[30];
  const int* edge_index = (const int*)d_in[31];
  const int* batch = (const int*)d_in[32];
  const int* src = edge_index;
  const int* tgt = edge_index + N_EDGES;

  char* w = (char*)d_ws;
  size_t off = 0;
  auto carve = [&](size_t bytes) {
    void* p = w + off;
    off = (off + bytes + 511) & ~(size_t)511;
    return p;
  };
  float* ew = (float*)carve((size_t)N_EDGES * 4);
  int* rank = (int*)carve((size_t)N_EDGES * 4);
  float* dinv = (float*)carve((size_t)N_NODES * 4);
  int* rowcnt = (int*)carve((size_t)N_NODES * 4);
  int* rowstart = (int*)carve((size_t)(N_NODES + 1) * 4);
  int* bsum = (int*)carve((size_t)SCAN_BLOCKS * 4);
  int* boff = (int*)carve((size_t)512 * 4);
  uint2* meta = (uint2*)carve((size_t)N_EDGES * 8);
  int* start = (int*)carve((N_GRAPHS + 1) * 4);
  float* AB = (float*)carve((size_t)6 * N_GRAPHS * 128 * 4);
  unsigned* xb = (unsigned*)carve((size_t)N_NODES * 64 * 2);
  unsigned* aggxb = (unsigned*)carve((size_t)N_NODES * 64 * 2);
  unsigned* h1b = (unsigned*)carve((size_t)N_NODES * 128 * 2);
  unsigned* hwb = (unsigned*)carve((size_t)N_NODES * 128 * 2);
  unsigned* agg1b = (unsigned*)carve((size_t)N_NODES * 128 * 2);
  unsigned* agg2b = (unsigned*)carve((size_t)N_NODES * 128 * 2);
  unsigned short* wt0 = (unsigned short*)carve((size_t)128 * 64 * 2);
  unsigned short* wt1 = (unsigned short*)carve((size_t)128 * 128 * 2);
  unsigned short* wt2 = (unsigned short*)carve((size_t)128 * 128 * 2);
  float* pooled = (float*)carve((size_t)N_GRAPHS * 128 * 4);

  float* A0 = AB, *B0 = AB + N_GRAPHS * 128;
  float* A1 = AB + 2 * N_GRAPHS * 128, *B1 = AB + 3 * N_GRAPHS * 128;
  float* A2 = AB + 4 * N_GRAPHS * 128, *B2 = AB + 5 * N_GRAPHS * 128;

  hipMemsetAsync(rowcnt, 0, (size_t)N_NODES * 4, stream);

  k_prep<<<PREP_BLOCKS, 256, 0, stream>>>(
      edge_attr, em_w1, em_b1, em_w2, em_b2, tgt, ew, rowcnt, rank, x, xb,
      conv_w[1], conv_w[2], wt1, wt2, conv_w[0], wt0, batch, start);
  k_scan1<<<SCAN_BLOCKS, 256, 0, stream>>>(rowcnt, bsum);
  k_scan2<<<1, 512, 0, stream>>>(bsum, boff);
  k_scan3<<<SCAN_BLOCKS, 256, 0, stream>>>(rowcnt, boff, rowstart);
  k_fill<<<(N_EDGES + 255) / 256, 256, 0, stream>>>(src, tgt, ew, rank,
                                                    rowstart, meta);
  k_deg<<<(N_NODES + 255) / 256, 256, 0, stream>>>(meta, rowstart, dinv);
  k_scale<<<(N_NODES + 3) / 4, 256, 0, stream>>>(meta, rowstart, dinv);

  const int ggrid = (N_NODES + 3) / 4;
  const int hwgrid = (N_NODES + 63) / 64;

  // layer 0: aggregate-first (bf16), MFMA GEMM with bias -> h1b (pre-norm).
  k_gather64b<<<ggrid, 256, 0, stream>>>(xb, meta, rowstart, dinv, aggxb);
  k_hw_mfma0<<<hwgrid, 256, 0, stream>>>((unsigned short*)aggxb, wt0,
                                         conv_b[0], (unsigned short*)h1b);
  k_gstats<<<N_GRAPHS, 512, 0, stream>>>(h1b, start, gn_w[0], gn_b[0],
                                         gn_ms[0], A0, B0);
  // layer 1
  k_hw_mfma<<<hwgrid, 256, 0, stream>>>(h1b, wt1, batch, A0, B0,
                                        (unsigned short*)hwb);
  k_gatherb<<<ggrid, 256, 0, stream>>>(hwb, meta, rowstart, dinv, conv_b[1],
                                       agg1b);
  k_gstats<<<N_GRAPHS, 512, 0, stream>>>(agg1b, start, gn_w[1], gn_b[1],
                                         gn_ms[1], A1, B1);
  // layer 2
  k_hw_mfma<<<hwgrid, 256, 0, stream>>>(agg1b, wt2, batch, A1, B1,
                                        (unsigned short*)hwb);
  k_gatherb<<<ggrid, 256, 0, stream>>>(hwb, meta, rowstart, dinv, conv_b[2],
                                       agg2b);
  k_gstats<<<N_GRAPHS, 512, 0, stream>>>(agg2b, start, gn_w[2], gn_b[2],
                                         gn_ms[2], A2, B2);

  k_pool<<<N_GRAPHS, 512, 0, stream>>>(agg2b, start, A2, B2, pooled);
  k_head<<<N_GRAPHS, 256, 0, stream>>>(pooled, lin_w0, lin_b0, bn_g0, bn_b0,
                                       lin_w1, lin_b1, bn_g1, bn_b1, out_w,
                                       out_b, (float*)d_out);
}